// Round 3
// baseline (423.927 us; speedup 1.0000x reference)
//
#include <hip/hip_runtime.h>

// Problem constants
#define BATCH 2
#define LSEQ 384
#define NHID 512
#define NH 8
#define DH 64
#define BH (BATCH*NH)          // 16
#define MROWS (BATCH*LSEQ)     // 768
#define XELEMS ((size_t)MROWS * NHID)      // 393216 (x output elems)
#define TQ 4                   // q-rows per attn block
#define QTILES (LSEQ/TQ)       // 96

typedef unsigned short ushort_t;

__device__ __forceinline__ float bf2f(ushort_t u) {
    unsigned int v = ((unsigned int)u) << 16;
    return __uint_as_float(v);
}
__device__ __forceinline__ ushort_t f2bf(float f) {
    unsigned int u = __float_as_uint(f);
    unsigned int lsb = (u >> 16) & 1u;
    u += 0x7fffu + lsb;           // round-to-nearest-even
    return (ushort_t)(u >> 16);
}

// ---------------- workspace layout (float offsets) ----------------
// ws[0] = dtype flag (int), ws[1] = vbSum (float)
#define OFF_QF    16
#define OFF_KF    393232
#define OFF_VF    786448
#define OFF_WQ    1179664
#define OFF_BQ    2228240
#define OFF_WK    1441808
#define OFF_BK    2228752
#define OFF_WV    1703952
#define OFF_BV    2229264
#define OFF_WO    1966096
#define OFF_BO    2229776
#define OFF_W1    2230288
#define OFF_B1    2238480
#define OFF_W2    2234384
#define OFF_B2    2238544
#define OFF_VW    2238608
#define OFF_VB    2238672
#define OFF_WQE   2238688
#define OFF_WKE   2500832
#define OFF_BQE   2762976
#define OFF_BKE   2763488
#define OFF_TQ    2764000     // Etq = exp(2 tq)  [bh][l][d]
#define OFF_TKT   3157216     // Etk = exp(2 tk)  [bh][d][l]
#define OFF_VH    3550432     // V               [bh][l][d]
#define OFF_XH    3943648     // context [B,L,H,D]
// end = 4336864 floats = 17.35 MB

// ---------------------------------------------------------------------------
// Kernel 0: detect packed-bf16 (flag=0) vs fp32 (flag=1) inputs.
// ---------------------------------------------------------------------------
__global__ __launch_bounds__(256) void detect_dtype(const unsigned int* __restrict__ q,
                                                    int* __restrict__ flag)
{
    __shared__ int cnt;
    int t = threadIdx.x;
    if (t == 0) cnt = 0;
    __syncthreads();
    unsigned int w = q[t];
    unsigned int elo = (w >> 7) & 0xFFu;   // low halfword's bf16 exponent field
    int isbf = (elo >= 100u && elo <= 150u) ? 1 : 0;
    atomicAdd(&cnt, isbf);
    __syncthreads();
    if (t == 0) *flag = (cnt > 128) ? 0 : 1;
}

// ---------------------------------------------------------------------------
// Kernel 1: convert all 17 float inputs into fp32 ws buffers.
// Segment lookup is a compile-time-constant if-chain (no memory walks);
// 4-wide vectorized (all segment boundaries are %4==0 except the final vb).
// ---------------------------------------------------------------------------
struct Srcs { const void* p[17]; };
#define CONV_TOTAL 2238657
#define NGRP 559665           // 559664 full float4 groups + 1 scalar (vb)

__global__ __launch_bounds__(256) void convert_inputs(Srcs s, float* __restrict__ ws,
                                                      const int* __restrict__ flag)
{
    int f = *flag;
    for (int g = blockIdx.x * 256 + threadIdx.x; g < NGRP; g += gridDim.x * 256) {
        int r = g * 4;
        const void* sp; int dof;
        if (r < 393216)                  { sp = s.p[0];  dof = OFF_QF; }
        else if ((r -= 393216) < 393216) { sp = s.p[1];  dof = OFF_KF; }
        else if ((r -= 393216) < 393216) { sp = s.p[2];  dof = OFF_VF; }
        else if ((r -= 393216) < 262144) { sp = s.p[3];  dof = OFF_WQ; }
        else if ((r -= 262144) < 512)    { sp = s.p[4];  dof = OFF_BQ; }
        else if ((r -= 512) < 262144)    { sp = s.p[5];  dof = OFF_WK; }
        else if ((r -= 262144) < 512)    { sp = s.p[6];  dof = OFF_BK; }
        else if ((r -= 512) < 262144)    { sp = s.p[7];  dof = OFF_WV; }
        else if ((r -= 262144) < 512)    { sp = s.p[8];  dof = OFF_BV; }
        else if ((r -= 512) < 262144)    { sp = s.p[9];  dof = OFF_WO; }
        else if ((r -= 262144) < 512)    { sp = s.p[10]; dof = OFF_BO; }
        else if ((r -= 512) < 4096)      { sp = s.p[11]; dof = OFF_W1; }
        else if ((r -= 4096) < 64)       { sp = s.p[12]; dof = OFF_B1; }
        else if ((r -= 64) < 4096)       { sp = s.p[13]; dof = OFF_W2; }
        else if ((r -= 4096) < 64)       { sp = s.p[14]; dof = OFF_B2; }
        else if ((r -= 64) < 64)         { sp = s.p[15]; dof = OFF_VW; }
        else                { r -= 64;     sp = s.p[16]; dof = OFF_VB; }

        if (g == NGRP - 1) {           // vb scalar tail
            float v = f ? ((const float*)sp)[r] : bf2f(((const ushort_t*)sp)[r]);
            ws[dof + r] = v;
        } else {
            float4 v;
            if (f) v = ((const float4*)sp)[r >> 2];
            else {
                ushort4 u = ((const ushort4*)sp)[r >> 2];
                v.x = bf2f(u.x); v.y = bf2f(u.y); v.z = bf2f(u.z); v.w = bf2f(u.w);
            }
            *reinterpret_cast<float4*>(ws + dof + r) = v;
        }
    }
}

// ---------------------------------------------------------------------------
// Kernel 2: fold W1 into Wq, W2 into Wk (per-head), scaled by 2 so the QKV
// GEMM outputs 2*tq / 2*tk directly. Also vbSum = vb + sum(vw) -> ws[1].
// ---------------------------------------------------------------------------
__global__ __launch_bounds__(256) void fuse_weights(const float* __restrict__ ws_in,
                                                    float* __restrict__ ws)
{
    const float* Wq = ws_in + OFF_WQ;
    const float* Wk = ws_in + OFF_WK;
    const float* W1 = ws_in + OFF_W1;
    const float* W2 = ws_in + OFF_W2;
    const float* bq = ws_in + OFF_BQ;
    const float* bk = ws_in + OFF_BK;
    const float* b1 = ws_in + OFF_B1;
    const float* b2 = ws_in + OFF_B2;
    float* WqE = ws + OFF_WQE;
    float* WkE = ws + OFF_WKE;
    float* bqE = ws + OFF_BQE;
    float* bkE = ws + OFF_BKE;

    int gid = blockIdx.x * 256 + threadIdx.x;   // 0 .. 512*512-1
    int o = gid >> 9;
    int i = gid & 511;
    int h = o >> 6, od = o & 63;
    float aq = 0.f, ak = 0.f;
    for (int j = 0; j < 64; j++) {
        aq = fmaf(W1[od * 64 + j], Wq[(h * 64 + j) * 512 + i], aq);
        ak = fmaf(W2[od * 64 + j], Wk[(h * 64 + j) * 512 + i], ak);
    }
    WqE[o * 512 + i] = 2.0f * aq;
    WkE[o * 512 + i] = 2.0f * ak;
    if (i == 0) {
        float sq = b1[od], sk = b2[od];
        for (int j = 0; j < 64; j++) {
            sq = fmaf(W1[od * 64 + j], bq[h * 64 + j], sq);
            sk = fmaf(W2[od * 64 + j], bk[h * 64 + j], sk);
        }
        bqE[o] = 2.0f * sq; bkE[o] = 2.0f * sk;
    }
    // vbSum reduction by block 0's first wave
    if (blockIdx.x == 0 && threadIdx.x < 64) {
        float v = ws_in[OFF_VW + threadIdx.x];
        #pragma unroll
        for (int off = 32; off > 0; off >>= 1) v += __shfl_xor(v, off, 64);
        if (threadIdx.x == 0) ws[1] = ws_in[OFF_VB] + v;
    }
}

// ---------------------------------------------------------------------------
// Kernel 3: QKV projection GEMM. z=0: Etq=exp(2tq) [bh][l][d];
// z=1: Etk=exp(2tk) transposed [bh][d][l]; z=2: V [bh][l][d].
// ---------------------------------------------------------------------------
__global__ __launch_bounds__(256) void gemm_qkv(const float* __restrict__ ws_in,
                                                float* __restrict__ ws)
{
    const int mode = blockIdx.z;
    const float* A    = ws_in + ((mode == 0) ? OFF_QF  : (mode == 1) ? OFF_KF  : OFF_VF);
    const float* W    = ws_in + ((mode == 0) ? OFF_WQE : (mode == 1) ? OFF_WKE : OFF_WV);
    const float* bias = ws_in + ((mode == 0) ? OFF_BQE : (mode == 1) ? OFF_BKE : OFF_BV);
    float* Out        = ws    + ((mode == 0) ? OFF_TQ  : (mode == 1) ? OFF_TKT : OFF_VH);

    __shared__ float As[64][17];
    __shared__ float Bs[16][64];

    const int tid = threadIdx.x;
    const int row0 = blockIdx.y * 64;
    const int col0 = blockIdx.x * 64;
    const int ty = tid >> 4, tx = tid & 15;
    const int lm = tid >> 2;
    const int lk = (tid & 3) << 2;

    float acc[4][4];
    #pragma unroll
    for (int i = 0; i < 4; i++)
        #pragma unroll
        for (int j = 0; j < 4; j++) acc[i][j] = 0.f;

    for (int k0 = 0; k0 < 512; k0 += 16) {
        float4 av = *reinterpret_cast<const float4*>(A + (row0 + lm) * 512 + k0 + lk);
        float4 wv = *reinterpret_cast<const float4*>(W + (col0 + lm) * 512 + k0 + lk);
        __syncthreads();
        As[lm][lk + 0] = av.x; As[lm][lk + 1] = av.y;
        As[lm][lk + 2] = av.z; As[lm][lk + 3] = av.w;
        Bs[lk + 0][lm] = wv.x; Bs[lk + 1][lm] = wv.y;
        Bs[lk + 2][lm] = wv.z; Bs[lk + 3][lm] = wv.w;
        __syncthreads();
        #pragma unroll
        for (int kk = 0; kk < 16; kk++) {
            float a0 = As[ty * 4 + 0][kk], a1 = As[ty * 4 + 1][kk];
            float a2 = As[ty * 4 + 2][kk], a3 = As[ty * 4 + 3][kk];
            float b0 = Bs[kk][tx * 4 + 0], b1 = Bs[kk][tx * 4 + 1];
            float b2 = Bs[kk][tx * 4 + 2], b3 = Bs[kk][tx * 4 + 3];
            acc[0][0] = fmaf(a0, b0, acc[0][0]); acc[0][1] = fmaf(a0, b1, acc[0][1]);
            acc[0][2] = fmaf(a0, b2, acc[0][2]); acc[0][3] = fmaf(a0, b3, acc[0][3]);
            acc[1][0] = fmaf(a1, b0, acc[1][0]); acc[1][1] = fmaf(a1, b1, acc[1][1]);
            acc[1][2] = fmaf(a1, b2, acc[1][2]); acc[1][3] = fmaf(a1, b3, acc[1][3]);
            acc[2][0] = fmaf(a2, b0, acc[2][0]); acc[2][1] = fmaf(a2, b1, acc[2][1]);
            acc[2][2] = fmaf(a2, b2, acc[2][2]); acc[2][3] = fmaf(a2, b3, acc[2][3]);
            acc[3][0] = fmaf(a3, b0, acc[3][0]); acc[3][1] = fmaf(a3, b1, acc[3][1]);
            acc[3][2] = fmaf(a3, b2, acc[3][2]); acc[3][3] = fmaf(a3, b3, acc[3][3]);
        }
    }

    #pragma unroll
    for (int i = 0; i < 4; i++) {
        int m = row0 + ty * 4 + i;
        int bb = m / LSEQ, ll = m % LSEQ;
        #pragma unroll
        for (int j = 0; j < 4; j++) {
            int n = col0 + tx * 4 + j;
            float c = acc[i][j] + bias[n];
            if (mode != 2) c = __expf(c);       // Etq / Etk
            int hh = n >> 6, dd = n & 63;
            int bh = bb * NH + hh;
            size_t off = (mode == 1) ? ((size_t)(bh * 64 + dd) * LSEQ + ll)
                                     : ((size_t)(bh * LSEQ + ll) * 64 + dd);
            Out[off] = c;
        }
    }
}

// ---------------------------------------------------------------------------
// Kernel 4: additive attention, TQ=4 q-rows per block, 384 threads (t = k).
// energy term: vw/(1+Etq*Etk) = rcp(fma(Etq*iw, Etk, iw)); e = vbSum - 2*sum.
// ---------------------------------------------------------------------------
__global__ __launch_bounds__(384) void attn_kernel(const float* __restrict__ ws_in,
                                                   float* __restrict__ ws,
                                                   const int* __restrict__ mask,
                                                   void* __restrict__ dout,
                                                   const int* __restrict__ flag)
{
    const float* Etq = ws_in + OFF_TQ;
    const float* Etk = ws_in + OFF_TKT;
    const float* Vh  = ws_in + OFF_VH;
    const float* vwf = ws_in + OFF_VW;
    float* Xh = ws + OFF_XH;

    const int bid = blockIdx.x;            // bh*QTILES + qt
    const int qt = bid % QTILES;
    const int bh = bid / QTILES;
    const int q0 = qt * TQ;
    const int b  = bh >> 3;
    const int h  = bh & 7;
    const int t  = threadIdx.x;            // 0..383 (= k)
    const int wave = t >> 6;
    const int f  = *flag;
    const float vbSum = ws_in[1];

    __shared__ float etqT[64][TQ];         // [d][qi], pre-multiplied by iw[d]
    __shared__ float iws[64];
    __shared__ float ps[TQ][LSEQ];
    __shared__ float red[6][TQ][16][4];
    __shared__ float rmax[TQ][6];
    __shared__ float rsum[TQ][6];

    if (t < 256) {
        int d = t & 63, qi = t >> 6;
        float iw = __builtin_amdgcn_rcpf(vwf[d]);
        etqT[d][qi] = Etq[(size_t)(bh * LSEQ + q0 + qi) * 64 + d] * iw;
        if (qi == 0) iws[d] = iw;
    }

    float etk[64];
    const float* ekbase = Etk + (size_t)bh * 64 * LSEQ + t;
    #pragma unroll
    for (int d = 0; d < 64; d++) etk[d] = ekbase[d * LSEQ];
    const int mok = mask[b * LSEQ + t];
    __syncthreads();

    // ---- energy for TQ q-rows ----
    float e2[TQ] = {0.f, 0.f, 0.f, 0.f};
    #pragma unroll
    for (int d = 0; d < 64; d++) {
        float4 eq = *reinterpret_cast<const float4*>(&etqT[d][0]);  // broadcast b128
        float iw = iws[d];
        float ek = etk[d];
        e2[0] += __builtin_amdgcn_rcpf(fmaf(eq.x, ek, iw));
        e2[1] += __builtin_amdgcn_rcpf(fmaf(eq.y, ek, iw));
        e2[2] += __builtin_amdgcn_rcpf(fmaf(eq.z, ek, iw));
        e2[3] += __builtin_amdgcn_rcpf(fmaf(eq.w, ek, iw));
    }
    float en[TQ];
    #pragma unroll
    for (int qi = 0; qi < TQ; qi++) {
        en[qi] = fmaf(-2.0f, e2[qi], vbSum);
        if (mok == 0) en[qi] = -1e10f;
    }

    // ---- softmax (block-wide over 6 waves), batched for TQ rows ----
    #pragma unroll
    for (int qi = 0; qi < TQ; qi++) {
        float m = en[qi];
        #pragma unroll
        for (int off = 32; off > 0; off >>= 1) m = fmaxf(m, __shfl_xor(m, off, 64));
        if ((t & 63) == 0) rmax[qi][wave] = m;
    }
    __syncthreads();
    float p[TQ];
    #pragma unroll
    for (int qi = 0; qi < TQ; qi++) {
        float gm = fmaxf(fmaxf(fmaxf(rmax[qi][0], rmax[qi][1]),
                               fmaxf(rmax[qi][2], rmax[qi][3])),
                         fmaxf(rmax[qi][4], rmax[qi][5]));
        p[qi] = __expf(en[qi] - gm);
        float s = p[qi];
        #pragma unroll
        for (int off = 32; off > 0; off >>= 1) s += __shfl_xor(s, off, 64);
        if ((t & 63) == 0) rsum[qi][wave] = s;
    }
    __syncthreads();
    #pragma unroll
    for (int qi = 0; qi < TQ; qi++) {
        float gs = rsum[qi][0] + rsum[qi][1] + rsum[qi][2] +
                   rsum[qi][3] + rsum[qi][4] + rsum[qi][5];
        p[qi] *= 1.0f / gs;
        ps[qi][t] = p[qi];
        size_t aidx = XELEMS + (size_t)(bh * LSEQ + q0 + qi) * LSEQ + t;
        if (f) ((float*)dout)[aidx] = p[qi];
        else   ((ushort_t*)dout)[aidx] = f2bf(p[qi]);
    }
    __syncthreads();

    // ---- context: x[qi][d] = sum_k p[k] V[k][d]; float4 V reused across qi ----
    const int dq = t & 15;                 // d-quad: d = dq*4 .. dq*4+3
    const int ksub = t >> 4;               // 0..23
    const float* vb4 = Vh + (size_t)bh * LSEQ * 64 + dq * 4;
    float4 acc[TQ];
    #pragma unroll
    for (int qi = 0; qi < TQ; qi++) acc[qi] = make_float4(0.f, 0.f, 0.f, 0.f);
    for (int kk = ksub; kk < LSEQ; kk += 24) {
        float4 v4 = *reinterpret_cast<const float4*>(vb4 + (size_t)kk * 64);
        #pragma unroll
        for (int qi = 0; qi < TQ; qi++) {
            float pq = ps[qi][kk];
            acc[qi].x = fmaf(pq, v4.x, acc[qi].x);
            acc[qi].y = fmaf(pq, v4.y, acc[qi].y);
            acc[qi].z = fmaf(pq, v4.z, acc[qi].z);
            acc[qi].w = fmaf(pq, v4.w, acc[qi].w);
        }
    }
    // in-wave reduce over the 4 local ksubs (lanes t^16, t^32 share dq)
    #pragma unroll
    for (int qi = 0; qi < TQ; qi++) {
        #pragma unroll
        for (int off = 16; off <= 32; off <<= 1) {
            acc[qi].x += __shfl_xor(acc[qi].x, off, 64);
            acc[qi].y += __shfl_xor(acc[qi].y, off, 64);
            acc[qi].z += __shfl_xor(acc[qi].z, off, 64);
            acc[qi].w += __shfl_xor(acc[qi].w, off, 64);
        }
    }
    if ((t & 63) < 16) {
        #pragma unroll
        for (int qi = 0; qi < TQ; qi++) {
            red[wave][qi][dq][0] = acc[qi].x;
            red[wave][qi][dq][1] = acc[qi].y;
            red[wave][qi][dq][2] = acc[qi].z;
            red[wave][qi][dq][3] = acc[qi].w;
        }
    }
    __syncthreads();
    if (t < 256) {
        int qi = t >> 6, d = t & 63;
        float sx = 0.f;
        #pragma unroll
        for (int w = 0; w < 6; w++) sx += red[w][qi][d >> 2][d & 3];
        Xh[((size_t)(b * LSEQ + q0 + qi) * NH + h) * 64 + d] = sx;
    }
}

// ---------------------------------------------------------------------------
// Kernel 5: output projection. x[768,512] = Xh @ Wo.T + bo.
// ---------------------------------------------------------------------------
__global__ __launch_bounds__(256) void gemm_out(const float* __restrict__ ws_in,
                                                void* __restrict__ dout,
                                                const int* __restrict__ flag)
{
    const float* Xh = ws_in + OFF_XH;
    const float* Wo = ws_in + OFF_WO;
    const float* bo = ws_in + OFF_BO;

    __shared__ float As[64][17];
    __shared__ float Bs[16][64];

    const int tid = threadIdx.x;
    const int row0 = blockIdx.y * 64;
    const int col0 = blockIdx.x * 64;
    const int ty = tid >> 4, tx = tid & 15;
    const int lm = tid >> 2;
    const int lk = (tid & 3) << 2;
    const int f = *flag;

    float acc[4][4];
    #pragma unroll
    for (int i = 0; i < 4; i++)
        #pragma unroll
        for (int j = 0; j < 4; j++) acc[i][j] = 0.f;

    for (int k0 = 0; k0 < 512; k0 += 16) {
        float4 av = *reinterpret_cast<const float4*>(Xh + (row0 + lm) * 512 + k0 + lk);
        float4 wv = *reinterpret_cast<const float4*>(Wo + (col0 + lm) * 512 + k0 + lk);
        __syncthreads();
        As[lm][lk + 0] = av.x; As[lm][lk + 1] = av.y;
        As[lm][lk + 2] = av.z; As[lm][lk + 3] = av.w;
        Bs[lk + 0][lm] = wv.x; Bs[lk + 1][lm] = wv.y;
        Bs[lk + 2][lm] = wv.z; Bs[lk + 3][lm] = wv.w;
        __syncthreads();
        #pragma unroll
        for (int kk = 0; kk < 16; kk++) {
            float a0 = As[ty * 4 + 0][kk], a1 = As[ty * 4 + 1][kk];
            float a2 = As[ty * 4 + 2][kk], a3 = As[ty * 4 + 3][kk];
            float b0 = Bs[kk][tx * 4 + 0], b1 = Bs[kk][tx * 4 + 1];
            float b2 = Bs[kk][tx * 4 + 2], b3 = Bs[kk][tx * 4 + 3];
            acc[0][0] = fmaf(a0, b0, acc[0][0]); acc[0][1] = fmaf(a0, b1, acc[0][1]);
            acc[0][2] = fmaf(a0, b2, acc[0][2]); acc[0][3] = fmaf(a0, b3, acc[0][3]);
            acc[1][0] = fmaf(a1, b0, acc[1][0]); acc[1][1] = fmaf(a1, b1, acc[1][1]);
            acc[1][2] = fmaf(a1, b2, acc[1][2]); acc[1][3] = fmaf(a1, b3, acc[1][3]);
            acc[2][0] = fmaf(a2, b0, acc[2][0]); acc[2][1] = fmaf(a2, b1, acc[2][1]);
            acc[2][2] = fmaf(a2, b2, acc[2][2]); acc[2][3] = fmaf(a2, b3, acc[2][3]);
            acc[3][0] = fmaf(a3, b0, acc[3][0]); acc[3][1] = fmaf(a3, b1, acc[3][1]);
            acc[3][2] = fmaf(a3, b2, acc[3][2]); acc[3][3] = fmaf(a3, b3, acc[3][3]);
        }
    }

    #pragma unroll
    for (int i = 0; i < 4; i++) {
        int m = row0 + ty * 4 + i;
        #pragma unroll
        for (int j = 0; j < 4; j++) {
            int n = col0 + tx * 4 + j;
            float c = acc[i][j] + bo[n];
            size_t idx = (size_t)m * 512 + n;
            if (f) ((float*)dout)[idx] = c;
            else   ((ushort_t*)dout)[idx] = f2bf(c);
        }
    }
}

// ---------------------------------------------------------------------------
extern "C" void kernel_launch(void* const* d_in, const int* in_sizes, int n_in,
                              void* d_out, int out_size, void* d_ws, size_t ws_size,
                              hipStream_t stream)
{
    const int* mask = (const int*)d_in[3];
    float* ws = (float*)d_ws;
    int* flag = (int*)d_ws;       // ws[0]

    Srcs s;
    const int map[17] = {0,1,2,4,5,6,7,8,9,10,11,12,13,14,15,16,17};
    for (int i = 0; i < 17; i++) s.p[i] = d_in[map[i]];

    detect_dtype<<<1, 256, 0, stream>>>((const unsigned int*)d_in[0], flag);
    convert_inputs<<<2187, 256, 0, stream>>>(s, ws, flag);
    fuse_weights<<<1024, 256, 0, stream>>>(ws, ws);
    gemm_qkv<<<dim3(8, 12, 3), 256, 0, stream>>>(ws, ws);
    attn_kernel<<<BH * QTILES, 384, 0, stream>>>(ws, ws, mask, d_out, flag);
    gemm_out<<<dim3(8, 12, 1), 256, 0, stream>>>(ws, d_out, flag);
}

// Round 4
// 219.359 us; speedup vs baseline: 1.9326x; 1.9326x over previous
//
#include <hip/hip_runtime.h>

// Problem constants
#define BATCH 2
#define LSEQ 384
#define NHID 512
#define NH 8
#define DH 64
#define BH (BATCH*NH)          // 16
#define MROWS (BATCH*LSEQ)     // 768
#define XELEMS ((size_t)MROWS * NHID)      // 393216 (x output elems)
#define TQ 4                   // q-rows per attn block
#define QTILES (LSEQ/TQ)       // 96

typedef unsigned short ushort_t;

__device__ __forceinline__ float bf2f(ushort_t u) {
    unsigned int v = ((unsigned int)u) << 16;
    return __uint_as_float(v);
}
__device__ __forceinline__ ushort_t f2bf(float f) {
    unsigned int u = __float_as_uint(f);
    unsigned int lsb = (u >> 16) & 1u;
    u += 0x7fffu + lsb;           // round-to-nearest-even
    return (ushort_t)(u >> 16);
}
// dual-path loads: f=1 -> fp32, f=0 -> packed bf16 (wave-uniform branch)
__device__ __forceinline__ float ld1(const void* p, size_t i, int f) {
    return f ? ((const float*)p)[i] : bf2f(((const ushort_t*)p)[i]);
}
__device__ __forceinline__ float4 ld4(const void* p, size_t i, int f) {
    if (f) return ((const float4*)p)[i >> 2];
    ushort4 u = ((const ushort4*)p)[i >> 2];
    return make_float4(bf2f(u.x), bf2f(u.y), bf2f(u.z), bf2f(u.w));
}
// per-block dtype vote on first 256 words of query (L1-hot after first block)
__device__ __forceinline__ int block_detect(const unsigned int* q, int* cnt) {
    int t = threadIdx.x;
    if (t == 0) *cnt = 0;
    __syncthreads();
    if (t < 256) {
        unsigned int elo = (q[t] >> 7) & 0xFFu;   // low halfword bf16 exponent
        if (elo >= 100u && elo <= 150u) atomicAdd(cnt, 1);
    }
    __syncthreads();
    return (*cnt > 128) ? 0 : 1;     // 0 = bf16-packed, 1 = fp32
}

// ---------------- workspace layout (float offsets) ----------------
// ws[1] = vbSum (float) produced by fuse_weights
#define OFF_WQE   2238688
#define OFF_WKE   2500832
#define OFF_BQE   2762976
#define OFF_BKE   2763488
#define OFF_TQ    2764000     // Etq = exp(2 tq)  [bh][l][d]
#define OFF_TKT   3157216     // Etk = exp(2 tk)  [bh][d][l]
#define OFF_VH    3550432     // V                [bh][l][d]
#define OFF_XH    3943648     // context [B,L,H,D]
// end = 4336864 floats = 17.35 MB

// ---------------------------------------------------------------------------
// Kernel 1: fold W1 into Wq, W2 into Wk (per-head), scaled by 2 so the QKV
// GEMM emits 2*tq / 2*tk directly. Block 0 also computes vbSum = vb + sum(vw).
// Raw (dual-path) weight loads; W1/W2 rows staged in LDS (block-uniform o).
// ---------------------------------------------------------------------------
__global__ __launch_bounds__(256) void fuse_weights(
    const void* qp,
    const void* Wqp, const void* bqp, const void* Wkp, const void* bkp,
    const void* W1p, const void* b1p, const void* W2p, const void* b2p,
    const void* vwp, const void* vbp, float* __restrict__ ws)
{
    __shared__ int s_cnt;
    __shared__ float W1s[64], W2s[64];
    const int f = block_detect((const unsigned int*)qp, &s_cnt);

    int gid = blockIdx.x * 256 + threadIdx.x;   // 0 .. 512*512-1
    int o = gid >> 9;          // block-uniform output feature (h*64+od)
    int i = gid & 511;
    int h = o >> 6, od = o & 63;

    if (threadIdx.x < 64)  W1s[threadIdx.x] = ld1(W1p, od * 64 + threadIdx.x, f);
    else if (threadIdx.x < 128) W2s[threadIdx.x - 64] = ld1(W2p, od * 64 + threadIdx.x - 64, f);
    __syncthreads();

    float aq = 0.f, ak = 0.f;
    if (f) {
        const float* Wq = (const float*)Wqp;
        const float* Wk = (const float*)Wkp;
        #pragma unroll 8
        for (int j = 0; j < 64; j++) {
            aq = fmaf(W1s[j], Wq[(h * 64 + j) * 512 + i], aq);
            ak = fmaf(W2s[j], Wk[(h * 64 + j) * 512 + i], ak);
        }
    } else {
        const ushort_t* Wq = (const ushort_t*)Wqp;
        const ushort_t* Wk = (const ushort_t*)Wkp;
        #pragma unroll 8
        for (int j = 0; j < 64; j++) {
            aq = fmaf(W1s[j], bf2f(Wq[(h * 64 + j) * 512 + i]), aq);
            ak = fmaf(W2s[j], bf2f(Wk[(h * 64 + j) * 512 + i]), ak);
        }
    }
    ws[OFF_WQE + o * 512 + i] = 2.0f * aq;
    ws[OFF_WKE + o * 512 + i] = 2.0f * ak;

    if (i == 0) {
        float sq = ld1(b1p, od, f), sk = ld1(b2p, od, f);
        for (int j = 0; j < 64; j++) {
            sq = fmaf(W1s[j], ld1(bqp, h * 64 + j, f), sq);
            sk = fmaf(W2s[j], ld1(bkp, h * 64 + j, f), sk);
        }
        ws[OFF_BQE + o] = 2.0f * sq;
        ws[OFF_BKE + o] = 2.0f * sk;
    }
    if (blockIdx.x == 0 && threadIdx.x < 64) {
        float v = ld1(vwp, threadIdx.x, f);
        #pragma unroll
        for (int off = 32; off > 0; off >>= 1) v += __shfl_xor(v, off, 64);
        if (threadIdx.x == 0) ws[1] = ld1(vbp, 0, f) + v;
    }
}

// ---------------------------------------------------------------------------
// Kernel 2: QKV projection GEMM. z=0: Etq=exp(2tq) [bh][l][d];
// z=1: Etk=exp(2tk) transposed [bh][d][l]; z=2: V [bh][l][d].
// A is raw input (dual-path); W fp32 ws for z<2, raw Wv for z=2.
// ---------------------------------------------------------------------------
__global__ __launch_bounds__(256) void gemm_qkv(
    const void* qp, const void* kp, const void* vp,
    const void* Wvp, const void* bvp,
    const float* __restrict__ ws_in, float* __restrict__ ws)
{
    __shared__ int s_cnt;
    const int f = block_detect((const unsigned int*)qp, &s_cnt);

    const int mode = blockIdx.z;
    const void* A     = (mode == 0) ? qp : (mode == 1) ? kp : vp;
    const float* W    = ws_in + ((mode == 0) ? OFF_WQE : OFF_WKE);  // unused for mode 2
    const float* bias = ws_in + ((mode == 0) ? OFF_BQE : OFF_BKE);
    float* Out        = ws    + ((mode == 0) ? OFF_TQ  : (mode == 1) ? OFF_TKT : OFF_VH);

    __shared__ float As[64][17];
    __shared__ float Bs[16][64];

    const int tid = threadIdx.x;
    const int row0 = blockIdx.y * 64;
    const int col0 = blockIdx.x * 64;
    const int ty = tid >> 4, tx = tid & 15;
    const int lm = tid >> 2;
    const int lk = (tid & 3) << 2;

    float acc[4][4];
    #pragma unroll
    for (int i = 0; i < 4; i++)
        #pragma unroll
        for (int j = 0; j < 4; j++) acc[i][j] = 0.f;

    for (int k0 = 0; k0 < 512; k0 += 16) {
        float4 av = ld4(A, (size_t)(row0 + lm) * 512 + k0 + lk, f);
        float4 wv;
        if (mode == 2) wv = ld4(Wvp, (size_t)(col0 + lm) * 512 + k0 + lk, f);
        else           wv = *reinterpret_cast<const float4*>(W + (col0 + lm) * 512 + k0 + lk);
        __syncthreads();
        As[lm][lk + 0] = av.x; As[lm][lk + 1] = av.y;
        As[lm][lk + 2] = av.z; As[lm][lk + 3] = av.w;
        Bs[lk + 0][lm] = wv.x; Bs[lk + 1][lm] = wv.y;
        Bs[lk + 2][lm] = wv.z; Bs[lk + 3][lm] = wv.w;
        __syncthreads();
        #pragma unroll
        for (int kk = 0; kk < 16; kk++) {
            float a0 = As[ty * 4 + 0][kk], a1 = As[ty * 4 + 1][kk];
            float a2 = As[ty * 4 + 2][kk], a3 = As[ty * 4 + 3][kk];
            float b0 = Bs[kk][tx * 4 + 0], b1 = Bs[kk][tx * 4 + 1];
            float b2 = Bs[kk][tx * 4 + 2], b3 = Bs[kk][tx * 4 + 3];
            acc[0][0] = fmaf(a0, b0, acc[0][0]); acc[0][1] = fmaf(a0, b1, acc[0][1]);
            acc[0][2] = fmaf(a0, b2, acc[0][2]); acc[0][3] = fmaf(a0, b3, acc[0][3]);
            acc[1][0] = fmaf(a1, b0, acc[1][0]); acc[1][1] = fmaf(a1, b1, acc[1][1]);
            acc[1][2] = fmaf(a1, b2, acc[1][2]); acc[1][3] = fmaf(a1, b3, acc[1][3]);
            acc[2][0] = fmaf(a2, b0, acc[2][0]); acc[2][1] = fmaf(a2, b1, acc[2][1]);
            acc[2][2] = fmaf(a2, b2, acc[2][2]); acc[2][3] = fmaf(a2, b3, acc[2][3]);
            acc[3][0] = fmaf(a3, b0, acc[3][0]); acc[3][1] = fmaf(a3, b1, acc[3][1]);
            acc[3][2] = fmaf(a3, b2, acc[3][2]); acc[3][3] = fmaf(a3, b3, acc[3][3]);
        }
    }

    #pragma unroll
    for (int i = 0; i < 4; i++) {
        int m = row0 + ty * 4 + i;
        int bb = m / LSEQ, ll = m % LSEQ;
        #pragma unroll
        for (int j = 0; j < 4; j++) {
            int n = col0 + tx * 4 + j;
            float bi = (mode == 2) ? ld1(bvp, n, f) : bias[n];
            float c = acc[i][j] + bi;
            if (mode != 2) c = __expf(c);       // Etq / Etk
            int hh = n >> 6, dd = n & 63;
            int bh = bb * NH + hh;
            size_t off = (mode == 1) ? ((size_t)(bh * 64 + dd) * LSEQ + ll)
                                     : ((size_t)(bh * LSEQ + ll) * 64 + dd);
            Out[off] = c;
        }
    }
}

// ---------------------------------------------------------------------------
// Kernel 3: additive attention, TQ=4 q-rows per block, 384 threads (t = k).
// vw*tanh(tq+tk) = vw - 2*rcp(iw + (Etq*iw)*Etk); e = vbSum - 2*sum_d rcp(..)
// No per-thread arrays -> no spill; launch_bounds caps VGPR at ~84.
// ---------------------------------------------------------------------------
__global__ __launch_bounds__(384, 6) void attn_kernel(
    const void* qp, const void* vwp,
    const float* __restrict__ ws_in, float* __restrict__ ws,
    const int* __restrict__ mask, void* __restrict__ dout)
{
    __shared__ int s_cnt;
    const int f = block_detect((const unsigned int*)qp, &s_cnt);

    const float* Etq = ws_in + OFF_TQ;
    const float* Etk = ws_in + OFF_TKT;
    const float* Vh  = ws_in + OFF_VH;
    float* Xh = ws + OFF_XH;

    const int bid = blockIdx.x;            // bh*QTILES + qt
    const int qt = bid % QTILES;
    const int bh = bid / QTILES;
    const int q0 = qt * TQ;
    const int b  = bh >> 3;
    const int h  = bh & 7;
    const int t  = threadIdx.x;            // 0..383 (= k)
    const int wave = t >> 6;
    const float vbSum = ws_in[1];

    __shared__ float etqT[64][TQ];         // [d][qi], pre-multiplied by iw[d]
    __shared__ float iws[64];
    __shared__ float ps[TQ][LSEQ];
    __shared__ float red[6][TQ][16][4];
    __shared__ float rmax[TQ][6];
    __shared__ float rsum[TQ][6];

    if (t < 256) {
        int d = t & 63, qi = t >> 6;
        float iw = __builtin_amdgcn_rcpf(ld1(vwp, d, f));
        etqT[d][qi] = Etq[(size_t)(bh * LSEQ + q0 + qi) * 64 + d] * iw;
        if (qi == 0) iws[d] = iw;
    }
    const int mok = mask[b * LSEQ + t];
    __syncthreads();

    // ---- energy: one live ekv scalar, no register array ----
    float e2[TQ] = {0.f, 0.f, 0.f, 0.f};
    const float* ekp = Etk + (size_t)bh * 64 * LSEQ + t;
    #pragma unroll 4
    for (int d = 0; d < 64; d++) {
        float ekv = ekp[(size_t)d * LSEQ];
        float4 eq = *reinterpret_cast<const float4*>(&etqT[d][0]);  // LDS broadcast
        float iw = iws[d];
        e2[0] += __builtin_amdgcn_rcpf(fmaf(eq.x, ekv, iw));
        e2[1] += __builtin_amdgcn_rcpf(fmaf(eq.y, ekv, iw));
        e2[2] += __builtin_amdgcn_rcpf(fmaf(eq.z, ekv, iw));
        e2[3] += __builtin_amdgcn_rcpf(fmaf(eq.w, ekv, iw));
    }
    float en[TQ];
    #pragma unroll
    for (int qi = 0; qi < TQ; qi++) {
        en[qi] = fmaf(-2.0f, e2[qi], vbSum);
        if (mok == 0) en[qi] = -1e10f;
    }

    // ---- softmax (block-wide over 6 waves), batched for TQ rows ----
    #pragma unroll
    for (int qi = 0; qi < TQ; qi++) {
        float m = en[qi];
        #pragma unroll
        for (int off = 32; off > 0; off >>= 1) m = fmaxf(m, __shfl_xor(m, off, 64));
        if ((t & 63) == 0) rmax[qi][wave] = m;
    }
    __syncthreads();
    float p[TQ];
    #pragma unroll
    for (int qi = 0; qi < TQ; qi++) {
        float gm = fmaxf(fmaxf(fmaxf(rmax[qi][0], rmax[qi][1]),
                               fmaxf(rmax[qi][2], rmax[qi][3])),
                         fmaxf(rmax[qi][4], rmax[qi][5]));
        p[qi] = __expf(en[qi] - gm);
        float s = p[qi];
        #pragma unroll
        for (int off = 32; off > 0; off >>= 1) s += __shfl_xor(s, off, 64);
        if ((t & 63) == 0) rsum[qi][wave] = s;
    }
    __syncthreads();
    #pragma unroll
    for (int qi = 0; qi < TQ; qi++) {
        float gs = rsum[qi][0] + rsum[qi][1] + rsum[qi][2] +
                   rsum[qi][3] + rsum[qi][4] + rsum[qi][5];
        p[qi] *= 1.0f / gs;
        ps[qi][t] = p[qi];
        size_t aidx = XELEMS + (size_t)(bh * LSEQ + q0 + qi) * LSEQ + t;
        if (f) ((float*)dout)[aidx] = p[qi];
        else   ((ushort_t*)dout)[aidx] = f2bf(p[qi]);
    }
    __syncthreads();

    // ---- context: x[qi][d] = sum_k p[k] V[k][d]; float4 V reused across qi ----
    const int dq = t & 15;                 // d-quad: d = dq*4 .. dq*4+3
    const int ksub = t >> 4;               // 0..23
    const float* vb4 = Vh + (size_t)bh * LSEQ * 64 + dq * 4;
    float4 acc[TQ];
    #pragma unroll
    for (int qi = 0; qi < TQ; qi++) acc[qi] = make_float4(0.f, 0.f, 0.f, 0.f);
    for (int kk = ksub; kk < LSEQ; kk += 24) {
        float4 v4 = *reinterpret_cast<const float4*>(vb4 + (size_t)kk * 64);
        #pragma unroll
        for (int qi = 0; qi < TQ; qi++) {
            float pq = ps[qi][kk];
            acc[qi].x = fmaf(pq, v4.x, acc[qi].x);
            acc[qi].y = fmaf(pq, v4.y, acc[qi].y);
            acc[qi].z = fmaf(pq, v4.z, acc[qi].z);
            acc[qi].w = fmaf(pq, v4.w, acc[qi].w);
        }
    }
    #pragma unroll
    for (int qi = 0; qi < TQ; qi++) {
        #pragma unroll
        for (int off = 16; off <= 32; off <<= 1) {
            acc[qi].x += __shfl_xor(acc[qi].x, off, 64);
            acc[qi].y += __shfl_xor(acc[qi].y, off, 64);
            acc[qi].z += __shfl_xor(acc[qi].z, off, 64);
            acc[qi].w += __shfl_xor(acc[qi].w, off, 64);
        }
    }
    if ((t & 63) < 16) {
        #pragma unroll
        for (int qi = 0; qi < TQ; qi++) {
            red[wave][qi][dq][0] = acc[qi].x;
            red[wave][qi][dq][1] = acc[qi].y;
            red[wave][qi][dq][2] = acc[qi].z;
            red[wave][qi][dq][3] = acc[qi].w;
        }
    }
    __syncthreads();
    if (t < 256) {
        int qi = t >> 6, d = t & 63;
        float sx = 0.f;
        #pragma unroll
        for (int w = 0; w < 6; w++) sx += red[w][qi][d >> 2][d & 3];
        Xh[((size_t)(b * LSEQ + q0 + qi) * NH + h) * 64 + d] = sx;
    }
}

// ---------------------------------------------------------------------------
// Kernel 4: output projection. x[768,512] = Xh @ Wo.T + bo (Wo/bo raw dual).
// ---------------------------------------------------------------------------
__global__ __launch_bounds__(256) void gemm_out(
    const void* qp, const void* Wop, const void* bop,
    const float* __restrict__ ws_in, void* __restrict__ dout)
{
    __shared__ int s_cnt;
    const int f = block_detect((const unsigned int*)qp, &s_cnt);

    const float* Xh = ws_in + OFF_XH;

    __shared__ float As[64][17];
    __shared__ float Bs[16][64];

    const int tid = threadIdx.x;
    const int row0 = blockIdx.y * 64;
    const int col0 = blockIdx.x * 64;
    const int ty = tid >> 4, tx = tid & 15;
    const int lm = tid >> 2;
    const int lk = (tid & 3) << 2;

    float acc[4][4];
    #pragma unroll
    for (int i = 0; i < 4; i++)
        #pragma unroll
        for (int j = 0; j < 4; j++) acc[i][j] = 0.f;

    for (int k0 = 0; k0 < 512; k0 += 16) {
        float4 av = *reinterpret_cast<const float4*>(Xh + (row0 + lm) * 512 + k0 + lk);
        float4 wv = ld4(Wop, (size_t)(col0 + lm) * 512 + k0 + lk, f);
        __syncthreads();
        As[lm][lk + 0] = av.x; As[lm][lk + 1] = av.y;
        As[lm][lk + 2] = av.z; As[lm][lk + 3] = av.w;
        Bs[lk + 0][lm] = wv.x; Bs[lk + 1][lm] = wv.y;
        Bs[lk + 2][lm] = wv.z; Bs[lk + 3][lm] = wv.w;
        __syncthreads();
        #pragma unroll
        for (int kk = 0; kk < 16; kk++) {
            float a0 = As[ty * 4 + 0][kk], a1 = As[ty * 4 + 1][kk];
            float a2 = As[ty * 4 + 2][kk], a3 = As[ty * 4 + 3][kk];
            float b0 = Bs[kk][tx * 4 + 0], b1 = Bs[kk][tx * 4 + 1];
            float b2 = Bs[kk][tx * 4 + 2], b3 = Bs[kk][tx * 4 + 3];
            acc[0][0] = fmaf(a0, b0, acc[0][0]); acc[0][1] = fmaf(a0, b1, acc[0][1]);
            acc[0][2] = fmaf(a0, b2, acc[0][2]); acc[0][3] = fmaf(a0, b3, acc[0][3]);
            acc[1][0] = fmaf(a1, b0, acc[1][0]); acc[1][1] = fmaf(a1, b1, acc[1][1]);
            acc[1][2] = fmaf(a1, b2, acc[1][2]); acc[1][3] = fmaf(a1, b3, acc[1][3]);
            acc[2][0] = fmaf(a2, b0, acc[2][0]); acc[2][1] = fmaf(a2, b1, acc[2][1]);
            acc[2][2] = fmaf(a2, b2, acc[2][2]); acc[2][3] = fmaf(a2, b3, acc[2][3]);
            acc[3][0] = fmaf(a3, b0, acc[3][0]); acc[3][1] = fmaf(a3, b1, acc[3][1]);
            acc[3][2] = fmaf(a3, b2, acc[3][2]); acc[3][3] = fmaf(a3, b3, acc[3][3]);
        }
    }

    #pragma unroll
    for (int i = 0; i < 4; i++) {
        int m = row0 + ty * 4 + i;
        #pragma unroll
        for (int j = 0; j < 4; j++) {
            int n = col0 + tx * 4 + j;
            float c = acc[i][j] + ld1(bop, n, f);
            size_t idx = (size_t)m * 512 + n;
            if (f) ((float*)dout)[idx] = c;
            else   ((ushort_t*)dout)[idx] = f2bf(c);
        }
    }
}

// ---------------------------------------------------------------------------
extern "C" void kernel_launch(void* const* d_in, const int* in_sizes, int n_in,
                              void* d_out, int out_size, void* d_ws, size_t ws_size,
                              hipStream_t stream)
{
    const void* qp = d_in[0];
    const void* kp = d_in[1];
    const void* vp = d_in[2];
    const int* mask = (const int*)d_in[3];
    const void* Wqp = d_in[4];  const void* bqp = d_in[5];
    const void* Wkp = d_in[6];  const void* bkp = d_in[7];
    const void* Wvp = d_in[8];  const void* bvp = d_in[9];
    const void* Wop = d_in[10]; const void* bop = d_in[11];
    const void* W1p = d_in[12]; const void* b1p = d_in[13];
    const void* W2p = d_in[14]; const void* b2p = d_in[15];
    const void* vwp = d_in[16]; const void* vbp = d_in[17];

    float* ws = (float*)d_ws;

    fuse_weights<<<1024, 256, 0, stream>>>(qp, Wqp, bqp, Wkp, bkp,
                                           W1p, b1p, W2p, b2p, vwp, vbp, ws);
    gemm_qkv<<<dim3(8, 12, 3), 256, 0, stream>>>(qp, kp, vp, Wvp, bvp, ws, ws);
    attn_kernel<<<BH * QTILES, 384, 0, stream>>>(qp, vwp, ws, ws, mask, d_out);
    gemm_out<<<dim3(8, 12, 1), 256, 0, stream>>>(qp, Wop, bop, ws, d_out);
}

// Round 5
// 203.195 us; speedup vs baseline: 2.0863x; 1.0795x over previous
//
#include <hip/hip_runtime.h>

// Problem constants
#define BATCH 2
#define LSEQ 384
#define NHID 512
#define NH 8
#define DH 64
#define BH (BATCH*NH)          // 16
#define MROWS (BATCH*LSEQ)     // 768
#define XELEMS ((size_t)MROWS * NHID)      // 393216 (x output elems)
#define TQ 4                   // q-rows per attn block
#define QTILES (LSEQ/TQ)       // 96

typedef unsigned short ushort_t;

__device__ __forceinline__ float bf2f(ushort_t u) {
    unsigned int v = ((unsigned int)u) << 16;
    return __uint_as_float(v);
}
__device__ __forceinline__ ushort_t f2bf(float f) {
    unsigned int u = __float_as_uint(f);
    unsigned int lsb = (u >> 16) & 1u;
    u += 0x7fffu + lsb;           // round-to-nearest-even
    return (ushort_t)(u >> 16);
}
// dual-path loads: f=1 -> fp32, f=0 -> packed bf16 (wave-uniform branch)
__device__ __forceinline__ float ld1(const void* p, size_t i, int f) {
    return f ? ((const float*)p)[i] : bf2f(((const ushort_t*)p)[i]);
}
__device__ __forceinline__ float4 ld4(const void* p, size_t i, int f) {
    if (f) return ((const float4*)p)[i >> 2];
    ushort4 u = ((const ushort4*)p)[i >> 2];
    return make_float4(bf2f(u.x), bf2f(u.y), bf2f(u.z), bf2f(u.w));
}
// per-block dtype vote (works for any blockDim >= 64)
__device__ __forceinline__ int block_detect(const unsigned int* q, int* cnt) {
    int t = threadIdx.x;
    if (t == 0) *cnt = 0;
    __syncthreads();
    int n = blockDim.x < 256 ? blockDim.x : 256;
    if (t < n) {
        unsigned int elo = (q[t] >> 7) & 0xFFu;   // low halfword bf16 exponent
        if (elo >= 100u && elo <= 150u) atomicAdd(cnt, 1);
    }
    __syncthreads();
    return (*cnt * 2 > n) ? 0 : 1;     // 0 = bf16-packed, 1 = fp32
}

// ---------------- workspace layout (float offsets) ----------------
// ws[1] = vbSum (float) produced by fuse_weights
#define OFF_WQE   2238688
#define OFF_WKE   2500832
#define OFF_BQE   2762976
#define OFF_BKE   2763488
#define OFF_TQ    2764000     // Etq = exp(2 tq)  [bh][l][d]
#define OFF_TKT   3157216     // Etk = exp(2 tk)  [bh][d][l]
#define OFF_VH    3550432     // V                [bh][l][d]
#define OFF_XH    3943648     // context [B,L,H,D]
// end = 4336864 floats = 17.35 MB

// 16-FMA microtile step
#define MICRO_FMA(a, b)                                                  \
    acc[0][0] = fmaf(a.x, b.x, acc[0][0]); acc[0][1] = fmaf(a.x, b.y, acc[0][1]); \
    acc[0][2] = fmaf(a.x, b.z, acc[0][2]); acc[0][3] = fmaf(a.x, b.w, acc[0][3]); \
    acc[1][0] = fmaf(a.y, b.x, acc[1][0]); acc[1][1] = fmaf(a.y, b.y, acc[1][1]); \
    acc[1][2] = fmaf(a.y, b.z, acc[1][2]); acc[1][3] = fmaf(a.y, b.w, acc[1][3]); \
    acc[2][0] = fmaf(a.z, b.x, acc[2][0]); acc[2][1] = fmaf(a.z, b.y, acc[2][1]); \
    acc[2][2] = fmaf(a.z, b.z, acc[2][2]); acc[2][3] = fmaf(a.z, b.w, acc[2][3]); \
    acc[3][0] = fmaf(a.w, b.x, acc[3][0]); acc[3][1] = fmaf(a.w, b.y, acc[3][1]); \
    acc[3][2] = fmaf(a.w, b.z, acc[3][2]); acc[3][3] = fmaf(a.w, b.w, acc[3][3])

// ---------------------------------------------------------------------------
// Kernel 1: fuse_weights — WqE = 2*(W1@Wq) [512,512], WkE = 2*(W2@Wk),
// as an LDS-tiled GEMM over K=64. grid (8 n-tiles, 16 m-tiles, 2), 128 thr.
// n-tile-0 blocks also compute fused biases; block(0,0,0) computes vbSum.
// ---------------------------------------------------------------------------
__global__ __launch_bounds__(128) void fuse_weights(
    const void* qp,
    const void* Wqp, const void* bqp, const void* Wkp, const void* bkp,
    const void* W1p, const void* b1p, const void* W2p, const void* b2p,
    const void* vwp, const void* vbp, float* __restrict__ ws)
{
    __shared__ int s_cnt;
    __shared__ __align__(16) float As[32][36];   // [k][m]
    __shared__ __align__(16) float Bs[32][68];   // [k][n]
    const int f = block_detect((const unsigned int*)qp, &s_cnt);

    const int z = blockIdx.z;                 // 0 = q, 1 = k
    const void* W1x = z ? W2p : W1p;
    const void* Wx  = z ? Wkp : Wqp;
    float* OutW = ws + (z ? OFF_WKE : OFF_WQE);

    const int row0 = blockIdx.y * 32;         // o-range (one h since 64|row0*2)
    const int col0 = blockIdx.x * 64;         // i-range
    const int h   = row0 >> 6;
    const int od0 = row0 & 63;
    const int tid = threadIdx.x;

    const int alr = tid >> 2, alc = tid & 3;  // A: 32 rows x 8 f4-cols, 2 each
    const int bkr = tid >> 2, bkc = tid & 3;  // B: 32 k-rows x 16 f4-cols, 4 each
    const int tm = tid >> 4, tn = tid & 15;

    float acc[4][4];
    #pragma unroll
    for (int i = 0; i < 4; i++)
        #pragma unroll
        for (int j = 0; j < 4; j++) acc[i][j] = 0.f;

    for (int k0 = 0; k0 < 64; k0 += 32) {
        // A = W1x[od][j], row stride 64
        float4 a0 = ld4(W1x, (size_t)(od0 + alr) * 64 + k0 + alc * 4, f);
        float4 a1 = ld4(W1x, (size_t)(od0 + alr) * 64 + k0 + (alc + 4) * 4, f);
        // B = Wx[(h*64 + k)][i] — already k-major, direct stores
        float4 b0 = ld4(Wx, (size_t)(h * 64 + k0 + bkr) * 512 + col0 + (bkc +  0) * 4, f);
        float4 b1 = ld4(Wx, (size_t)(h * 64 + k0 + bkr) * 512 + col0 + (bkc +  4) * 4, f);
        float4 b2 = ld4(Wx, (size_t)(h * 64 + k0 + bkr) * 512 + col0 + (bkc +  8) * 4, f);
        float4 b3 = ld4(Wx, (size_t)(h * 64 + k0 + bkr) * 512 + col0 + (bkc + 12) * 4, f);
        __syncthreads();
        As[alc * 4 + 0][alr] = a0.x; As[alc * 4 + 1][alr] = a0.y;
        As[alc * 4 + 2][alr] = a0.z; As[alc * 4 + 3][alr] = a0.w;
        As[(alc + 4) * 4 + 0][alr] = a1.x; As[(alc + 4) * 4 + 1][alr] = a1.y;
        As[(alc + 4) * 4 + 2][alr] = a1.z; As[(alc + 4) * 4 + 3][alr] = a1.w;
        *reinterpret_cast<float4*>(&Bs[bkr][(bkc +  0) * 4]) = b0;
        *reinterpret_cast<float4*>(&Bs[bkr][(bkc +  4) * 4]) = b1;
        *reinterpret_cast<float4*>(&Bs[bkr][(bkc +  8) * 4]) = b2;
        *reinterpret_cast<float4*>(&Bs[bkr][(bkc + 12) * 4]) = b3;
        __syncthreads();
        #pragma unroll
        for (int kk = 0; kk < 32; kk++) {
            float4 a = *reinterpret_cast<const float4*>(&As[kk][tm * 4]);
            float4 b = *reinterpret_cast<const float4*>(&Bs[kk][tn * 4]);
            MICRO_FMA(a, b);
        }
    }

    #pragma unroll
    for (int i = 0; i < 4; i++) {
        int o = row0 + tm * 4 + i;
        #pragma unroll
        for (int j = 0; j < 4; j++)
            OutW[(size_t)o * 512 + col0 + tn * 4 + j] = 2.0f * acc[i][j];
    }

    // fused biases (n-tile 0 only): bE[o] = 2*(b1x[od] + sum_j W1x[od][j]*bx[h*64+j])
    if (blockIdx.x == 0 && tid < 32) {
        int o = row0 + tid, od = o & 63;
        const void* b1x = z ? b2p : b1p;
        const void* bx  = z ? bkp : bqp;
        float s = ld1(b1x, od, f);
        for (int j = 0; j < 64; j++)
            s = fmaf(ld1(W1x, od * 64 + j, f), ld1(bx, h * 64 + j, f), s);
        ws[(z ? OFF_BKE : OFF_BQE) + o] = 2.0f * s;
    }
    if (blockIdx.x == 0 && blockIdx.y == 0 && z == 0 && tid < 64) {
        float v = ld1(vwp, tid, f);
        #pragma unroll
        for (int off = 32; off > 0; off >>= 1) v += __shfl_xor(v, off, 64);
        if (tid == 0) ws[1] = ld1(vbp, 0, f) + v;
    }
}

// ---------------------------------------------------------------------------
// Kernel 2: QKV GEMM, 32(m)x64(n) tile, 128 thr, K-tile 32, reg prefetch.
// z=0: Etq=exp(2tq) [bh][l][d]; z=1: Etk transposed [bh][d][l]; z=2: V.
// ---------------------------------------------------------------------------
__global__ __launch_bounds__(128) void gemm_qkv(
    const void* qp, const void* kp, const void* vp,
    const void* Wvp, const void* bvp,
    const float* __restrict__ ws_in, float* __restrict__ ws)
{
    __shared__ int s_cnt;
    __shared__ __align__(16) float As[32][36];
    __shared__ __align__(16) float Bs[32][68];
    const int f = block_detect((const unsigned int*)qp, &s_cnt);

    const int mode = blockIdx.z;
    const void* A  = (mode == 0) ? qp : (mode == 1) ? kp : vp;
    const float* W = ws_in + ((mode == 0) ? OFF_WQE : OFF_WKE);
    float* Out     = ws + ((mode == 0) ? OFF_TQ : (mode == 1) ? OFF_TKT : OFF_VH);

    const int row0 = blockIdx.y * 32;
    const int col0 = blockIdx.x * 64;
    const int tid = threadIdx.x;

    const int alr = tid >> 2, alc = tid & 3;   // A: 32r x 8 f4c, 2 each
    const int blr = tid >> 1, blc = tid & 1;   // B: 64r x 8 f4c, 4 each
    const int tm = tid >> 4, tn = tid & 15;

    const size_t abase = (size_t)(row0 + alr) * 512;
    const size_t bbase = (size_t)(col0 + blr) * 512;

    float4 a0, a1, b0, b1, b2, b3;
    {
        a0 = ld4(A, abase + alc * 4, f);
        a1 = ld4(A, abase + (alc + 4) * 4, f);
        if (mode == 2) {
            b0 = ld4(Wvp, bbase + (blc + 0) * 4, f);
            b1 = ld4(Wvp, bbase + (blc + 2) * 4, f);
            b2 = ld4(Wvp, bbase + (blc + 4) * 4, f);
            b3 = ld4(Wvp, bbase + (blc + 6) * 4, f);
        } else {
            const float* Wb = W + bbase;
            b0 = *reinterpret_cast<const float4*>(Wb + (blc + 0) * 4);
            b1 = *reinterpret_cast<const float4*>(Wb + (blc + 2) * 4);
            b2 = *reinterpret_cast<const float4*>(Wb + (blc + 4) * 4);
            b3 = *reinterpret_cast<const float4*>(Wb + (blc + 6) * 4);
        }
    }

    float acc[4][4];
    #pragma unroll
    for (int i = 0; i < 4; i++)
        #pragma unroll
        for (int j = 0; j < 4; j++) acc[i][j] = 0.f;

    for (int k0 = 0; k0 < 512; k0 += 32) {
        __syncthreads();
        As[alc * 4 + 0][alr] = a0.x; As[alc * 4 + 1][alr] = a0.y;
        As[alc * 4 + 2][alr] = a0.z; As[alc * 4 + 3][alr] = a0.w;
        As[(alc + 4) * 4 + 0][alr] = a1.x; As[(alc + 4) * 4 + 1][alr] = a1.y;
        As[(alc + 4) * 4 + 2][alr] = a1.z; As[(alc + 4) * 4 + 3][alr] = a1.w;
        Bs[(blc + 0) * 4 + 0][blr] = b0.x; Bs[(blc + 0) * 4 + 1][blr] = b0.y;
        Bs[(blc + 0) * 4 + 2][blr] = b0.z; Bs[(blc + 0) * 4 + 3][blr] = b0.w;
        Bs[(blc + 2) * 4 + 0][blr] = b1.x; Bs[(blc + 2) * 4 + 1][blr] = b1.y;
        Bs[(blc + 2) * 4 + 2][blr] = b1.z; Bs[(blc + 2) * 4 + 3][blr] = b1.w;
        Bs[(blc + 4) * 4 + 0][blr] = b2.x; Bs[(blc + 4) * 4 + 1][blr] = b2.y;
        Bs[(blc + 4) * 4 + 2][blr] = b2.z; Bs[(blc + 4) * 4 + 3][blr] = b2.w;
        Bs[(blc + 6) * 4 + 0][blr] = b3.x; Bs[(blc + 6) * 4 + 1][blr] = b3.y;
        Bs[(blc + 6) * 4 + 2][blr] = b3.z; Bs[(blc + 6) * 4 + 3][blr] = b3.w;
        __syncthreads();
        int k1 = k0 + 32;
        if (k1 < 512) {                      // prefetch next K-tile
            a0 = ld4(A, abase + k1 + alc * 4, f);
            a1 = ld4(A, abase + k1 + (alc + 4) * 4, f);
            if (mode == 2) {
                b0 = ld4(Wvp, bbase + k1 + (blc + 0) * 4, f);
                b1 = ld4(Wvp, bbase + k1 + (blc + 2) * 4, f);
                b2 = ld4(Wvp, bbase + k1 + (blc + 4) * 4, f);
                b3 = ld4(Wvp, bbase + k1 + (blc + 6) * 4, f);
            } else {
                const float* Wb = W + bbase + k1;
                b0 = *reinterpret_cast<const float4*>(Wb + (blc + 0) * 4);
                b1 = *reinterpret_cast<const float4*>(Wb + (blc + 2) * 4);
                b2 = *reinterpret_cast<const float4*>(Wb + (blc + 4) * 4);
                b3 = *reinterpret_cast<const float4*>(Wb + (blc + 6) * 4);
            }
        }
        #pragma unroll
        for (int kk = 0; kk < 32; kk++) {
            float4 a = *reinterpret_cast<const float4*>(&As[kk][tm * 4]);
            float4 b = *reinterpret_cast<const float4*>(&Bs[kk][tn * 4]);
            MICRO_FMA(a, b);
        }
    }

    #pragma unroll
    for (int i = 0; i < 4; i++) {
        int m = row0 + tm * 4 + i;
        int bb = m / LSEQ, ll = m % LSEQ;
        #pragma unroll
        for (int j = 0; j < 4; j++) {
            int n = col0 + tn * 4 + j;
            float bi = (mode == 2) ? ld1(bvp, n, f) : ws_in[(mode == 0 ? OFF_BQE : OFF_BKE) + n];
            float c = acc[i][j] + bi;
            if (mode != 2) c = __expf(c);       // Etq / Etk
            int hh = n >> 6, dd = n & 63;
            int bh = bb * NH + hh;
            size_t off = (mode == 1) ? ((size_t)(bh * 64 + dd) * LSEQ + ll)
                                     : ((size_t)(bh * LSEQ + ll) * 64 + dd);
            Out[off] = c;
        }
    }
}

// ---------------------------------------------------------------------------
// Kernel 3: additive attention, TQ=4 q-rows per block, 384 threads (t = k).
// vw*tanh(tq+tk) = vw - 2*rcp(iw + (Etq*iw)*Etk); e = vbSum - 2*sum_d rcp(..)
// ---------------------------------------------------------------------------
__global__ __launch_bounds__(384, 6) void attn_kernel(
    const void* qp, const void* vwp,
    const float* __restrict__ ws_in, float* __restrict__ ws,
    const int* __restrict__ mask, void* __restrict__ dout)
{
    __shared__ int s_cnt;
    const int f = block_detect((const unsigned int*)qp, &s_cnt);

    const float* Etq = ws_in + OFF_TQ;
    const float* Etk = ws_in + OFF_TKT;
    const float* Vh  = ws_in + OFF_VH;
    float* Xh = ws + OFF_XH;

    const int bid = blockIdx.x;            // bh*QTILES + qt
    const int qt = bid % QTILES;
    const int bh = bid / QTILES;
    const int q0 = qt * TQ;
    const int b  = bh >> 3;
    const int h  = bh & 7;
    const int t  = threadIdx.x;            // 0..383 (= k)
    const int wave = t >> 6;
    const float vbSum = ws_in[1];

    __shared__ __align__(16) float etqT[64][TQ];  // [d][qi], pre-mult by iw[d]
    __shared__ float iws[64];
    __shared__ float ps[TQ][LSEQ];
    __shared__ float red[6][TQ][16][4];
    __shared__ float rmax[TQ][6];
    __shared__ float rsum[TQ][6];

    if (t < 256) {
        int d = t & 63, qi = t >> 6;
        float iw = __builtin_amdgcn_rcpf(ld1(vwp, d, f));
        etqT[d][qi] = Etq[(size_t)(bh * LSEQ + q0 + qi) * 64 + d] * iw;
        if (qi == 0) iws[d] = iw;
    }
    const int mok = mask[b * LSEQ + t];
    __syncthreads();

    // ---- energy: one live ekv scalar, no register array ----
    float e2[TQ] = {0.f, 0.f, 0.f, 0.f};
    const float* ekp = Etk + (size_t)bh * 64 * LSEQ + t;
    #pragma unroll 4
    for (int d = 0; d < 64; d++) {
        float ekv = ekp[(size_t)d * LSEQ];
        float4 eq = *reinterpret_cast<const float4*>(&etqT[d][0]);  // LDS broadcast
        float iw = iws[d];
        e2[0] += __builtin_amdgcn_rcpf(fmaf(eq.x, ekv, iw));
        e2[1] += __builtin_amdgcn_rcpf(fmaf(eq.y, ekv, iw));
        e2[2] += __builtin_amdgcn_rcpf(fmaf(eq.z, ekv, iw));
        e2[3] += __builtin_amdgcn_rcpf(fmaf(eq.w, ekv, iw));
    }
    float en[TQ];
    #pragma unroll
    for (int qi = 0; qi < TQ; qi++) {
        en[qi] = fmaf(-2.0f, e2[qi], vbSum);
        if (mok == 0) en[qi] = -1e10f;
    }

    // ---- softmax (block-wide over 6 waves), batched for TQ rows ----
    #pragma unroll
    for (int qi = 0; qi < TQ; qi++) {
        float m = en[qi];
        #pragma unroll
        for (int off = 32; off > 0; off >>= 1) m = fmaxf(m, __shfl_xor(m, off, 64));
        if ((t & 63) == 0) rmax[qi][wave] = m;
    }
    __syncthreads();
    float p[TQ];
    #pragma unroll
    for (int qi = 0; qi < TQ; qi++) {
        float gm = fmaxf(fmaxf(fmaxf(rmax[qi][0], rmax[qi][1]),
                               fmaxf(rmax[qi][2], rmax[qi][3])),
                         fmaxf(rmax[qi][4], rmax[qi][5]));
        p[qi] = __expf(en[qi] - gm);
        float s = p[qi];
        #pragma unroll
        for (int off = 32; off > 0; off >>= 1) s += __shfl_xor(s, off, 64);
        if ((t & 63) == 0) rsum[qi][wave] = s;
    }
    __syncthreads();
    #pragma unroll
    for (int qi = 0; qi < TQ; qi++) {
        float gs = rsum[qi][0] + rsum[qi][1] + rsum[qi][2] +
                   rsum[qi][3] + rsum[qi][4] + rsum[qi][5];
        p[qi] *= 1.0f / gs;
        ps[qi][t] = p[qi];
        size_t aidx = XELEMS + (size_t)(bh * LSEQ + q0 + qi) * LSEQ + t;
        if (f) ((float*)dout)[aidx] = p[qi];
        else   ((ushort_t*)dout)[aidx] = f2bf(p[qi]);
    }
    __syncthreads();

    // ---- context: x[qi][d] = sum_k p[k] V[k][d]; float4 V reused across qi ----
    const int dq = t & 15;
    const int ksub = t >> 4;               // 0..23
    const float* vb4 = Vh + (size_t)bh * LSEQ * 64 + dq * 4;
    float4 acc[TQ];
    #pragma unroll
    for (int qi = 0; qi < TQ; qi++) acc[qi] = make_float4(0.f, 0.f, 0.f, 0.f);
    for (int kk = ksub; kk < LSEQ; kk += 24) {
        float4 v4 = *reinterpret_cast<const float4*>(vb4 + (size_t)kk * 64);
        #pragma unroll
        for (int qi = 0; qi < TQ; qi++) {
            float pq = ps[qi][kk];
            acc[qi].x = fmaf(pq, v4.x, acc[qi].x);
            acc[qi].y = fmaf(pq, v4.y, acc[qi].y);
            acc[qi].z = fmaf(pq, v4.z, acc[qi].z);
            acc[qi].w = fmaf(pq, v4.w, acc[qi].w);
        }
    }
    #pragma unroll
    for (int qi = 0; qi < TQ; qi++) {
        #pragma unroll
        for (int off = 16; off <= 32; off <<= 1) {
            acc[qi].x += __shfl_xor(acc[qi].x, off, 64);
            acc[qi].y += __shfl_xor(acc[qi].y, off, 64);
            acc[qi].z += __shfl_xor(acc[qi].z, off, 64);
            acc[qi].w += __shfl_xor(acc[qi].w, off, 64);
        }
    }
    if ((t & 63) < 16) {
        #pragma unroll
        for (int qi = 0; qi < TQ; qi++) {
            red[wave][qi][dq][0] = acc[qi].x;
            red[wave][qi][dq][1] = acc[qi].y;
            red[wave][qi][dq][2] = acc[qi].z;
            red[wave][qi][dq][3] = acc[qi].w;
        }
    }
    __syncthreads();
    if (t < 256) {
        int qi = t >> 6, d = t & 63;
        float sx = 0.f;
        #pragma unroll
        for (int w = 0; w < 6; w++) sx += red[w][qi][d >> 2][d & 3];
        Xh[((size_t)(b * LSEQ + q0 + qi) * NH + h) * 64 + d] = sx;
    }
}

// ---------------------------------------------------------------------------
// Kernel 4: output projection, same 32x64 prefetch tile. x = Xh @ Wo.T + bo.
// ---------------------------------------------------------------------------
__global__ __launch_bounds__(128) void gemm_out(
    const void* qp, const void* Wop, const void* bop,
    const float* __restrict__ ws_in, void* __restrict__ dout)
{
    __shared__ int s_cnt;
    __shared__ __align__(16) float As[32][36];
    __shared__ __align__(16) float Bs[32][68];
    const int f = block_detect((const unsigned int*)qp, &s_cnt);

    const float* Xh = ws_in + OFF_XH;
    const int row0 = blockIdx.y * 32;
    const int col0 = blockIdx.x * 64;
    const int tid = threadIdx.x;

    const int alr = tid >> 2, alc = tid & 3;
    const int blr = tid >> 1, blc = tid & 1;
    const int tm = tid >> 4, tn = tid & 15;

    const float* Ab = Xh + (size_t)(row0 + alr) * 512;
    const size_t bbase = (size_t)(col0 + blr) * 512;

    float4 a0, a1, b0, b1, b2, b3;
    a0 = *reinterpret_cast<const float4*>(Ab + alc * 4);
    a1 = *reinterpret_cast<const float4*>(Ab + (alc + 4) * 4);
    b0 = ld4(Wop, bbase + (blc + 0) * 4, f);
    b1 = ld4(Wop, bbase + (blc + 2) * 4, f);
    b2 = ld4(Wop, bbase + (blc + 4) * 4, f);
    b3 = ld4(Wop, bbase + (blc + 6) * 4, f);

    float acc[4][4];
    #pragma unroll
    for (int i = 0; i < 4; i++)
        #pragma unroll
        for (int j = 0; j < 4; j++) acc[i][j] = 0.f;

    for (int k0 = 0; k0 < 512; k0 += 32) {
        __syncthreads();
        As[alc * 4 + 0][alr] = a0.x; As[alc * 4 + 1][alr] = a0.y;
        As[alc * 4 + 2][alr] = a0.z; As[alc * 4 + 3][alr] = a0.w;
        As[(alc + 4) * 4 + 0][alr] = a1.x; As[(alc + 4) * 4 + 1][alr] = a1.y;
        As[(alc + 4) * 4 + 2][alr] = a1.z; As[(alc + 4) * 4 + 3][alr] = a1.w;
        Bs[(blc + 0) * 4 + 0][blr] = b0.x; Bs[(blc + 0) * 4 + 1][blr] = b0.y;
        Bs[(blc + 0) * 4 + 2][blr] = b0.z; Bs[(blc + 0) * 4 + 3][blr] = b0.w;
        Bs[(blc + 2) * 4 + 0][blr] = b1.x; Bs[(blc + 2) * 4 + 1][blr] = b1.y;
        Bs[(blc + 2) * 4 + 2][blr] = b1.z; Bs[(blc + 2) * 4 + 3][blr] = b1.w;
        Bs[(blc + 4) * 4 + 0][blr] = b2.x; Bs[(blc + 4) * 4 + 1][blr] = b2.y;
        Bs[(blc + 4) * 4 + 2][blr] = b2.z; Bs[(blc + 4) * 4 + 3][blr] = b2.w;
        Bs[(blc + 6) * 4 + 0][blr] = b3.x; Bs[(blc + 6) * 4 + 1][blr] = b3.y;
        Bs[(blc + 6) * 4 + 2][blr] = b3.z; Bs[(blc + 6) * 4 + 3][blr] = b3.w;
        __syncthreads();
        int k1 = k0 + 32;
        if (k1 < 512) {
            a0 = *reinterpret_cast<const float4*>(Ab + k1 + alc * 4);
            a1 = *reinterpret_cast<const float4*>(Ab + k1 + (alc + 4) * 4);
            b0 = ld4(Wop, bbase + k1 + (blc + 0) * 4, f);
            b1 = ld4(Wop, bbase + k1 + (blc + 2) * 4, f);
            b2 = ld4(Wop, bbase + k1 + (blc + 4) * 4, f);
            b3 = ld4(Wop, bbase + k1 + (blc + 6) * 4, f);
        }
        #pragma unroll
        for (int kk = 0; kk < 32; kk++) {
            float4 a = *reinterpret_cast<const float4*>(&As[kk][tm * 4]);
            float4 b = *reinterpret_cast<const float4*>(&Bs[kk][tn * 4]);
            MICRO_FMA(a, b);
        }
    }

    #pragma unroll
    for (int i = 0; i < 4; i++) {
        int m = row0 + tm * 4 + i;
        #pragma unroll
        for (int j = 0; j < 4; j++) {
            int n = col0 + tn * 4 + j;
            float c = acc[i][j] + ld1(bop, n, f);
            size_t idx = (size_t)m * 512 + n;
            if (f) ((float*)dout)[idx] = c;
            else   ((ushort_t*)dout)[idx] = f2bf(c);
        }
    }
}

// ---------------------------------------------------------------------------
extern "C" void kernel_launch(void* const* d_in, const int* in_sizes, int n_in,
                              void* d_out, int out_size, void* d_ws, size_t ws_size,
                              hipStream_t stream)
{
    const void* qp = d_in[0];
    const void* kp = d_in[1];
    const void* vp = d_in[2];
    const int* mask = (const int*)d_in[3];
    const void* Wqp = d_in[4];  const void* bqp = d_in[5];
    const void* Wkp = d_in[6];  const void* bkp = d_in[7];
    const void* Wvp = d_in[8];  const void* bvp = d_in[9];
    const void* Wop = d_in[10]; const void* bop = d_in[11];
    const void* W1p = d_in[12]; const void* b1p = d_in[13];
    const void* W2p = d_in[14]; const void* b2p = d_in[15];
    const void* vwp = d_in[16]; const void* vbp = d_in[17];

    float* ws = (float*)d_ws;

    fuse_weights<<<dim3(8, 16, 2), 128, 0, stream>>>(qp, Wqp, bqp, Wkp, bkp,
                                                     W1p, b1p, W2p, b2p, vwp, vbp, ws);
    gemm_qkv<<<dim3(8, 24, 3), 128, 0, stream>>>(qp, kp, vp, Wvp, bvp, ws, ws);
    attn_kernel<<<BH * QTILES, 384, 0, stream>>>(qp, vwp, ws, ws, mask, d_out);
    gemm_out<<<dim3(8, 24, 1), 128, 0, stream>>>(qp, Wop, bop, ws, d_out);
}

// Round 6
// 188.479 us; speedup vs baseline: 2.2492x; 1.0781x over previous
//
#include <hip/hip_runtime.h>

// Problem constants
#define BATCH 2
#define LSEQ 384
#define NHID 512
#define NH 8
#define DH 64
#define BH (BATCH*NH)          // 16
#define MROWS (BATCH*LSEQ)     // 768
#define XELEMS ((size_t)MROWS * NHID)      // 393216 (x output elems)
#define TQ 4                   // q-rows per attn block
#define QTILES (LSEQ/TQ)       // 96

typedef unsigned short ushort_t;

__device__ __forceinline__ float bf2f(ushort_t u) {
    unsigned int v = ((unsigned int)u) << 16;
    return __uint_as_float(v);
}
__device__ __forceinline__ ushort_t f2bf(float f) {
    unsigned int u = __float_as_uint(f);
    unsigned int lsb = (u >> 16) & 1u;
    u += 0x7fffu + lsb;           // round-to-nearest-even
    return (ushort_t)(u >> 16);
}
// dual-path loads: f=1 -> fp32, f=0 -> packed bf16 (wave-uniform branch)
__device__ __forceinline__ float ld1(const void* p, size_t i, int f) {
    return f ? ((const float*)p)[i] : bf2f(((const ushort_t*)p)[i]);
}
__device__ __forceinline__ float4 ld4(const void* p, size_t i, int f) {
    if (f) return ((const float4*)p)[i >> 2];
    ushort4 u = ((const ushort4*)p)[i >> 2];
    return make_float4(bf2f(u.x), bf2f(u.y), bf2f(u.z), bf2f(u.w));
}
// per-block dtype vote (works for any blockDim >= 64)
__device__ __forceinline__ int block_detect(const unsigned int* q, int* cnt) {
    int t = threadIdx.x;
    if (t == 0) *cnt = 0;
    __syncthreads();
    int n = blockDim.x < 256 ? blockDim.x : 256;
    if (t < n) {
        unsigned int elo = (q[t] >> 7) & 0xFFu;   // low halfword bf16 exponent
        if (elo >= 100u && elo <= 150u) atomicAdd(cnt, 1);
    }
    __syncthreads();
    return (*cnt * 2 > n) ? 0 : 1;     // 0 = bf16-packed, 1 = fp32
}

// ---------------- workspace layout (float offsets) ----------------
// P(i) = partial buffers, i = mode*2 + ksplit, each [768][512] fp32
#define OFF_P     16
#define PSTRIDE   393216
#define OFF_BQE   2359312   // fused bias (b1 + W1@bq), NOT pre-scaled
#define OFF_BKE   2359824
#define OFF_ETQ   2360336   // Etq = exp(2 tq)  [bh][l][d]
#define OFF_ETKT  2753552   // Etk = exp(2 tk)  [bh][d][l]
#define OFF_VH    3146768   // V                [bh][l][d]
#define OFF_XH    3539984   // context [B,L,H,D]
// end = 3933200 floats = 15.7 MB

// 16-FMA microtile step
#define MICRO_FMA(a, b)                                                  \
    acc[0][0] = fmaf(a.x, b.x, acc[0][0]); acc[0][1] = fmaf(a.x, b.y, acc[0][1]); \
    acc[0][2] = fmaf(a.x, b.z, acc[0][2]); acc[0][3] = fmaf(a.x, b.w, acc[0][3]); \
    acc[1][0] = fmaf(a.y, b.x, acc[1][0]); acc[1][1] = fmaf(a.y, b.y, acc[1][1]); \
    acc[1][2] = fmaf(a.y, b.z, acc[1][2]); acc[1][3] = fmaf(a.y, b.w, acc[1][3]); \
    acc[2][0] = fmaf(a.z, b.x, acc[2][0]); acc[2][1] = fmaf(a.z, b.y, acc[2][1]); \
    acc[2][2] = fmaf(a.z, b.z, acc[2][2]); acc[2][3] = fmaf(a.z, b.w, acc[2][3]); \
    acc[3][0] = fmaf(a.w, b.x, acc[3][0]); acc[3][1] = fmaf(a.w, b.y, acc[3][1]); \
    acc[3][2] = fmaf(a.w, b.z, acc[3][2]); acc[3][3] = fmaf(a.w, b.w, acc[3][3])

#define FMA4(dst, p, v)  dst.x = fmaf(p, v.x, dst.x); dst.y = fmaf(p, v.y, dst.y); \
                         dst.z = fmaf(p, v.z, dst.z); dst.w = fmaf(p, v.w, dst.w)

// ---------------------------------------------------------------------------
// Kernel 1: QKV GEMM, split-K=2. blockIdx.z = mode*2 + ksplit.
// 32(m)x64(n) tile, 128 thr, K-slab 256, reg prefetch, k-major LDS.
// Modes 0/1 apply the per-head W1/W2 fold in an LDS mini-GEMM epilogue
// (linear, so split-K partials transform independently). Partials written
// in natural [m][o] fp32 layout; bias/exp/transpose deferred to finalize.
// ---------------------------------------------------------------------------
__global__ __launch_bounds__(128) void gemm_qkv(
    const void* qp, const void* kp, const void* vp,
    const void* Wqp, const void* Wkp, const void* Wvp,
    const void* W1p, const void* W2p,
    const void* bqp, const void* bkp, const void* b1p, const void* b2p,
    float* __restrict__ ws)
{
    __shared__ int s_cnt;
    // union: main As[32*36]=1152, Bs[32*68]=2176 | epi Qs[64*36]=2304, W1s[64*68]=4352
    __shared__ __align__(16) float smem[6656];
    const int f = block_detect((const unsigned int*)qp, &s_cnt);

    const int z = blockIdx.z;
    const int mode = z >> 1, ks = z & 1;
    const int kbase = ks * 256;
    const void* A = (mode == 0) ? qp : (mode == 1) ? kp : vp;
    const void* W = (mode == 0) ? Wqp : (mode == 1) ? Wkp : Wvp;
    float* P = ws + OFF_P + (size_t)z * PSTRIDE;

    float* As = smem;            // [32][36] k-major
    float* Bs = smem + 1152;     // [32][68] k-major

    const int row0 = blockIdx.y * 32;
    const int col0 = blockIdx.x * 64;      // == one head (h = col0>>6)
    const int tid = threadIdx.x;

    const int alr = tid >> 2, alc = tid & 3;   // A: 32r x 8 f4c, 2 each
    const int blr = tid >> 1, blc = tid & 1;   // B: 64r x 8 f4c, 4 each
    const int tm = tid >> 4, tn = tid & 15;

    const size_t abase = (size_t)(row0 + alr) * 512;
    const size_t bbase = (size_t)(col0 + blr) * 512;

    float4 a0, a1, b0, b1, b2, b3;
    a0 = ld4(A, abase + kbase + alc * 4, f);
    a1 = ld4(A, abase + kbase + (alc + 4) * 4, f);
    b0 = ld4(W, bbase + kbase + (blc + 0) * 4, f);
    b1 = ld4(W, bbase + kbase + (blc + 2) * 4, f);
    b2 = ld4(W, bbase + kbase + (blc + 4) * 4, f);
    b3 = ld4(W, bbase + kbase + (blc + 6) * 4, f);

    float acc[4][4];
    #pragma unroll
    for (int i = 0; i < 4; i++)
        #pragma unroll
        for (int j = 0; j < 4; j++) acc[i][j] = 0.f;

    for (int k0 = kbase; k0 < kbase + 256; k0 += 32) {
        __syncthreads();
        As[(alc * 4 + 0) * 36 + alr] = a0.x; As[(alc * 4 + 1) * 36 + alr] = a0.y;
        As[(alc * 4 + 2) * 36 + alr] = a0.z; As[(alc * 4 + 3) * 36 + alr] = a0.w;
        As[((alc + 4) * 4 + 0) * 36 + alr] = a1.x; As[((alc + 4) * 4 + 1) * 36 + alr] = a1.y;
        As[((alc + 4) * 4 + 2) * 36 + alr] = a1.z; As[((alc + 4) * 4 + 3) * 36 + alr] = a1.w;
        Bs[((blc + 0) * 4 + 0) * 68 + blr] = b0.x; Bs[((blc + 0) * 4 + 1) * 68 + blr] = b0.y;
        Bs[((blc + 0) * 4 + 2) * 68 + blr] = b0.z; Bs[((blc + 0) * 4 + 3) * 68 + blr] = b0.w;
        Bs[((blc + 2) * 4 + 0) * 68 + blr] = b1.x; Bs[((blc + 2) * 4 + 1) * 68 + blr] = b1.y;
        Bs[((blc + 2) * 4 + 2) * 68 + blr] = b1.z; Bs[((blc + 2) * 4 + 3) * 68 + blr] = b1.w;
        Bs[((blc + 4) * 4 + 0) * 68 + blr] = b2.x; Bs[((blc + 4) * 4 + 1) * 68 + blr] = b2.y;
        Bs[((blc + 4) * 4 + 2) * 68 + blr] = b2.z; Bs[((blc + 4) * 4 + 3) * 68 + blr] = b2.w;
        Bs[((blc + 6) * 4 + 0) * 68 + blr] = b3.x; Bs[((blc + 6) * 4 + 1) * 68 + blr] = b3.y;
        Bs[((blc + 6) * 4 + 2) * 68 + blr] = b3.z; Bs[((blc + 6) * 4 + 3) * 68 + blr] = b3.w;
        __syncthreads();
        int k1 = k0 + 32;
        if (k1 < kbase + 256) {              // prefetch next K-tile
            a0 = ld4(A, abase + k1 + alc * 4, f);
            a1 = ld4(A, abase + k1 + (alc + 4) * 4, f);
            b0 = ld4(W, bbase + k1 + (blc + 0) * 4, f);
            b1 = ld4(W, bbase + k1 + (blc + 2) * 4, f);
            b2 = ld4(W, bbase + k1 + (blc + 4) * 4, f);
            b3 = ld4(W, bbase + k1 + (blc + 6) * 4, f);
        }
        #pragma unroll
        for (int kk = 0; kk < 32; kk++) {
            float4 a = *reinterpret_cast<const float4*>(&As[kk * 36 + tm * 4]);
            float4 b = *reinterpret_cast<const float4*>(&Bs[kk * 68 + tn * 4]);
            MICRO_FMA(a, b);
        }
    }

    if (mode == 2) {
        #pragma unroll
        for (int i = 0; i < 4; i++) {
            int m = row0 + tm * 4 + i;
            float4 o4 = make_float4(acc[i][0], acc[i][1], acc[i][2], acc[i][3]);
            *reinterpret_cast<float4*>(&P[(size_t)m * 512 + col0 + tn * 4]) = o4;
        }
    } else {
        // ---- epilogue fold: tq_tile = Q_tile @ W1^T (per head) ----
        const void* W1x = mode ? W2p : W1p;
        float* Qs  = smem;           // [64 j][36 m]  (aliases As/Bs)
        float* W1s = smem + 2304;    // [64 j][68 od]
        __syncthreads();             // main-loop LDS dead
        #pragma unroll
        for (int i = 0; i < 4; i++)
            #pragma unroll
            for (int j = 0; j < 4; j++)
                Qs[(tn * 4 + j) * 36 + tm * 4 + i] = acc[i][j];
        {
            int od = tid >> 1;
            #pragma unroll
            for (int c = 0; c < 8; c++) {
                int j = (tid & 1) * 32 + c * 4;
                float4 w = ld4(W1x, (size_t)od * 64 + j, f);
                W1s[(j + 0) * 68 + od] = w.x; W1s[(j + 1) * 68 + od] = w.y;
                W1s[(j + 2) * 68 + od] = w.z; W1s[(j + 3) * 68 + od] = w.w;
            }
        }
        __syncthreads();
        float facc[4][4];
        #pragma unroll
        for (int i = 0; i < 4; i++)
            #pragma unroll
            for (int j = 0; j < 4; j++) facc[i][j] = 0.f;
        {
            float acc[4][4];                 // reuse macro on facc via alias
            #pragma unroll
            for (int i = 0; i < 4; i++)
                #pragma unroll
                for (int j = 0; j < 4; j++) acc[i][j] = 0.f;
            #pragma unroll 8
            for (int kk = 0; kk < 64; kk++) {
                float4 a = *reinterpret_cast<const float4*>(&Qs[kk * 36 + tm * 4]);
                float4 b = *reinterpret_cast<const float4*>(&W1s[kk * 68 + tn * 4]);
                MICRO_FMA(a, b);
            }
            #pragma unroll
            for (int i = 0; i < 4; i++)
                #pragma unroll
                for (int j = 0; j < 4; j++) facc[i][j] = acc[i][j];
        }
        #pragma unroll
        for (int i = 0; i < 4; i++) {
            int m = row0 + tm * 4 + i;
            float4 o4 = make_float4(facc[i][0], facc[i][1], facc[i][2], facc[i][3]);
            *reinterpret_cast<float4*>(&P[(size_t)m * 512 + col0 + tn * 4]) = o4;
        }
        // fused bias (once per n-block): biasF[o] = b1[od] + sum_j W1[od][j]*bq[h*64+j]
        if (blockIdx.y == 0 && ks == 0 && tid < 64) {
            int o = col0 + tid, od = o & 63, h = o >> 6;
            const void* b1x = mode ? b2p : b1p;
            const void* bx  = mode ? bkp : bqp;
            float s = ld1(b1x, od, f);
            for (int j = 0; j < 64; j++)
                s = fmaf(ld1(W1x, (size_t)od * 64 + j, f), ld1(bx, h * 64 + j, f), s);
            ws[(mode ? OFF_BKE : OFF_BQE) + o] = s;
        }
    }
}

// ---------------------------------------------------------------------------
// Kernel 2: finalize. blocks 0..383: Etq = exp(2(P0+P1+bqE)) -> [bh][l][d];
// 384..479: Etk = exp(2(P2+P3+bkE)) transposed -> [bh][d][l] via LDS tiles;
// 480..863: V = P4+P5+bv -> [bh][l][d].
// ---------------------------------------------------------------------------
__global__ __launch_bounds__(256) void finalize(
    const void* qp, const void* bvp,
    const float* __restrict__ ws_in, float* __restrict__ ws)
{
    __shared__ int s_cnt;
    __shared__ __align__(16) float T[64 * 68];
    const int f = block_detect((const unsigned int*)qp, &s_cnt);
    const int blk = blockIdx.x;
    const int tid = threadIdx.x;

    if (blk < 384 || blk >= 480) {
        const int isV = (blk >= 480);
        const float* P0 = ws_in + OFF_P + (size_t)(isV ? 4 : 0) * PSTRIDE;
        const float* P1 = P0 + PSTRIDE;
        float* Out = ws + (isV ? OFF_VH : OFF_ETQ);
        int gid = (isV ? blk - 480 : blk) * 256 + tid;   // float4 index
        int m = gid >> 7;                  // 128 float4 per row
        int o4 = (gid & 127) * 4;
        float4 p0 = *reinterpret_cast<const float4*>(P0 + (size_t)m * 512 + o4);
        float4 p1 = *reinterpret_cast<const float4*>(P1 + (size_t)m * 512 + o4);
        float4 bb;
        if (isV) bb = ld4(bvp, o4, f);
        else     bb = *reinterpret_cast<const float4*>(ws_in + OFF_BQE + o4);
        float4 r;
        if (isV) {
            r.x = p0.x + p1.x + bb.x; r.y = p0.y + p1.y + bb.y;
            r.z = p0.z + p1.z + bb.z; r.w = p0.w + p1.w + bb.w;
        } else {
            r.x = __expf(2.f * (p0.x + p1.x + bb.x));
            r.y = __expf(2.f * (p0.y + p1.y + bb.y));
            r.z = __expf(2.f * (p0.z + p1.z + bb.z));
            r.w = __expf(2.f * (p0.w + p1.w + bb.w));
        }
        int b = m / LSEQ, l = m % LSEQ, h = o4 >> 6, d = o4 & 63;
        *reinterpret_cast<float4*>(&Out[(size_t)((b * NH + h) * LSEQ + l) * 64 + d]) = r;
    } else {
        int blk2 = blk - 384;              // 96 = 16 bh x 6 l-tiles
        int bh = blk2 / 6, l0 = (blk2 % 6) * 64;
        int b = bh >> 3, h = bh & 7;
        const float* P0 = ws_in + OFF_P + (size_t)2 * PSTRIDE;
        const float* P1 = P0 + PSTRIDE;
        #pragma unroll
        for (int it = 0; it < 4; it++) {
            int li = (tid >> 4) + it * 16;
            int d4 = (tid & 15) * 4;
            size_t src = (size_t)(b * LSEQ + l0 + li) * 512 + h * 64 + d4;
            float4 p0 = *reinterpret_cast<const float4*>(P0 + src);
            float4 p1 = *reinterpret_cast<const float4*>(P1 + src);
            const float4 bb = *reinterpret_cast<const float4*>(ws_in + OFF_BKE + h * 64 + d4);
            T[(d4 + 0) * 68 + li] = __expf(2.f * (p0.x + p1.x + bb.x));
            T[(d4 + 1) * 68 + li] = __expf(2.f * (p0.y + p1.y + bb.y));
            T[(d4 + 2) * 68 + li] = __expf(2.f * (p0.z + p1.z + bb.z));
            T[(d4 + 3) * 68 + li] = __expf(2.f * (p0.w + p1.w + bb.w));
        }
        __syncthreads();
        float* Out = ws + OFF_ETKT;
        #pragma unroll
        for (int it = 0; it < 4; it++) {
            int d = (tid >> 4) + it * 16;
            int l4 = (tid & 15) * 4;
            float4 v = *reinterpret_cast<const float4*>(&T[d * 68 + l4]);
            *reinterpret_cast<float4*>(&Out[(size_t)(bh * 64 + d) * LSEQ + l0 + l4]) = v;
        }
    }
}

// ---------------------------------------------------------------------------
// Kernel 3: additive attention, TQ=4 q-rows per block, 384 threads (t = k).
// vw*tanh(tq+tk) = vw - 2*rcp(iw + (Etq*iw)*Etk); e = vbSum - 2*sum_d rcp(..)
// ---------------------------------------------------------------------------
__global__ __launch_bounds__(384, 6) void attn_kernel(
    const void* qp, const void* vwp, const void* vbp,
    const float* __restrict__ ws_in, float* __restrict__ ws,
    const int* __restrict__ mask, void* __restrict__ dout)
{
    __shared__ int s_cnt;
    const int f = block_detect((const unsigned int*)qp, &s_cnt);

    const float* Etq = ws_in + OFF_ETQ;
    const float* Etk = ws_in + OFF_ETKT;
    const float* Vh  = ws_in + OFF_VH;
    float* Xh = ws + OFF_XH;

    const int bid = blockIdx.x;            // bh*QTILES + qt
    const int qt = bid % QTILES;
    const int bh = bid / QTILES;
    const int q0 = qt * TQ;
    const int b  = bh >> 3;
    const int h  = bh & 7;
    const int t  = threadIdx.x;            // 0..383 (= k)
    const int wave = t >> 6;

    __shared__ __align__(16) float etqT[64][TQ];  // [d][qi], pre-mult by iw[d]
    __shared__ float iws[64];
    __shared__ float ps[TQ][LSEQ];
    __shared__ float red[6][TQ][16][4];
    __shared__ float rmax[TQ][6];
    __shared__ float rsum[TQ][6];
    __shared__ float s_vb;

    if (t < 256) {
        int d = t & 63, qi = t >> 6;
        float vwv = ld1(vwp, d, f);
        float iw = __builtin_amdgcn_rcpf(vwv);
        etqT[d][qi] = Etq[(size_t)(bh * LSEQ + q0 + qi) * 64 + d] * iw;
        if (qi == 0) {
            iws[d] = iw;
            float v = vwv;
            #pragma unroll
            for (int off = 32; off > 0; off >>= 1) v += __shfl_xor(v, off, 64);
            if (d == 0) s_vb = ld1(vbp, 0, f) + v;
        }
    }
    const int mok = mask[b * LSEQ + t];
    __syncthreads();
    const float vbSum = s_vb;

    // ---- energy: one live ekv scalar, no register array ----
    float e2[TQ] = {0.f, 0.f, 0.f, 0.f};
    const float* ekp = Etk + (size_t)bh * 64 * LSEQ + t;
    #pragma unroll 4
    for (int d = 0; d < 64; d++) {
        float ekv = ekp[(size_t)d * LSEQ];
        float4 eq = *reinterpret_cast<const float4*>(&etqT[d][0]);  // LDS broadcast
        float iw = iws[d];
        e2[0] += __builtin_amdgcn_rcpf(fmaf(eq.x, ekv, iw));
        e2[1] += __builtin_amdgcn_rcpf(fmaf(eq.y, ekv, iw));
        e2[2] += __builtin_amdgcn_rcpf(fmaf(eq.z, ekv, iw));
        e2[3] += __builtin_amdgcn_rcpf(fmaf(eq.w, ekv, iw));
    }
    float en[TQ];
    #pragma unroll
    for (int qi = 0; qi < TQ; qi++) {
        en[qi] = fmaf(-2.0f, e2[qi], vbSum);
        if (mok == 0) en[qi] = -1e10f;
    }

    // ---- softmax (block-wide over 6 waves), batched for TQ rows ----
    #pragma unroll
    for (int qi = 0; qi < TQ; qi++) {
        float m = en[qi];
        #pragma unroll
        for (int off = 32; off > 0; off >>= 1) m = fmaxf(m, __shfl_xor(m, off, 64));
        if ((t & 63) == 0) rmax[qi][wave] = m;
    }
    __syncthreads();
    float p[TQ];
    #pragma unroll
    for (int qi = 0; qi < TQ; qi++) {
        float gm = fmaxf(fmaxf(fmaxf(rmax[qi][0], rmax[qi][1]),
                               fmaxf(rmax[qi][2], rmax[qi][3])),
                         fmaxf(rmax[qi][4], rmax[qi][5]));
        p[qi] = __expf(en[qi] - gm);
        float s = p[qi];
        #pragma unroll
        for (int off = 32; off > 0; off >>= 1) s += __shfl_xor(s, off, 64);
        if ((t & 63) == 0) rsum[qi][wave] = s;
    }
    __syncthreads();
    #pragma unroll
    for (int qi = 0; qi < TQ; qi++) {
        float gs = rsum[qi][0] + rsum[qi][1] + rsum[qi][2] +
                   rsum[qi][3] + rsum[qi][4] + rsum[qi][5];
        p[qi] *= 1.0f / gs;
        ps[qi][t] = p[qi];
        size_t aidx = XELEMS + (size_t)(bh * LSEQ + q0 + qi) * LSEQ + t;
        if (f) ((float*)dout)[aidx] = p[qi];
        else   ((ushort_t*)dout)[aidx] = f2bf(p[qi]);
    }
    __syncthreads();

    // ---- context: x[qi][d] = sum_k p[k] V[k][d]; float4 V reused across qi ----
    const int dq = t & 15;
    const int ksub = t >> 4;               // 0..23
    const float* vb4 = Vh + (size_t)bh * LSEQ * 64 + dq * 4;
    float4 acc[TQ];
    #pragma unroll
    for (int qi = 0; qi < TQ; qi++) acc[qi] = make_float4(0.f, 0.f, 0.f, 0.f);
    for (int kk = ksub; kk < LSEQ; kk += 24) {
        float4 v4 = *reinterpret_cast<const float4*>(vb4 + (size_t)kk * 64);
        #pragma unroll
        for (int qi = 0; qi < TQ; qi++) {
            float pq = ps[qi][kk];
            FMA4(acc[qi], pq, v4);
        }
    }
    #pragma unroll
    for (int qi = 0; qi < TQ; qi++) {
        #pragma unroll
        for (int off = 16; off <= 32; off <<= 1) {
            acc[qi].x += __shfl_xor(acc[qi].x, off, 64);
            acc[qi].y += __shfl_xor(acc[qi].y, off, 64);
            acc[qi].z += __shfl_xor(acc[qi].z, off, 64);
            acc[qi].w += __shfl_xor(acc[qi].w, off, 64);
        }
    }
    if ((t & 63) < 16) {
        #pragma unroll
        for (int qi = 0; qi < TQ; qi++) {
            red[wave][qi][dq][0] = acc[qi].x;
            red[wave][qi][dq][1] = acc[qi].y;
            red[wave][qi][dq][2] = acc[qi].z;
            red[wave][qi][dq][3] = acc[qi].w;
        }
    }
    __syncthreads();
    if (t < 256) {
        int qi = t >> 6, d = t & 63;
        float sx = 0.f;
        #pragma unroll
        for (int w = 0; w < 6; w++) sx += red[w][qi][d >> 2][d & 3];
        Xh[((size_t)(b * LSEQ + q0 + qi) * NH + h) * 64 + d] = sx;
    }
}

// ---------------------------------------------------------------------------
// Kernel 4: output projection, 32x64 prefetch tile. x = Xh @ Wo.T + bo.
// ---------------------------------------------------------------------------
__global__ __launch_bounds__(128) void gemm_out(
    const void* qp, const void* Wop, const void* bop,
    const float* __restrict__ ws_in, void* __restrict__ dout)
{
    __shared__ int s_cnt;
    __shared__ __align__(16) float As[32][36];
    __shared__ __align__(16) float Bs[32][68];
    const int f = block_detect((const unsigned int*)qp, &s_cnt);

    const float* Xh = ws_in + OFF_XH;
    const int row0 = blockIdx.y * 32;
    const int col0 = blockIdx.x * 64;
    const int tid = threadIdx.x;

    const int alr = tid >> 2, alc = tid & 3;
    const int blr = tid >> 1, blc = tid & 1;
    const int tm = tid >> 4, tn = tid & 15;

    const float* Ab = Xh + (size_t)(row0 + alr) * 512;
    const size_t bbase = (size_t)(col0 + blr) * 512;

    float4 a0, a1, b0, b1, b2, b3;
    a0 = *reinterpret_cast<const float4*>(Ab + alc * 4);
    a1 = *reinterpret_cast<const float4*>(Ab + (alc + 4) * 4);
    b0 = ld4(Wop, bbase + (blc + 0) * 4, f);
    b1 = ld4(Wop, bbase + (blc + 2) * 4, f);
    b2 = ld4(Wop, bbase + (blc + 4) * 4, f);
    b3 = ld4(Wop, bbase + (blc + 6) * 4, f);

    float acc[4][4];
    #pragma unroll
    for (int i = 0; i < 4; i++)
        #pragma unroll
        for (int j = 0; j < 4; j++) acc[i][j] = 0.f;

    for (int k0 = 0; k0 < 512; k0 += 32) {
        __syncthreads();
        As[alc * 4 + 0][alr] = a0.x; As[alc * 4 + 1][alr] = a0.y;
        As[alc * 4 + 2][alr] = a0.z; As[alc * 4 + 3][alr] = a0.w;
        As[(alc + 4) * 4 + 0][alr] = a1.x; As[(alc + 4) * 4 + 1][alr] = a1.y;
        As[(alc + 4) * 4 + 2][alr] = a1.z; As[(alc + 4) * 4 + 3][alr] = a1.w;
        Bs[(blc + 0) * 4 + 0][blr] = b0.x; Bs[(blc + 0) * 4 + 1][blr] = b0.y;
        Bs[(blc + 0) * 4 + 2][blr] = b0.z; Bs[(blc + 0) * 4 + 3][blr] = b0.w;
        Bs[(blc + 2) * 4 + 0][blr] = b1.x; Bs[(blc + 2) * 4 + 1][blr] = b1.y;
        Bs[(blc + 2) * 4 + 2][blr] = b1.z; Bs[(blc + 2) * 4 + 3][blr] = b1.w;
        Bs[(blc + 4) * 4 + 0][blr] = b2.x; Bs[(blc + 4) * 4 + 1][blr] = b2.y;
        Bs[(blc + 4) * 4 + 2][blr] = b2.z; Bs[(blc + 4) * 4 + 3][blr] = b2.w;
        Bs[(blc + 6) * 4 + 0][blr] = b3.x; Bs[(blc + 6) * 4 + 1][blr] = b3.y;
        Bs[(blc + 6) * 4 + 2][blr] = b3.z; Bs[(blc + 6) * 4 + 3][blr] = b3.w;
        __syncthreads();
        int k1 = k0 + 32;
        if (k1 < 512) {
            a0 = *reinterpret_cast<const float4*>(Ab + k1 + alc * 4);
            a1 = *reinterpret_cast<const float4*>(Ab + k1 + (alc + 4) * 4);
            b0 = ld4(Wop, bbase + k1 + (blc + 0) * 4, f);
            b1 = ld4(Wop, bbase + k1 + (blc + 2) * 4, f);
            b2 = ld4(Wop, bbase + k1 + (blc + 4) * 4, f);
            b3 = ld4(Wop, bbase + k1 + (blc + 6) * 4, f);
        }
        #pragma unroll
        for (int kk = 0; kk < 32; kk++) {
            float4 a = *reinterpret_cast<const float4*>(&As[kk][tm * 4]);
            float4 b = *reinterpret_cast<const float4*>(&Bs[kk][tn * 4]);
            MICRO_FMA(a, b);
        }
    }

    #pragma unroll
    for (int i = 0; i < 4; i++) {
        int m = row0 + tm * 4 + i;
        #pragma unroll
        for (int j = 0; j < 4; j++) {
            int n = col0 + tn * 4 + j;
            float c = acc[i][j] + ld1(bop, n, f);
            size_t idx = (size_t)m * 512 + n;
            if (f) ((float*)dout)[idx] = c;
            else   ((ushort_t*)dout)[idx] = f2bf(c);
        }
    }
}

// ---------------------------------------------------------------------------
extern "C" void kernel_launch(void* const* d_in, const int* in_sizes, int n_in,
                              void* d_out, int out_size, void* d_ws, size_t ws_size,
                              hipStream_t stream)
{
    const void* qp = d_in[0];
    const void* kp = d_in[1];
    const void* vp = d_in[2];
    const int* mask = (const int*)d_in[3];
    const void* Wqp = d_in[4];  const void* bqp = d_in[5];
    const void* Wkp = d_in[6];  const void* bkp = d_in[7];
    const void* Wvp = d_in[8];  const void* bvp = d_in[9];
    const void* Wop = d_in[10]; const void* bop = d_in[11];
    const void* W1p = d_in[12]; const void* b1p = d_in[13];
    const void* W2p = d_in[14]; const void* b2p = d_in[15];
    const void* vwp = d_in[16]; const void* vbp = d_in[17];

    float* ws = (float*)d_ws;

    gemm_qkv<<<dim3(8, 24, 6), 128, 0, stream>>>(qp, kp, vp, Wqp, Wkp, Wvp,
                                                 W1p, W2p, bqp, bkp, b1p, b2p, ws);
    finalize<<<864, 256, 0, stream>>>(qp, bvp, ws, ws);
    attn_kernel<<<BH * QTILES, 384, 0, stream>>>(qp, vwp, vbp, ws, ws, mask, d_out);
    gemm_out<<<dim3(8, 24, 1), 128, 0, stream>>>(qp, Wop, bop, ws, d_out);
}

// Round 7
// 183.113 us; speedup vs baseline: 2.3151x; 1.0293x over previous
//
#include <hip/hip_runtime.h>

// Problem constants
#define BATCH 2
#define LSEQ 384
#define NHID 512
#define NH 8
#define DH 64
#define BH (BATCH*NH)          // 16
#define MROWS (BATCH*LSEQ)     // 768
#define XELEMS ((size_t)MROWS * NHID)      // 393216 (x output elems)
#define TQ 4                   // q-rows per attn block
#define QTILES (LSEQ/TQ)       // 96

typedef unsigned short ushort_t;

__device__ __forceinline__ float bf2f(ushort_t u) {
    unsigned int v = ((unsigned int)u) << 16;
    return __uint_as_float(v);
}
__device__ __forceinline__ ushort_t f2bf(float f) {
    unsigned int u = __float_as_uint(f);
    unsigned int lsb = (u >> 16) & 1u;
    u += 0x7fffu + lsb;           // round-to-nearest-even
    return (ushort_t)(u >> 16);
}
// dual-path loads: f=1 -> fp32, f=0 -> packed bf16 (wave-uniform branch)
__device__ __forceinline__ float ld1(const void* p, size_t i, int f) {
    return f ? ((const float*)p)[i] : bf2f(((const ushort_t*)p)[i]);
}
__device__ __forceinline__ float4 ld4(const void* p, size_t i, int f) {
    if (f) return ((const float4*)p)[i >> 2];
    ushort4 u = ((const ushort4*)p)[i >> 2];
    return make_float4(bf2f(u.x), bf2f(u.y), bf2f(u.z), bf2f(u.w));
}
// per-block dtype vote (works for any blockDim >= 64)
__device__ __forceinline__ int block_detect(const unsigned int* q, int* cnt) {
    int t = threadIdx.x;
    if (t == 0) *cnt = 0;
    __syncthreads();
    int n = blockDim.x < 256 ? blockDim.x : 256;
    if (t < n) {
        unsigned int elo = (q[t] >> 7) & 0xFFu;   // low halfword bf16 exponent
        if (elo >= 100u && elo <= 150u) atomicAdd(cnt, 1);
    }
    __syncthreads();
    return (*cnt * 2 > n) ? 0 : 1;     // 0 = bf16-packed, 1 = fp32
}

// ---------------- workspace layout (float offsets) ----------------
// P(i) partial buffers (qkv split-K, then reused by gemm_out split-K)
#define OFF_P     16
#define PSTRIDE   393216
#define OFF_BQE   2359312   // fused bias (b1 + W1@bq), NOT pre-scaled
#define OFF_BKE   2359824
#define OFF_ETQ   2360336   // Etq = exp(2 tq)  [bh][l][d]
#define OFF_ETKT  2753552   // Etk = exp(2 tk)  [bh][d][l]
#define OFF_VH    3146768   // V                [bh][l][d]
#define OFF_XH    3539984   // context [B,L,H,D]
// end = 3933200 floats = 15.7 MB

// 16-FMA microtile step
#define MICRO_FMA(a, b)                                                  \
    acc[0][0] = fmaf(a.x, b.x, acc[0][0]); acc[0][1] = fmaf(a.x, b.y, acc[0][1]); \
    acc[0][2] = fmaf(a.x, b.z, acc[0][2]); acc[0][3] = fmaf(a.x, b.w, acc[0][3]); \
    acc[1][0] = fmaf(a.y, b.x, acc[1][0]); acc[1][1] = fmaf(a.y, b.y, acc[1][1]); \
    acc[1][2] = fmaf(a.y, b.z, acc[1][2]); acc[1][3] = fmaf(a.y, b.w, acc[1][3]); \
    acc[2][0] = fmaf(a.z, b.x, acc[2][0]); acc[2][1] = fmaf(a.z, b.y, acc[2][1]); \
    acc[2][2] = fmaf(a.z, b.z, acc[2][2]); acc[2][3] = fmaf(a.z, b.w, acc[2][3]); \
    acc[3][0] = fmaf(a.w, b.x, acc[3][0]); acc[3][1] = fmaf(a.w, b.y, acc[3][1]); \
    acc[3][2] = fmaf(a.w, b.z, acc[3][2]); acc[3][3] = fmaf(a.w, b.w, acc[3][3])

#define FMA4(dst, p, v)  dst.x = fmaf(p, v.x, dst.x); dst.y = fmaf(p, v.y, dst.y); \
                         dst.z = fmaf(p, v.z, dst.z); dst.w = fmaf(p, v.w, dst.w)

// ---------------------------------------------------------------------------
// Kernel 1: QKV GEMM, split-K=2. blockIdx.z = mode*2 + ksplit. (unchanged r6)
// ---------------------------------------------------------------------------
__global__ __launch_bounds__(128) void gemm_qkv(
    const void* qp, const void* kp, const void* vp,
    const void* Wqp, const void* Wkp, const void* Wvp,
    const void* W1p, const void* W2p,
    const void* bqp, const void* bkp, const void* b1p, const void* b2p,
    float* __restrict__ ws)
{
    __shared__ int s_cnt;
    __shared__ __align__(16) float smem[6656];
    const int f = block_detect((const unsigned int*)qp, &s_cnt);

    const int z = blockIdx.z;
    const int mode = z >> 1, ks = z & 1;
    const int kbase = ks * 256;
    const void* A = (mode == 0) ? qp : (mode == 1) ? kp : vp;
    const void* W = (mode == 0) ? Wqp : (mode == 1) ? Wkp : Wvp;
    float* P = ws + OFF_P + (size_t)z * PSTRIDE;

    float* As = smem;            // [32][36] k-major
    float* Bs = smem + 1152;     // [32][68] k-major

    const int row0 = blockIdx.y * 32;
    const int col0 = blockIdx.x * 64;      // == one head (h = col0>>6)
    const int tid = threadIdx.x;

    const int alr = tid >> 2, alc = tid & 3;
    const int blr = tid >> 1, blc = tid & 1;
    const int tm = tid >> 4, tn = tid & 15;

    const size_t abase = (size_t)(row0 + alr) * 512;
    const size_t bbase = (size_t)(col0 + blr) * 512;

    float4 a0, a1, b0, b1, b2, b3;
    a0 = ld4(A, abase + kbase + alc * 4, f);
    a1 = ld4(A, abase + kbase + (alc + 4) * 4, f);
    b0 = ld4(W, bbase + kbase + (blc + 0) * 4, f);
    b1 = ld4(W, bbase + kbase + (blc + 2) * 4, f);
    b2 = ld4(W, bbase + kbase + (blc + 4) * 4, f);
    b3 = ld4(W, bbase + kbase + (blc + 6) * 4, f);

    float acc[4][4];
    #pragma unroll
    for (int i = 0; i < 4; i++)
        #pragma unroll
        for (int j = 0; j < 4; j++) acc[i][j] = 0.f;

    for (int k0 = kbase; k0 < kbase + 256; k0 += 32) {
        __syncthreads();
        As[(alc * 4 + 0) * 36 + alr] = a0.x; As[(alc * 4 + 1) * 36 + alr] = a0.y;
        As[(alc * 4 + 2) * 36 + alr] = a0.z; As[(alc * 4 + 3) * 36 + alr] = a0.w;
        As[((alc + 4) * 4 + 0) * 36 + alr] = a1.x; As[((alc + 4) * 4 + 1) * 36 + alr] = a1.y;
        As[((alc + 4) * 4 + 2) * 36 + alr] = a1.z; As[((alc + 4) * 4 + 3) * 36 + alr] = a1.w;
        Bs[((blc + 0) * 4 + 0) * 68 + blr] = b0.x; Bs[((blc + 0) * 4 + 1) * 68 + blr] = b0.y;
        Bs[((blc + 0) * 4 + 2) * 68 + blr] = b0.z; Bs[((blc + 0) * 4 + 3) * 68 + blr] = b0.w;
        Bs[((blc + 2) * 4 + 0) * 68 + blr] = b1.x; Bs[((blc + 2) * 4 + 1) * 68 + blr] = b1.y;
        Bs[((blc + 2) * 4 + 2) * 68 + blr] = b1.z; Bs[((blc + 2) * 4 + 3) * 68 + blr] = b1.w;
        Bs[((blc + 4) * 4 + 0) * 68 + blr] = b2.x; Bs[((blc + 4) * 4 + 1) * 68 + blr] = b2.y;
        Bs[((blc + 4) * 4 + 2) * 68 + blr] = b2.z; Bs[((blc + 4) * 4 + 3) * 68 + blr] = b2.w;
        Bs[((blc + 6) * 4 + 0) * 68 + blr] = b3.x; Bs[((blc + 6) * 4 + 1) * 68 + blr] = b3.y;
        Bs[((blc + 6) * 4 + 2) * 68 + blr] = b3.z; Bs[((blc + 6) * 4 + 3) * 68 + blr] = b3.w;
        __syncthreads();
        int k1 = k0 + 32;
        if (k1 < kbase + 256) {
            a0 = ld4(A, abase + k1 + alc * 4, f);
            a1 = ld4(A, abase + k1 + (alc + 4) * 4, f);
            b0 = ld4(W, bbase + k1 + (blc + 0) * 4, f);
            b1 = ld4(W, bbase + k1 + (blc + 2) * 4, f);
            b2 = ld4(W, bbase + k1 + (blc + 4) * 4, f);
            b3 = ld4(W, bbase + k1 + (blc + 6) * 4, f);
        }
        #pragma unroll
        for (int kk = 0; kk < 32; kk++) {
            float4 a = *reinterpret_cast<const float4*>(&As[kk * 36 + tm * 4]);
            float4 b = *reinterpret_cast<const float4*>(&Bs[kk * 68 + tn * 4]);
            MICRO_FMA(a, b);
        }
    }

    if (mode == 2) {
        #pragma unroll
        for (int i = 0; i < 4; i++) {
            int m = row0 + tm * 4 + i;
            float4 o4 = make_float4(acc[i][0], acc[i][1], acc[i][2], acc[i][3]);
            *reinterpret_cast<float4*>(&P[(size_t)m * 512 + col0 + tn * 4]) = o4;
        }
    } else {
        const void* W1x = mode ? W2p : W1p;
        float* Qs  = smem;           // [64 j][36 m]
        float* W1s = smem + 2304;    // [64 j][68 od]
        __syncthreads();
        #pragma unroll
        for (int i = 0; i < 4; i++)
            #pragma unroll
            for (int j = 0; j < 4; j++)
                Qs[(tn * 4 + j) * 36 + tm * 4 + i] = acc[i][j];
        {
            int od = tid >> 1;
            #pragma unroll
            for (int c = 0; c < 8; c++) {
                int j = (tid & 1) * 32 + c * 4;
                float4 w = ld4(W1x, (size_t)od * 64 + j, f);
                W1s[(j + 0) * 68 + od] = w.x; W1s[(j + 1) * 68 + od] = w.y;
                W1s[(j + 2) * 68 + od] = w.z; W1s[(j + 3) * 68 + od] = w.w;
            }
        }
        __syncthreads();
        {
            float acc[4][4];
            #pragma unroll
            for (int i = 0; i < 4; i++)
                #pragma unroll
                for (int j = 0; j < 4; j++) acc[i][j] = 0.f;
            #pragma unroll 8
            for (int kk = 0; kk < 64; kk++) {
                float4 a = *reinterpret_cast<const float4*>(&Qs[kk * 36 + tm * 4]);
                float4 b = *reinterpret_cast<const float4*>(&W1s[kk * 68 + tn * 4]);
                MICRO_FMA(a, b);
            }
            #pragma unroll
            for (int i = 0; i < 4; i++) {
                int m = row0 + tm * 4 + i;
                float4 o4 = make_float4(acc[i][0], acc[i][1], acc[i][2], acc[i][3]);
                *reinterpret_cast<float4*>(&P[(size_t)m * 512 + col0 + tn * 4]) = o4;
            }
        }
        if (blockIdx.y == 0 && ks == 0 && tid < 64) {
            int o = col0 + tid, od = o & 63, h = o >> 6;
            const void* b1x = mode ? b2p : b1p;
            const void* bx  = mode ? bkp : bqp;
            float s = ld1(b1x, od, f);
            for (int j = 0; j < 64; j++)
                s = fmaf(ld1(W1x, (size_t)od * 64 + j, f), ld1(bx, h * 64 + j, f), s);
            ws[(mode ? OFF_BKE : OFF_BQE) + o] = s;
        }
    }
}

// ---------------------------------------------------------------------------
// Kernel 2: finalize (unchanged r6).
// ---------------------------------------------------------------------------
__global__ __launch_bounds__(256) void finalize(
    const void* qp, const void* bvp,
    const float* __restrict__ ws_in, float* __restrict__ ws)
{
    __shared__ int s_cnt;
    __shared__ __align__(16) float T[64 * 68];
    const int f = block_detect((const unsigned int*)qp, &s_cnt);
    const int blk = blockIdx.x;
    const int tid = threadIdx.x;

    if (blk < 384 || blk >= 480) {
        const int isV = (blk >= 480);
        const float* P0 = ws_in + OFF_P + (size_t)(isV ? 4 : 0) * PSTRIDE;
        const float* P1 = P0 + PSTRIDE;
        float* Out = ws + (isV ? OFF_VH : OFF_ETQ);
        int gid = (isV ? blk - 480 : blk) * 256 + tid;
        int m = gid >> 7;
        int o4 = (gid & 127) * 4;
        float4 p0 = *reinterpret_cast<const float4*>(P0 + (size_t)m * 512 + o4);
        float4 p1 = *reinterpret_cast<const float4*>(P1 + (size_t)m * 512 + o4);
        float4 bb;
        if (isV) bb = ld4(bvp, o4, f);
        else     bb = *reinterpret_cast<const float4*>(ws_in + OFF_BQE + o4);
        float4 r;
        if (isV) {
            r.x = p0.x + p1.x + bb.x; r.y = p0.y + p1.y + bb.y;
            r.z = p0.z + p1.z + bb.z; r.w = p0.w + p1.w + bb.w;
        } else {
            r.x = __expf(2.f * (p0.x + p1.x + bb.x));
            r.y = __expf(2.f * (p0.y + p1.y + bb.y));
            r.z = __expf(2.f * (p0.z + p1.z + bb.z));
            r.w = __expf(2.f * (p0.w + p1.w + bb.w));
        }
        int b = m / LSEQ, l = m % LSEQ, h = o4 >> 6, d = o4 & 63;
        *reinterpret_cast<float4*>(&Out[(size_t)((b * NH + h) * LSEQ + l) * 64 + d]) = r;
    } else {
        int blk2 = blk - 384;              // 96 = 16 bh x 6 l-tiles
        int bh = blk2 / 6, l0 = (blk2 % 6) * 64;
        int b = bh >> 3, h = bh & 7;
        const float* P0 = ws_in + OFF_P + (size_t)2 * PSTRIDE;
        const float* P1 = P0 + PSTRIDE;
        #pragma unroll
        for (int it = 0; it < 4; it++) {
            int li = (tid >> 4) + it * 16;
            int d4 = (tid & 15) * 4;
            size_t src = (size_t)(b * LSEQ + l0 + li) * 512 + h * 64 + d4;
            float4 p0 = *reinterpret_cast<const float4*>(P0 + src);
            float4 p1 = *reinterpret_cast<const float4*>(P1 + src);
            const float4 bb = *reinterpret_cast<const float4*>(ws_in + OFF_BKE + h * 64 + d4);
            T[(d4 + 0) * 68 + li] = __expf(2.f * (p0.x + p1.x + bb.x));
            T[(d4 + 1) * 68 + li] = __expf(2.f * (p0.y + p1.y + bb.y));
            T[(d4 + 2) * 68 + li] = __expf(2.f * (p0.z + p1.z + bb.z));
            T[(d4 + 3) * 68 + li] = __expf(2.f * (p0.w + p1.w + bb.w));
        }
        __syncthreads();
        float* Out = ws + OFF_ETKT;
        #pragma unroll
        for (int it = 0; it < 4; it++) {
            int d = (tid >> 4) + it * 16;
            int l4 = (tid & 15) * 4;
            float4 v = *reinterpret_cast<const float4*>(&T[d * 68 + l4]);
            *reinterpret_cast<float4*>(&Out[(size_t)(bh * 64 + d) * LSEQ + l0 + l4]) = v;
        }
    }
}

// ---------------------------------------------------------------------------
// Kernel 3: additive attention. Energy per element = fma+rcp+fma, all q-side
// operands (Etq rows, vw) read via UNIFORM addresses -> scalar loads (SMEM),
// zero LDS in the energy loop:  e = vbSum - 2*sum_d vw_d*rcp(1 + Etq*Etk).
// ---------------------------------------------------------------------------
__global__ __launch_bounds__(384, 6) void attn_kernel(
    const void* qp, const void* vwp, const void* vbp,
    const float* __restrict__ ws_in, float* __restrict__ ws,
    const int* __restrict__ mask, void* __restrict__ dout)
{
    __shared__ int s_cnt;
    const int f = block_detect((const unsigned int*)qp, &s_cnt);

    const float* Etq = ws_in + OFF_ETQ;
    const float* Etk = ws_in + OFF_ETKT;
    const float* Vh  = ws_in + OFF_VH;
    float* Xh = ws + OFF_XH;

    const int bid = blockIdx.x;            // bh*QTILES + qt
    const int qt = bid % QTILES;
    const int bh = bid / QTILES;
    const int q0 = qt * TQ;
    const int b  = bh >> 3;
    const int h  = bh & 7;
    const int t  = threadIdx.x;            // 0..383 (= k)
    const int wave = t >> 6;

    __shared__ float ps[TQ][LSEQ];
    __shared__ float red[6][TQ][16][4];
    __shared__ float rmax[TQ][6];
    __shared__ float rsum[TQ][6];
    __shared__ float s_vb;

    if (t < 64) {
        float v = ld1(vwp, t, f);
        #pragma unroll
        for (int off = 32; off > 0; off >>= 1) v += __shfl_xor(v, off, 64);
        if (t == 0) s_vb = ld1(vbp, 0, f) + v;
    }
    const int mok = mask[b * LSEQ + t];
    __syncthreads();
    const float vbSum = s_vb;

    // ---- energy: uniform-address (scalar) q-side operands ----
    const float* eqr0 = Etq + (size_t)(bh * LSEQ + q0) * 64;   // uniform rows
    const float* eqr1 = eqr0 + 64;
    const float* eqr2 = eqr0 + 128;
    const float* eqr3 = eqr0 + 192;
    const float* ekp  = Etk + (size_t)bh * 64 * LSEQ + t;

    float e2[TQ] = {0.f, 0.f, 0.f, 0.f};
    #pragma unroll 4
    for (int d = 0; d < 64; d++) {
        float ekv = ekp[(size_t)d * LSEQ];          // vector, coalesced
        float w = ld1(vwp, d, f);                   // uniform -> SGPR
        e2[0] = fmaf(w, __builtin_amdgcn_rcpf(fmaf(eqr0[d], ekv, 1.0f)), e2[0]);
        e2[1] = fmaf(w, __builtin_amdgcn_rcpf(fmaf(eqr1[d], ekv, 1.0f)), e2[1]);
        e2[2] = fmaf(w, __builtin_amdgcn_rcpf(fmaf(eqr2[d], ekv, 1.0f)), e2[2]);
        e2[3] = fmaf(w, __builtin_amdgcn_rcpf(fmaf(eqr3[d], ekv, 1.0f)), e2[3]);
    }
    float en[TQ];
    #pragma unroll
    for (int qi = 0; qi < TQ; qi++) {
        en[qi] = fmaf(-2.0f, e2[qi], vbSum);
        if (mok == 0) en[qi] = -1e10f;
    }

    // ---- softmax (block-wide over 6 waves), batched for TQ rows ----
    #pragma unroll
    for (int qi = 0; qi < TQ; qi++) {
        float m = en[qi];
        #pragma unroll
        for (int off = 32; off > 0; off >>= 1) m = fmaxf(m, __shfl_xor(m, off, 64));
        if ((t & 63) == 0) rmax[qi][wave] = m;
    }
    __syncthreads();
    float p[TQ];
    #pragma unroll
    for (int qi = 0; qi < TQ; qi++) {
        float gm = fmaxf(fmaxf(fmaxf(rmax[qi][0], rmax[qi][1]),
                               fmaxf(rmax[qi][2], rmax[qi][3])),
                         fmaxf(rmax[qi][4], rmax[qi][5]));
        p[qi] = __expf(en[qi] - gm);
        float s = p[qi];
        #pragma unroll
        for (int off = 32; off > 0; off >>= 1) s += __shfl_xor(s, off, 64);
        if ((t & 63) == 0) rsum[qi][wave] = s;
    }
    __syncthreads();
    #pragma unroll
    for (int qi = 0; qi < TQ; qi++) {
        float gs = rsum[qi][0] + rsum[qi][1] + rsum[qi][2] +
                   rsum[qi][3] + rsum[qi][4] + rsum[qi][5];
        p[qi] *= 1.0f / gs;
        ps[qi][t] = p[qi];
        size_t aidx = XELEMS + (size_t)(bh * LSEQ + q0 + qi) * LSEQ + t;
        if (f) ((float*)dout)[aidx] = p[qi];
        else   ((ushort_t*)dout)[aidx] = f2bf(p[qi]);
    }
    __syncthreads();

    // ---- context: x[qi][d] = sum_k p[k] V[k][d]; float4 V reused across qi ----
    const int dq = t & 15;
    const int ksub = t >> 4;               // 0..23
    const float* vb4 = Vh + (size_t)bh * LSEQ * 64 + dq * 4;
    float4 acc[TQ];
    #pragma unroll
    for (int qi = 0; qi < TQ; qi++) acc[qi] = make_float4(0.f, 0.f, 0.f, 0.f);
    for (int kk = ksub; kk < LSEQ; kk += 24) {
        float4 v4 = *reinterpret_cast<const float4*>(vb4 + (size_t)kk * 64);
        #pragma unroll
        for (int qi = 0; qi < TQ; qi++) {
            float pq = ps[qi][kk];
            FMA4(acc[qi], pq, v4);
        }
    }
    #pragma unroll
    for (int qi = 0; qi < TQ; qi++) {
        #pragma unroll
        for (int off = 16; off <= 32; off <<= 1) {
            acc[qi].x += __shfl_xor(acc[qi].x, off, 64);
            acc[qi].y += __shfl_xor(acc[qi].y, off, 64);
            acc[qi].z += __shfl_xor(acc[qi].z, off, 64);
            acc[qi].w += __shfl_xor(acc[qi].w, off, 64);
        }
    }
    if ((t & 63) < 16) {
        #pragma unroll
        for (int qi = 0; qi < TQ; qi++) {
            red[wave][qi][dq][0] = acc[qi].x;
            red[wave][qi][dq][1] = acc[qi].y;
            red[wave][qi][dq][2] = acc[qi].z;
            red[wave][qi][dq][3] = acc[qi].w;
        }
    }
    __syncthreads();
    if (t < 256) {
        int qi = t >> 6, d = t & 63;
        float sx = 0.f;
        #pragma unroll
        for (int w = 0; w < 6; w++) sx += red[w][qi][d >> 2][d & 3];
        Xh[((size_t)(b * LSEQ + q0 + qi) * NH + h) * 64 + d] = sx;
    }
}

// ---------------------------------------------------------------------------
// Kernel 4: output projection, split-K=4 (z=ksplit, K-slab 128). Partials
// into the (now dead) P region in natural [m][n] fp32 layout.
// ---------------------------------------------------------------------------
__global__ __launch_bounds__(128) void gemm_out(
    const void* qp, const void* Wop,
    const float* __restrict__ ws_in, float* __restrict__ ws)
{
    __shared__ int s_cnt;
    __shared__ __align__(16) float As[32][36];
    __shared__ __align__(16) float Bs[32][68];
    const int f = block_detect((const unsigned int*)qp, &s_cnt);

    const float* Xh = ws_in + OFF_XH;
    const int ks = blockIdx.z;
    const int kbase = ks * 128;
    float* P = ws + OFF_P + (size_t)ks * PSTRIDE;

    const int row0 = blockIdx.y * 32;
    const int col0 = blockIdx.x * 64;
    const int tid = threadIdx.x;

    const int alr = tid >> 2, alc = tid & 3;
    const int blr = tid >> 1, blc = tid & 1;
    const int tm = tid >> 4, tn = tid & 15;

    const float* Ab = Xh + (size_t)(row0 + alr) * 512 + kbase;
    const size_t bbase = (size_t)(col0 + blr) * 512 + kbase;

    float4 a0, a1, b0, b1, b2, b3;
    a0 = *reinterpret_cast<const float4*>(Ab + alc * 4);
    a1 = *reinterpret_cast<const float4*>(Ab + (alc + 4) * 4);
    b0 = ld4(Wop, bbase + (blc + 0) * 4, f);
    b1 = ld4(Wop, bbase + (blc + 2) * 4, f);
    b2 = ld4(Wop, bbase + (blc + 4) * 4, f);
    b3 = ld4(Wop, bbase + (blc + 6) * 4, f);

    float acc[4][4];
    #pragma unroll
    for (int i = 0; i < 4; i++)
        #pragma unroll
        for (int j = 0; j < 4; j++) acc[i][j] = 0.f;

    for (int k0 = 0; k0 < 128; k0 += 32) {
        __syncthreads();
        As[alc * 4 + 0][alr] = a0.x; As[alc * 4 + 1][alr] = a0.y;
        As[alc * 4 + 2][alr] = a0.z; As[alc * 4 + 3][alr] = a0.w;
        As[(alc + 4) * 4 + 0][alr] = a1.x; As[(alc + 4) * 4 + 1][alr] = a1.y;
        As[(alc + 4) * 4 + 2][alr] = a1.z; As[(alc + 4) * 4 + 3][alr] = a1.w;
        Bs[(blc + 0) * 4 + 0][blr] = b0.x; Bs[(blc + 0) * 4 + 1][blr] = b0.y;
        Bs[(blc + 0) * 4 + 2][blr] = b0.z; Bs[(blc + 0) * 4 + 3][blr] = b0.w;
        Bs[(blc + 2) * 4 + 0][blr] = b1.x; Bs[(blc + 2) * 4 + 1][blr] = b1.y;
        Bs[(blc + 2) * 4 + 2][blr] = b1.z; Bs[(blc + 2) * 4 + 3][blr] = b1.w;
        Bs[(blc + 4) * 4 + 0][blr] = b2.x; Bs[(blc + 4) * 4 + 1][blr] = b2.y;
        Bs[(blc + 4) * 4 + 2][blr] = b2.z; Bs[(blc + 4) * 4 + 3][blr] = b2.w;
        Bs[(blc + 6) * 4 + 0][blr] = b3.x; Bs[(blc + 6) * 4 + 1][blr] = b3.y;
        Bs[(blc + 6) * 4 + 2][blr] = b3.z; Bs[(blc + 6) * 4 + 3][blr] = b3.w;
        __syncthreads();
        int k1 = k0 + 32;
        if (k1 < 128) {
            a0 = *reinterpret_cast<const float4*>(Ab + k1 + alc * 4);
            a1 = *reinterpret_cast<const float4*>(Ab + k1 + (alc + 4) * 4);
            b0 = ld4(Wop, bbase + k1 + (blc + 0) * 4, f);
            b1 = ld4(Wop, bbase + k1 + (blc + 2) * 4, f);
            b2 = ld4(Wop, bbase + k1 + (blc + 4) * 4, f);
            b3 = ld4(Wop, bbase + k1 + (blc + 6) * 4, f);
        }
        #pragma unroll
        for (int kk = 0; kk < 32; kk++) {
            float4 a = *reinterpret_cast<const float4*>(&As[kk][tm * 4]);
            float4 b = *reinterpret_cast<const float4*>(&Bs[kk][tn * 4]);
            MICRO_FMA(a, b);
        }
    }

    #pragma unroll
    for (int i = 0; i < 4; i++) {
        int m = row0 + tm * 4 + i;
        float4 o4 = make_float4(acc[i][0], acc[i][1], acc[i][2], acc[i][3]);
        *reinterpret_cast<float4*>(&P[(size_t)m * 512 + col0 + tn * 4]) = o4;
    }
}

// ---------------------------------------------------------------------------
// Kernel 5: out_reduce — x = sum of 4 partials + bo, dual-dtype write.
// ---------------------------------------------------------------------------
__global__ __launch_bounds__(256) void out_reduce(
    const void* qp, const void* bop,
    const float* __restrict__ ws_in, void* __restrict__ dout)
{
    __shared__ int s_cnt;
    const int f = block_detect((const unsigned int*)qp, &s_cnt);
    int gid = blockIdx.x * 256 + threadIdx.x;   // float4 index, 0..98303
    size_t idx = (size_t)gid * 4;
    int o4 = (int)(idx & 511);
    const float* P = ws_in + OFF_P;
    float4 s0 = *reinterpret_cast<const float4*>(P + idx);
    float4 s1 = *reinterpret_cast<const float4*>(P + PSTRIDE + idx);
    float4 s2 = *reinterpret_cast<const float4*>(P + 2 * (size_t)PSTRIDE + idx);
    float4 s3 = *reinterpret_cast<const float4*>(P + 3 * (size_t)PSTRIDE + idx);
    float4 bb = ld4(bop, o4, f);
    float4 r;
    r.x = (s0.x + s1.x) + (s2.x + s3.x) + bb.x;
    r.y = (s0.y + s1.y) + (s2.y + s3.y) + bb.y;
    r.z = (s0.z + s1.z) + (s2.z + s3.z) + bb.z;
    r.w = (s0.w + s1.w) + (s2.w + s3.w) + bb.w;
    if (f) {
        *reinterpret_cast<float4*>((float*)dout + idx) = r;
    } else {
        ushort4 u;
        u.x = f2bf(r.x); u.y = f2bf(r.y); u.z = f2bf(r.z); u.w = f2bf(r.w);
        *reinterpret_cast<ushort4*>((ushort_t*)dout + idx) = u;
    }
}

// ---------------------------------------------------------------------------
extern "C" void kernel_launch(void* const* d_in, const int* in_sizes, int n_in,
                              void* d_out, int out_size, void* d_ws, size_t ws_size,
                              hipStream_t stream)
{
    const void* qp = d_in[0];
    const void* kp = d_in[1];
    const void* vp = d_in[2];
    const int* mask = (const int*)d_in[3];
    const void* Wqp = d_in[4];  const void* bqp = d_in[5];
    const void* Wkp = d_in[6];  const void* bkp = d_in[7];
    const void* Wvp = d_in[8];  const void* bvp = d_in[9];
    const void* Wop = d_in[10]; const void* bop = d_in[11];
    const void* W1p = d_in[12]; const void* b1p = d_in[13];
    const void* W2p = d_in[14]; const void* b2p = d_in[15];
    const void* vwp = d_in[16]; const void* vbp = d_in[17];

    float* ws = (float*)d_ws;

    gemm_qkv<<<dim3(8, 24, 6), 128, 0, stream>>>(qp, kp, vp, Wqp, Wkp, Wvp,
                                                 W1p, W2p, bqp, bkp, b1p, b2p, ws);
    finalize<<<864, 256, 0, stream>>>(qp, bvp, ws, ws);
    attn_kernel<<<BH * QTILES, 384, 0, stream>>>(qp, vwp, vbp, ws, ws, mask, d_out);
    gemm_out<<<dim3(8, 24, 4), 128, 0, stream>>>(qp, Wop, ws, ws);
    out_reduce<<<384, 256, 0, stream>>>(qp, bop, ws, d_out);
}

// Round 8
// 177.825 us; speedup vs baseline: 2.3840x; 1.0297x over previous
//
#include <hip/hip_runtime.h>

// Problem constants
#define BATCH 2
#define LSEQ 384
#define NHID 512
#define NH 8
#define DH 64
#define BH (BATCH*NH)          // 16
#define MROWS (BATCH*LSEQ)     // 768
#define XELEMS ((size_t)MROWS * NHID)      // 393216 (x output elems)
#define TQ 8                   // q-rows per attn block
#define QTILES (LSEQ/TQ)       // 48

typedef unsigned short ushort_t;

__device__ __forceinline__ float bf2f(ushort_t u) {
    unsigned int v = ((unsigned int)u) << 16;
    return __uint_as_float(v);
}
__device__ __forceinline__ ushort_t f2bf(float f) {
    unsigned int u = __float_as_uint(f);
    unsigned int lsb = (u >> 16) & 1u;
    u += 0x7fffu + lsb;           // round-to-nearest-even
    return (ushort_t)(u >> 16);
}
// dual-path loads: f=1 -> fp32, f=0 -> packed bf16 (wave-uniform branch)
__device__ __forceinline__ float ld1(const void* p, size_t i, int f) {
    return f ? ((const float*)p)[i] : bf2f(((const ushort_t*)p)[i]);
}
__device__ __forceinline__ float4 ld4(const void* p, size_t i, int f) {
    if (f) return ((const float4*)p)[i >> 2];
    ushort4 u = ((const ushort4*)p)[i >> 2];
    return make_float4(bf2f(u.x), bf2f(u.y), bf2f(u.z), bf2f(u.w));
}
// per-block dtype vote (works for any blockDim >= 64)
__device__ __forceinline__ int block_detect(const unsigned int* q, int* cnt) {
    int t = threadIdx.x;
    if (t == 0) *cnt = 0;
    __syncthreads();
    int n = blockDim.x < 256 ? blockDim.x : 256;
    if (t < n) {
        unsigned int elo = (q[t] >> 7) & 0xFFu;   // low halfword bf16 exponent
        if (elo >= 100u && elo <= 150u) atomicAdd(cnt, 1);
    }
    __syncthreads();
    return (*cnt * 2 > n) ? 0 : 1;     // 0 = bf16-packed, 1 = fp32
}

// ---------------- workspace layout (float offsets) ----------------
// P(i) partial buffers (qkv split-K, then reused by gemm_out split-K)
#define OFF_P     16
#define PSTRIDE   393216
#define OFF_BQE   2359312   // fused bias (b1 + W1@bq), NOT pre-scaled
#define OFF_BKE   2359824
#define OFF_ETQ   2360336   // Etq = exp(2 tq)  [bh][l][d]
#define OFF_ETKT  2753552   // Etk = exp(2 tk)  [bh][d][l]
#define OFF_VH    3146768   // V                [bh][l][d]
#define OFF_XH    3539984   // context [B,L,H,D]
// end = 3933200 floats = 15.7 MB

// 16-FMA microtile step
#define MICRO_FMA(a, b)                                                  \
    acc[0][0] = fmaf(a.x, b.x, acc[0][0]); acc[0][1] = fmaf(a.x, b.y, acc[0][1]); \
    acc[0][2] = fmaf(a.x, b.z, acc[0][2]); acc[0][3] = fmaf(a.x, b.w, acc[0][3]); \
    acc[1][0] = fmaf(a.y, b.x, acc[1][0]); acc[1][1] = fmaf(a.y, b.y, acc[1][1]); \
    acc[1][2] = fmaf(a.y, b.z, acc[1][2]); acc[1][3] = fmaf(a.y, b.w, acc[1][3]); \
    acc[2][0] = fmaf(a.z, b.x, acc[2][0]); acc[2][1] = fmaf(a.z, b.y, acc[2][1]); \
    acc[2][2] = fmaf(a.z, b.z, acc[2][2]); acc[2][3] = fmaf(a.z, b.w, acc[2][3]); \
    acc[3][0] = fmaf(a.w, b.x, acc[3][0]); acc[3][1] = fmaf(a.w, b.y, acc[3][1]); \
    acc[3][2] = fmaf(a.w, b.z, acc[3][2]); acc[3][3] = fmaf(a.w, b.w, acc[3][3])

#define FMA4(dst, p, v)  dst.x = fmaf(p, v.x, dst.x); dst.y = fmaf(p, v.y, dst.y); \
                         dst.z = fmaf(p, v.z, dst.z); dst.w = fmaf(p, v.w, dst.w)

// ---------------------------------------------------------------------------
// Kernel 1: QKV GEMM, split-K=2. blockIdx.z = mode*2 + ksplit. (unchanged r6)
// ---------------------------------------------------------------------------
__global__ __launch_bounds__(128) void gemm_qkv(
    const void* qp, const void* kp, const void* vp,
    const void* Wqp, const void* Wkp, const void* Wvp,
    const void* W1p, const void* W2p,
    const void* bqp, const void* bkp, const void* b1p, const void* b2p,
    float* __restrict__ ws)
{
    __shared__ int s_cnt;
    __shared__ __align__(16) float smem[6656];
    const int f = block_detect((const unsigned int*)qp, &s_cnt);

    const int z = blockIdx.z;
    const int mode = z >> 1, ks = z & 1;
    const int kbase = ks * 256;
    const void* A = (mode == 0) ? qp : (mode == 1) ? kp : vp;
    const void* W = (mode == 0) ? Wqp : (mode == 1) ? Wkp : Wvp;
    float* P = ws + OFF_P + (size_t)z * PSTRIDE;

    float* As = smem;            // [32][36] k-major
    float* Bs = smem + 1152;     // [32][68] k-major

    const int row0 = blockIdx.y * 32;
    const int col0 = blockIdx.x * 64;      // == one head (h = col0>>6)
    const int tid = threadIdx.x;

    const int alr = tid >> 2, alc = tid & 3;
    const int blr = tid >> 1, blc = tid & 1;
    const int tm = tid >> 4, tn = tid & 15;

    const size_t abase = (size_t)(row0 + alr) * 512;
    const size_t bbase = (size_t)(col0 + blr) * 512;

    float4 a0, a1, b0, b1, b2, b3;
    a0 = ld4(A, abase + kbase + alc * 4, f);
    a1 = ld4(A, abase + kbase + (alc + 4) * 4, f);
    b0 = ld4(W, bbase + kbase + (blc + 0) * 4, f);
    b1 = ld4(W, bbase + kbase + (blc + 2) * 4, f);
    b2 = ld4(W, bbase + kbase + (blc + 4) * 4, f);
    b3 = ld4(W, bbase + kbase + (blc + 6) * 4, f);

    float acc[4][4];
    #pragma unroll
    for (int i = 0; i < 4; i++)
        #pragma unroll
        for (int j = 0; j < 4; j++) acc[i][j] = 0.f;

    for (int k0 = kbase; k0 < kbase + 256; k0 += 32) {
        __syncthreads();
        As[(alc * 4 + 0) * 36 + alr] = a0.x; As[(alc * 4 + 1) * 36 + alr] = a0.y;
        As[(alc * 4 + 2) * 36 + alr] = a0.z; As[(alc * 4 + 3) * 36 + alr] = a0.w;
        As[((alc + 4) * 4 + 0) * 36 + alr] = a1.x; As[((alc + 4) * 4 + 1) * 36 + alr] = a1.y;
        As[((alc + 4) * 4 + 2) * 36 + alr] = a1.z; As[((alc + 4) * 4 + 3) * 36 + alr] = a1.w;
        Bs[((blc + 0) * 4 + 0) * 68 + blr] = b0.x; Bs[((blc + 0) * 4 + 1) * 68 + blr] = b0.y;
        Bs[((blc + 0) * 4 + 2) * 68 + blr] = b0.z; Bs[((blc + 0) * 4 + 3) * 68 + blr] = b0.w;
        Bs[((blc + 2) * 4 + 0) * 68 + blr] = b1.x; Bs[((blc + 2) * 4 + 1) * 68 + blr] = b1.y;
        Bs[((blc + 2) * 4 + 2) * 68 + blr] = b1.z; Bs[((blc + 2) * 4 + 3) * 68 + blr] = b1.w;
        Bs[((blc + 4) * 4 + 0) * 68 + blr] = b2.x; Bs[((blc + 4) * 4 + 1) * 68 + blr] = b2.y;
        Bs[((blc + 4) * 4 + 2) * 68 + blr] = b2.z; Bs[((blc + 4) * 4 + 3) * 68 + blr] = b2.w;
        Bs[((blc + 6) * 4 + 0) * 68 + blr] = b3.x; Bs[((blc + 6) * 4 + 1) * 68 + blr] = b3.y;
        Bs[((blc + 6) * 4 + 2) * 68 + blr] = b3.z; Bs[((blc + 6) * 4 + 3) * 68 + blr] = b3.w;
        __syncthreads();
        int k1 = k0 + 32;
        if (k1 < kbase + 256) {
            a0 = ld4(A, abase + k1 + alc * 4, f);
            a1 = ld4(A, abase + k1 + (alc + 4) * 4, f);
            b0 = ld4(W, bbase + k1 + (blc + 0) * 4, f);
            b1 = ld4(W, bbase + k1 + (blc + 2) * 4, f);
            b2 = ld4(W, bbase + k1 + (blc + 4) * 4, f);
            b3 = ld4(W, bbase + k1 + (blc + 6) * 4, f);
        }
        #pragma unroll
        for (int kk = 0; kk < 32; kk++) {
            float4 a = *reinterpret_cast<const float4*>(&As[kk * 36 + tm * 4]);
            float4 b = *reinterpret_cast<const float4*>(&Bs[kk * 68 + tn * 4]);
            MICRO_FMA(a, b);
        }
    }

    if (mode == 2) {
        #pragma unroll
        for (int i = 0; i < 4; i++) {
            int m = row0 + tm * 4 + i;
            float4 o4 = make_float4(acc[i][0], acc[i][1], acc[i][2], acc[i][3]);
            *reinterpret_cast<float4*>(&P[(size_t)m * 512 + col0 + tn * 4]) = o4;
        }
    } else {
        const void* W1x = mode ? W2p : W1p;
        float* Qs  = smem;           // [64 j][36 m]
        float* W1s = smem + 2304;    // [64 j][68 od]
        __syncthreads();
        #pragma unroll
        for (int i = 0; i < 4; i++)
            #pragma unroll
            for (int j = 0; j < 4; j++)
                Qs[(tn * 4 + j) * 36 + tm * 4 + i] = acc[i][j];
        {
            int od = tid >> 1;
            #pragma unroll
            for (int c = 0; c < 8; c++) {
                int j = (tid & 1) * 32 + c * 4;
                float4 w = ld4(W1x, (size_t)od * 64 + j, f);
                W1s[(j + 0) * 68 + od] = w.x; W1s[(j + 1) * 68 + od] = w.y;
                W1s[(j + 2) * 68 + od] = w.z; W1s[(j + 3) * 68 + od] = w.w;
            }
        }
        __syncthreads();
        {
            float acc[4][4];
            #pragma unroll
            for (int i = 0; i < 4; i++)
                #pragma unroll
                for (int j = 0; j < 4; j++) acc[i][j] = 0.f;
            #pragma unroll 8
            for (int kk = 0; kk < 64; kk++) {
                float4 a = *reinterpret_cast<const float4*>(&Qs[kk * 36 + tm * 4]);
                float4 b = *reinterpret_cast<const float4*>(&W1s[kk * 68 + tn * 4]);
                MICRO_FMA(a, b);
            }
            #pragma unroll
            for (int i = 0; i < 4; i++) {
                int m = row0 + tm * 4 + i;
                float4 o4 = make_float4(acc[i][0], acc[i][1], acc[i][2], acc[i][3]);
                *reinterpret_cast<float4*>(&P[(size_t)m * 512 + col0 + tn * 4]) = o4;
            }
        }
        if (blockIdx.y == 0 && ks == 0 && tid < 64) {
            int o = col0 + tid, od = o & 63, h = o >> 6;
            const void* b1x = mode ? b2p : b1p;
            const void* bx  = mode ? bkp : bqp;
            float s = ld1(b1x, od, f);
            for (int j = 0; j < 64; j++)
                s = fmaf(ld1(W1x, (size_t)od * 64 + j, f), ld1(bx, h * 64 + j, f), s);
            ws[(mode ? OFF_BKE : OFF_BQE) + o] = s;
        }
    }
}

// ---------------------------------------------------------------------------
// Kernel 2: finalize (unchanged r6).
// ---------------------------------------------------------------------------
__global__ __launch_bounds__(256) void finalize(
    const void* qp, const void* bvp,
    const float* __restrict__ ws_in, float* __restrict__ ws)
{
    __shared__ int s_cnt;
    __shared__ __align__(16) float T[64 * 68];
    const int f = block_detect((const unsigned int*)qp, &s_cnt);
    const int blk = blockIdx.x;
    const int tid = threadIdx.x;

    if (blk < 384 || blk >= 480) {
        const int isV = (blk >= 480);
        const float* P0 = ws_in + OFF_P + (size_t)(isV ? 4 : 0) * PSTRIDE;
        const float* P1 = P0 + PSTRIDE;
        float* Out = ws + (isV ? OFF_VH : OFF_ETQ);
        int gid = (isV ? blk - 480 : blk) * 256 + tid;
        int m = gid >> 7;
        int o4 = (gid & 127) * 4;
        float4 p0 = *reinterpret_cast<const float4*>(P0 + (size_t)m * 512 + o4);
        float4 p1 = *reinterpret_cast<const float4*>(P1 + (size_t)m * 512 + o4);
        float4 bb;
        if (isV) bb = ld4(bvp, o4, f);
        else     bb = *reinterpret_cast<const float4*>(ws_in + OFF_BQE + o4);
        float4 r;
        if (isV) {
            r.x = p0.x + p1.x + bb.x; r.y = p0.y + p1.y + bb.y;
            r.z = p0.z + p1.z + bb.z; r.w = p0.w + p1.w + bb.w;
        } else {
            r.x = __expf(2.f * (p0.x + p1.x + bb.x));
            r.y = __expf(2.f * (p0.y + p1.y + bb.y));
            r.z = __expf(2.f * (p0.z + p1.z + bb.z));
            r.w = __expf(2.f * (p0.w + p1.w + bb.w));
        }
        int b = m / LSEQ, l = m % LSEQ, h = o4 >> 6, d = o4 & 63;
        *reinterpret_cast<float4*>(&Out[(size_t)((b * NH + h) * LSEQ + l) * 64 + d]) = r;
    } else {
        int blk2 = blk - 384;              // 96 = 16 bh x 6 l-tiles
        int bh = blk2 / 6, l0 = (blk2 % 6) * 64;
        int b = bh >> 3, h = bh & 7;
        const float* P0 = ws_in + OFF_P + (size_t)2 * PSTRIDE;
        const float* P1 = P0 + PSTRIDE;
        #pragma unroll
        for (int it = 0; it < 4; it++) {
            int li = (tid >> 4) + it * 16;
            int d4 = (tid & 15) * 4;
            size_t src = (size_t)(b * LSEQ + l0 + li) * 512 + h * 64 + d4;
            float4 p0 = *reinterpret_cast<const float4*>(P0 + src);
            float4 p1 = *reinterpret_cast<const float4*>(P1 + src);
            const float4 bb = *reinterpret_cast<const float4*>(ws_in + OFF_BKE + h * 64 + d4);
            T[(d4 + 0) * 68 + li] = __expf(2.f * (p0.x + p1.x + bb.x));
            T[(d4 + 1) * 68 + li] = __expf(2.f * (p0.y + p1.y + bb.y));
            T[(d4 + 2) * 68 + li] = __expf(2.f * (p0.z + p1.z + bb.z));
            T[(d4 + 3) * 68 + li] = __expf(2.f * (p0.w + p1.w + bb.w));
        }
        __syncthreads();
        float* Out = ws + OFF_ETKT;
        #pragma unroll
        for (int it = 0; it < 4; it++) {
            int d = (tid >> 4) + it * 16;
            int l4 = (tid & 15) * 4;
            float4 v = *reinterpret_cast<const float4*>(&T[d * 68 + l4]);
            *reinterpret_cast<float4*>(&Out[(size_t)(bh * 64 + d) * LSEQ + l0 + l4]) = v;
        }
    }
}

// ---------------------------------------------------------------------------
// Kernel 3: additive attention, TQ=8 q-rows per block, 384 threads (t = k).
// Energy per element: e2 += vw_d * rcp(fma(Etq, Etk, 1.0)); LDS-broadcast
// q-side operands (2 x ds_read_b128 + 1 x b32 per d serve 24 VALU ops).
// ---------------------------------------------------------------------------
__global__ __launch_bounds__(384, 6) void attn_kernel(
    const void* qp, const void* vwp, const void* vbp,
    const float* __restrict__ ws_in, float* __restrict__ ws,
    const int* __restrict__ mask, void* __restrict__ dout)
{
    __shared__ int s_cnt;
    const int f = block_detect((const unsigned int*)qp, &s_cnt);

    const float* Etq = ws_in + OFF_ETQ;
    const float* Etk = ws_in + OFF_ETKT;
    const float* Vh  = ws_in + OFF_VH;
    float* Xh = ws + OFF_XH;

    const int bid = blockIdx.x;            // bh*QTILES + qt
    const int qt = bid % QTILES;
    const int bh = bid / QTILES;
    const int q0 = qt * TQ;
    const int b  = bh >> 3;
    const int h  = bh & 7;
    const int t  = threadIdx.x;            // 0..383 (= k)
    const int wave = t >> 6;

    __shared__ __align__(16) float etq8[64][TQ];   // [d][qi]
    __shared__ float vws[64];
    __shared__ float ps[TQ][LSEQ];
    __shared__ float red[6][TQ][16][4];
    __shared__ float rmax[TQ][6];
    __shared__ float rsum[TQ][6];
    __shared__ float s_vb;

    // stage Etq tile (8 rows x 64 d = 512) and vw into LDS
    for (int i = t; i < TQ * 64; i += 384) {
        int qi = i >> 6, d = i & 63;
        etq8[d][qi] = Etq[(size_t)(bh * LSEQ + q0 + qi) * 64 + d];
    }
    if (t < 64) {
        float v = ld1(vwp, t, f);
        vws[t] = v;
        #pragma unroll
        for (int off = 32; off > 0; off >>= 1) v += __shfl_xor(v, off, 64);
        if (t == 0) s_vb = ld1(vbp, 0, f) + v;
    }
    const int mok = mask[b * LSEQ + t];
    __syncthreads();
    const float vbSum = s_vb;

    // ---- energy for 8 q-rows ----
    float e2[TQ] = {0.f, 0.f, 0.f, 0.f, 0.f, 0.f, 0.f, 0.f};
    const float* ekp = Etk + (size_t)bh * 64 * LSEQ + t;
    #pragma unroll 4
    for (int d = 0; d < 64; d++) {
        float ekv = ekp[(size_t)d * LSEQ];          // vector, coalesced
        float4 eqA = *reinterpret_cast<const float4*>(&etq8[d][0]);  // broadcast
        float4 eqB = *reinterpret_cast<const float4*>(&etq8[d][4]);
        float w = vws[d];                           // broadcast b32
        e2[0] = fmaf(w, __builtin_amdgcn_rcpf(fmaf(eqA.x, ekv, 1.0f)), e2[0]);
        e2[1] = fmaf(w, __builtin_amdgcn_rcpf(fmaf(eqA.y, ekv, 1.0f)), e2[1]);
        e2[2] = fmaf(w, __builtin_amdgcn_rcpf(fmaf(eqA.z, ekv, 1.0f)), e2[2]);
        e2[3] = fmaf(w, __builtin_amdgcn_rcpf(fmaf(eqA.w, ekv, 1.0f)), e2[3]);
        e2[4] = fmaf(w, __builtin_amdgcn_rcpf(fmaf(eqB.x, ekv, 1.0f)), e2[4]);
        e2[5] = fmaf(w, __builtin_amdgcn_rcpf(fmaf(eqB.y, ekv, 1.0f)), e2[5]);
        e2[6] = fmaf(w, __builtin_amdgcn_rcpf(fmaf(eqB.z, ekv, 1.0f)), e2[6]);
        e2[7] = fmaf(w, __builtin_amdgcn_rcpf(fmaf(eqB.w, ekv, 1.0f)), e2[7]);
    }
    float en[TQ];
    #pragma unroll
    for (int qi = 0; qi < TQ; qi++) {
        en[qi] = fmaf(-2.0f, e2[qi], vbSum);
        if (mok == 0) en[qi] = -1e10f;
    }

    // ---- softmax (block-wide over 6 waves), batched for 8 rows ----
    #pragma unroll
    for (int qi = 0; qi < TQ; qi++) {
        float m = en[qi];
        #pragma unroll
        for (int off = 32; off > 0; off >>= 1) m = fmaxf(m, __shfl_xor(m, off, 64));
        if ((t & 63) == 0) rmax[qi][wave] = m;
    }
    __syncthreads();
    float p[TQ];
    #pragma unroll
    for (int qi = 0; qi < TQ; qi++) {
        float gm = fmaxf(fmaxf(fmaxf(rmax[qi][0], rmax[qi][1]),
                               fmaxf(rmax[qi][2], rmax[qi][3])),
                         fmaxf(rmax[qi][4], rmax[qi][5]));
        p[qi] = __expf(en[qi] - gm);
        float s = p[qi];
        #pragma unroll
        for (int off = 32; off > 0; off >>= 1) s += __shfl_xor(s, off, 64);
        if ((t & 63) == 0) rsum[qi][wave] = s;
    }
    __syncthreads();
    #pragma unroll
    for (int qi = 0; qi < TQ; qi++) {
        float gs = rsum[qi][0] + rsum[qi][1] + rsum[qi][2] +
                   rsum[qi][3] + rsum[qi][4] + rsum[qi][5];
        p[qi] *= 1.0f / gs;
        ps[qi][t] = p[qi];
        size_t aidx = XELEMS + (size_t)(bh * LSEQ + q0 + qi) * LSEQ + t;
        if (f) ((float*)dout)[aidx] = p[qi];
        else   ((ushort_t*)dout)[aidx] = f2bf(p[qi]);
    }
    __syncthreads();

    // ---- context: x[qi][d] = sum_k p[k] V[k][d]; float4 V reused across 8 qi ----
    const int dq = t & 15;
    const int ksub = t >> 4;               // 0..23
    const float* vb4 = Vh + (size_t)bh * LSEQ * 64 + dq * 4;
    float4 acc[TQ];
    #pragma unroll
    for (int qi = 0; qi < TQ; qi++) acc[qi] = make_float4(0.f, 0.f, 0.f, 0.f);
    for (int kk = ksub; kk < LSEQ; kk += 24) {
        float4 v4 = *reinterpret_cast<const float4*>(vb4 + (size_t)kk * 64);
        #pragma unroll
        for (int qi = 0; qi < TQ; qi++) {
            float pq = ps[qi][kk];
            FMA4(acc[qi], pq, v4);
        }
    }
    #pragma unroll
    for (int qi = 0; qi < TQ; qi++) {
        #pragma unroll
        for (int off = 16; off <= 32; off <<= 1) {
            acc[qi].x += __shfl_xor(acc[qi].x, off, 64);
            acc[qi].y += __shfl_xor(acc[qi].y, off, 64);
            acc[qi].z += __shfl_xor(acc[qi].z, off, 64);
            acc[qi].w += __shfl_xor(acc[qi].w, off, 64);
        }
    }
    if ((t & 63) < 16) {
        #pragma unroll
        for (int qi = 0; qi < TQ; qi++) {
            red[wave][qi][dq][0] = acc[qi].x;
            red[wave][qi][dq][1] = acc[qi].y;
            red[wave][qi][dq][2] = acc[qi].z;
            red[wave][qi][dq][3] = acc[qi].w;
        }
    }
    __syncthreads();
    if (t < 256) {
        int d = t & 63;
        #pragma unroll
        for (int half = 0; half < 2; half++) {
            int qi = (t >> 6) + half * 4;
            float sx = 0.f;
            #pragma unroll
            for (int w = 0; w < 6; w++) sx += red[w][qi][d >> 2][d & 3];
            Xh[((size_t)(b * LSEQ + q0 + qi) * NH + h) * 64 + d] = sx;
        }
    }
}

// ---------------------------------------------------------------------------
// Kernel 4: output projection, split-K=4 (z=ksplit, K-slab 128). Partials
// into the (now dead) P region in natural [m][n] fp32 layout.
// ---------------------------------------------------------------------------
__global__ __launch_bounds__(128) void gemm_out(
    const void* qp, const void* Wop,
    const float* __restrict__ ws_in, float* __restrict__ ws)
{
    __shared__ int s_cnt;
    __shared__ __align__(16) float As[32][36];
    __shared__ __align__(16) float Bs[32][68];
    const int f = block_detect((const unsigned int*)qp, &s_cnt);

    const float* Xh = ws_in + OFF_XH;
    const int ks = blockIdx.z;
    const int kbase = ks * 128;
    float* P = ws + OFF_P + (size_t)ks * PSTRIDE;

    const int row0 = blockIdx.y * 32;
    const int col0 = blockIdx.x * 64;
    const int tid = threadIdx.x;

    const int alr = tid >> 2, alc = tid & 3;
    const int blr = tid >> 1, blc = tid & 1;
    const int tm = tid >> 4, tn = tid & 15;

    const float* Ab = Xh + (size_t)(row0 + alr) * 512 + kbase;
    const size_t bbase = (size_t)(col0 + blr) * 512 + kbase;

    float4 a0, a1, b0, b1, b2, b3;
    a0 = *reinterpret_cast<const float4*>(Ab + alc * 4);
    a1 = *reinterpret_cast<const float4*>(Ab + (alc + 4) * 4);
    b0 = ld4(Wop, bbase + (blc + 0) * 4, f);
    b1 = ld4(Wop, bbase + (blc + 2) * 4, f);
    b2 = ld4(Wop, bbase + (blc + 4) * 4, f);
    b3 = ld4(Wop, bbase + (blc + 6) * 4, f);

    float acc[4][4];
    #pragma unroll
    for (int i = 0; i < 4; i++)
        #pragma unroll
        for (int j = 0; j < 4; j++) acc[i][j] = 0.f;

    for (int k0 = 0; k0 < 128; k0 += 32) {
        __syncthreads();
        As[alc * 4 + 0][alr] = a0.x; As[alc * 4 + 1][alr] = a0.y;
        As[alc * 4 + 2][alr] = a0.z; As[alc * 4 + 3][alr] = a0.w;
        As[(alc + 4) * 4 + 0][alr] = a1.x; As[(alc + 4) * 4 + 1][alr] = a1.y;
        As[(alc + 4) * 4 + 2][alr] = a1.z; As[(alc + 4) * 4 + 3][alr] = a1.w;
        Bs[(blc + 0) * 4 + 0][blr] = b0.x; Bs[(blc + 0) * 4 + 1][blr] = b0.y;
        Bs[(blc + 0) * 4 + 2][blr] = b0.z; Bs[(blc + 0) * 4 + 3][blr] = b0.w;
        Bs[(blc + 2) * 4 + 0][blr] = b1.x; Bs[(blc + 2) * 4 + 1][blr] = b1.y;
        Bs[(blc + 2) * 4 + 2][blr] = b1.z; Bs[(blc + 2) * 4 + 3][blr] = b1.w;
        Bs[(blc + 4) * 4 + 0][blr] = b2.x; Bs[(blc + 4) * 4 + 1][blr] = b2.y;
        Bs[(blc + 4) * 4 + 2][blr] = b2.z; Bs[(blc + 4) * 4 + 3][blr] = b2.w;
        Bs[(blc + 6) * 4 + 0][blr] = b3.x; Bs[(blc + 6) * 4 + 1][blr] = b3.y;
        Bs[(blc + 6) * 4 + 2][blr] = b3.z; Bs[(blc + 6) * 4 + 3][blr] = b3.w;
        __syncthreads();
        int k1 = k0 + 32;
        if (k1 < 128) {
            a0 = *reinterpret_cast<const float4*>(Ab + k1 + alc * 4);
            a1 = *reinterpret_cast<const float4*>(Ab + k1 + (alc + 4) * 4);
            b0 = ld4(Wop, bbase + k1 + (blc + 0) * 4, f);
            b1 = ld4(Wop, bbase + k1 + (blc + 2) * 4, f);
            b2 = ld4(Wop, bbase + k1 + (blc + 4) * 4, f);
            b3 = ld4(Wop, bbase + k1 + (blc + 6) * 4, f);
        }
        #pragma unroll
        for (int kk = 0; kk < 32; kk++) {
            float4 a = *reinterpret_cast<const float4*>(&As[kk][tm * 4]);
            float4 b = *reinterpret_cast<const float4*>(&Bs[kk][tn * 4]);
            MICRO_FMA(a, b);
        }
    }

    #pragma unroll
    for (int i = 0; i < 4; i++) {
        int m = row0 + tm * 4 + i;
        float4 o4 = make_float4(acc[i][0], acc[i][1], acc[i][2], acc[i][3]);
        *reinterpret_cast<float4*>(&P[(size_t)m * 512 + col0 + tn * 4]) = o4;
    }
}

// ---------------------------------------------------------------------------
// Kernel 5: out_reduce — x = sum of 4 partials + bo, dual-dtype write.
// ---------------------------------------------------------------------------
__global__ __launch_bounds__(256) void out_reduce(
    const void* qp, const void* bop,
    const float* __restrict__ ws_in, void* __restrict__ dout)
{
    __shared__ int s_cnt;
    const int f = block_detect((const unsigned int*)qp, &s_cnt);
    int gid = blockIdx.x * 256 + threadIdx.x;   // float4 index, 0..98303
    size_t idx = (size_t)gid * 4;
    int o4 = (int)(idx & 511);
    const float* P = ws_in + OFF_P;
    float4 s0 = *reinterpret_cast<const float4*>(P + idx);
    float4 s1 = *reinterpret_cast<const float4*>(P + PSTRIDE + idx);
    float4 s2 = *reinterpret_cast<const float4*>(P + 2 * (size_t)PSTRIDE + idx);
    float4 s3 = *reinterpret_cast<const float4*>(P + 3 * (size_t)PSTRIDE + idx);
    float4 bb = ld4(bop, o4, f);
    float4 r;
    r.x = (s0.x + s1.x) + (s2.x + s3.x) + bb.x;
    r.y = (s0.y + s1.y) + (s2.y + s3.y) + bb.y;
    r.z = (s0.z + s1.z) + (s2.z + s3.z) + bb.z;
    r.w = (s0.w + s1.w) + (s2.w + s3.w) + bb.w;
    if (f) {
        *reinterpret_cast<float4*>((float*)dout + idx) = r;
    } else {
        ushort4 u;
        u.x = f2bf(r.x); u.y = f2bf(r.y); u.z = f2bf(r.z); u.w = f2bf(r.w);
        *reinterpret_cast<ushort4*>((ushort_t*)dout + idx) = u;
    }
}

// ---------------------------------------------------------------------------
extern "C" void kernel_launch(void* const* d_in, const int* in_sizes, int n_in,
                              void* d_out, int out_size, void* d_ws, size_t ws_size,
                              hipStream_t stream)
{
    const void* qp = d_in[0];
    const void* kp = d_in[1];
    const void* vp = d_in[2];
    const int* mask = (const int*)d_in[3];
    const void* Wqp = d_in[4];  const void* bqp = d_in[5];
    const void* Wkp = d_in[6];  const void* bkp = d_in[7];
    const void* Wvp = d_in[8];  const void* bvp = d_in[9];
    const void* Wop = d_in[10]; const void* bop = d_in[11];
    const void* W1p = d_in[12]; const void* b1p = d_in[13];
    const void* W2p = d_in[14]; const void* b2p = d_in[15];
    const void* vwp = d_in[16]; const void* vbp = d_in[17];

    float* ws = (float*)d_ws;

    gemm_qkv<<<dim3(8, 24, 6), 128, 0, stream>>>(qp, kp, vp, Wqp, Wkp, Wvp,
                                                 W1p, W2p, bqp, bkp, b1p, b2p, ws);
    finalize<<<864, 256, 0, stream>>>(qp, bvp, ws, ws);
    attn_kernel<<<BH * QTILES, 384, 0, stream>>>(qp, vwp, vbp, ws, ws, mask, d_out);
    gemm_out<<<dim3(8, 24, 4), 128, 0, stream>>>(qp, Wop, ws, ws);
    out_reduce<<<384, 256, 0, stream>>>(qp, bop, ws, d_out);
}

// Round 9
// 168.959 us; speedup vs baseline: 2.5091x; 1.0525x over previous
//
#include <hip/hip_runtime.h>

// Problem constants
#define BATCH 2
#define LSEQ 384
#define NHID 512
#define NH 8
#define DH 64
#define BH (BATCH*NH)          // 16
#define MROWS (BATCH*NH*LSEQ/NH)           // 768
#define XELEMS ((size_t)768 * NHID)        // 393216 (x output elems)
#define TQ 8                   // q-rows per attn block
#define QTILES (LSEQ/TQ)       // 48

typedef unsigned short ushort_t;
typedef __attribute__((ext_vector_type(8))) short bf16x8;
typedef __attribute__((ext_vector_type(4))) float f32x4;

__device__ __forceinline__ float bf2f(ushort_t u) {
    unsigned int v = ((unsigned int)u) << 16;
    return __uint_as_float(v);
}
__device__ __forceinline__ ushort_t f2bf(float f) {
    unsigned int u = __float_as_uint(f);
    unsigned int lsb = (u >> 16) & 1u;
    u += 0x7fffu + lsb;           // round-to-nearest-even
    return (ushort_t)(u >> 16);
}
// dual-path loads: f=1 -> fp32, f=0 -> packed bf16 (wave-uniform branch)
__device__ __forceinline__ float ld1(const void* p, size_t i, int f) {
    return f ? ((const float*)p)[i] : bf2f(((const ushort_t*)p)[i]);
}
__device__ __forceinline__ float4 ld4(const void* p, size_t i, int f) {
    if (f) return ((const float4*)p)[i >> 2];
    ushort4 u = ((const ushort4*)p)[i >> 2];
    return make_float4(bf2f(u.x), bf2f(u.y), bf2f(u.z), bf2f(u.w));
}
__device__ __forceinline__ int block_detect(const unsigned int* q, int* cnt) {
    int t = threadIdx.x;
    if (t == 0) *cnt = 0;
    __syncthreads();
    int n = blockDim.x < 256 ? blockDim.x : 256;
    if (t < n) {
        unsigned int elo = (q[t] >> 7) & 0xFFu;
        if (elo >= 100u && elo <= 150u) atomicAdd(cnt, 1);
    }
    __syncthreads();
    return (*cnt * 2 > n) ? 0 : 1;     // 0 = bf16-packed, 1 = fp32
}
// pack 8 fp32 -> 8 bf16 in two uint4-storable halves
__device__ __forceinline__ uint4 packu4(float4 a, float4 b) {
    uint4 r;
    r.x = (unsigned)f2bf(a.x) | ((unsigned)f2bf(a.y) << 16);
    r.y = (unsigned)f2bf(a.z) | ((unsigned)f2bf(a.w) << 16);
    r.z = (unsigned)f2bf(b.x) | ((unsigned)f2bf(b.y) << 16);
    r.w = (unsigned)f2bf(b.z) | ((unsigned)f2bf(b.w) << 16);
    return r;
}
__device__ __forceinline__ bf16x8 pack_bf8(float4 a, float4 b) {
    bf16x8 r;
    r[0] = (short)f2bf(a.x); r[1] = (short)f2bf(a.y);
    r[2] = (short)f2bf(a.z); r[3] = (short)f2bf(a.w);
    r[4] = (short)f2bf(b.x); r[5] = (short)f2bf(b.y);
    r[6] = (short)f2bf(b.z); r[7] = (short)f2bf(b.w);
    return r;
}

// ---------------- workspace layout (float offsets) ----------------
#define OFF_ETQ   16                    // Etq = exp(2 tq)  [bh][l][d]
#define OFF_ETKT  (16 + 393216)         // Etk = exp(2 tk)  [bh][d][l]
#define OFF_VH    (16 + 2*393216)       // V                [bh][l][d]
#define OFF_XH    (16 + 3*393216)       // context [B,L,H,D]

#define LDSTR 72   // LDS row stride in ushorts (144 B: 16-B aligned, <=2-way banks)

// ---------------------------------------------------------------------------
// Kernel 1: QKV projection via bf16 MFMA. Tile 32(m) x 64(n=one head), 128 thr
// (2 waves; wave w owns m-strip w*16..w*16+16). K=512 in steps of 64.
// mode 0: Etq = exp(2(QWq^T W1^T + biasF))  -> [bh][l][d]
// mode 1: Etk transposed                    -> [bh][d][l] (float4 stores)
// mode 2: V = V Wv^T + bv                   -> [bh][l][d]
// MFMA layouts (HW-verified, cdna_hip_programming.md §3):
//   A-frag: lane holds A[m=l&15][k=quad*8+j]; B-frag: W row, k-contiguous;
//   C/D: col = l&15, row = quad*4 + reg.
// ---------------------------------------------------------------------------
__global__ __launch_bounds__(128) void gemm_qkv(
    const void* qp, const void* kp, const void* vp,
    const void* Wqp, const void* Wkp, const void* Wvp,
    const void* W1p, const void* W2p,
    const void* bqp, const void* bkp, const void* b1p, const void* b2p,
    const void* bvp, float* __restrict__ ws)
{
    __shared__ int s_cnt;
    __shared__ ushort_t smA[32 * LDSTR];
    __shared__ ushort_t smB[64 * LDSTR];
    __shared__ float biasF[64];
    const int f = block_detect((const unsigned int*)qp, &s_cnt);

    const int mode = blockIdx.z;
    const void* A = (mode == 0) ? qp : (mode == 1) ? kp : vp;
    const void* W = (mode == 0) ? Wqp : (mode == 1) ? Wkp : Wvp;
    const void* W1x = (mode == 1) ? W2p : W1p;

    const int h    = blockIdx.x;          // head = n-block
    const int col0 = h * 64;
    const int row0 = blockIdx.y * 32;
    const int t = threadIdx.x;
    const int w = t >> 6, l16 = t & 15, quad = (t & 63) >> 4;

    // fused bias into LDS (threads 0..63), overlapped with prefetch
    if (t < 64) {
        if (mode == 2) {
            biasF[t] = ld1(bvp, col0 + t, f);
        } else {
            const void* b1x = (mode == 1) ? b2p : b1p;
            const void* bx  = (mode == 1) ? bkp : bqp;
            float s = ld1(b1x, t, f);
            for (int j = 0; j < 64; j++)
                s = fmaf(ld1(W1x, (size_t)t * 64 + j, f), ld1(bx, h * 64 + j, f), s);
            biasF[t] = s;
        }
    }

    // staging assignment
    const int arow = t >> 2, acol = (t & 3) * 16;   // A: 32r x 4 groups of 16
    const int brow = t >> 1, bcol = (t & 1) * 32;   // B: 64r x 2 groups of 32

    const size_t abase = (size_t)(row0 + arow) * 512 + acol;
    const size_t bbase = (size_t)(col0 + brow) * 512 + bcol;

    float4 a4[4], b4[8];
    #pragma unroll
    for (int i = 0; i < 4; i++) a4[i] = ld4(A, abase + i * 4, f);
    #pragma unroll
    for (int i = 0; i < 8; i++) b4[i] = ld4(W, bbase + i * 4, f);

    f32x4 acc[4];
    #pragma unroll
    for (int nt = 0; nt < 4; nt++) acc[nt] = (f32x4){0.f, 0.f, 0.f, 0.f};

    for (int k0 = 0; k0 < 512; k0 += 64) {
        __syncthreads();
        *reinterpret_cast<uint4*>(&smA[arow * LDSTR + acol])     = packu4(a4[0], a4[1]);
        *reinterpret_cast<uint4*>(&smA[arow * LDSTR + acol + 8]) = packu4(a4[2], a4[3]);
        *reinterpret_cast<uint4*>(&smB[brow * LDSTR + bcol])      = packu4(b4[0], b4[1]);
        *reinterpret_cast<uint4*>(&smB[brow * LDSTR + bcol + 8])  = packu4(b4[2], b4[3]);
        *reinterpret_cast<uint4*>(&smB[brow * LDSTR + bcol + 16]) = packu4(b4[4], b4[5]);
        *reinterpret_cast<uint4*>(&smB[brow * LDSTR + bcol + 24]) = packu4(b4[6], b4[7]);
        __syncthreads();
        if (k0 + 64 < 512) {
            #pragma unroll
            for (int i = 0; i < 4; i++) a4[i] = ld4(A, abase + k0 + 64 + i * 4, f);
            #pragma unroll
            for (int i = 0; i < 8; i++) b4[i] = ld4(W, bbase + k0 + 64 + i * 4, f);
        }
        #pragma unroll
        for (int kk = 0; kk < 2; kk++) {
            bf16x8 af = *reinterpret_cast<const bf16x8*>(
                &smA[(w * 16 + l16) * LDSTR + kk * 32 + quad * 8]);
            #pragma unroll
            for (int nt = 0; nt < 4; nt++) {
                bf16x8 bfr = *reinterpret_cast<const bf16x8*>(
                    &smB[(nt * 16 + l16) * LDSTR + kk * 32 + quad * 8]);
                acc[nt] = __builtin_amdgcn_mfma_f32_16x16x32_bf16(af, bfr, acc[nt], 0, 0, 0);
            }
        }
    }

    const int b  = (row0 >= LSEQ) ? 1 : 0;
    const int lbase = row0 - b * LSEQ + w * 16;
    const int bh = b * NH + h;

    if (mode == 2) {
        float* Out = ws + OFF_VH;
        #pragma unroll
        for (int nt = 0; nt < 4; nt++) {
            int d = l16 + nt * 16;
            #pragma unroll
            for (int r = 0; r < 4; r++) {
                int l = lbase + quad * 4 + r;
                Out[(size_t)(bh * LSEQ + l) * 64 + d] = acc[nt][r] + biasF[d];
            }
        }
    } else {
        // ---- fold: restage acc (bf16) in wave-private LDS rows, x W1^T ----
        #pragma unroll
        for (int nt = 0; nt < 4; nt++)
            #pragma unroll
            for (int r = 0; r < 4; r++)
                smA[(w * 16 + quad * 4 + r) * LDSTR + l16 + nt * 16] =
                    f2bf(acc[nt][r]);
        // (wave-private rows: no block barrier; in-wave DS order via waitcnt)
        f32x4 acc2[4];
        #pragma unroll
        for (int nt = 0; nt < 4; nt++) acc2[nt] = (f32x4){0.f, 0.f, 0.f, 0.f};
        #pragma unroll
        for (int kk = 0; kk < 2; kk++) {
            bf16x8 af2 = *reinterpret_cast<const bf16x8*>(
                &smA[(w * 16 + l16) * LDSTR + kk * 32 + quad * 8]);
            #pragma unroll
            for (int nt = 0; nt < 4; nt++) {
                int od = nt * 16 + l16, j0 = kk * 32 + quad * 8;
                float4 wa = ld4(W1x, (size_t)od * 64 + j0, f);
                float4 wb = ld4(W1x, (size_t)od * 64 + j0 + 4, f);
                bf16x8 bfw = pack_bf8(wa, wb);
                acc2[nt] = __builtin_amdgcn_mfma_f32_16x16x32_bf16(af2, bfw, acc2[nt], 0, 0, 0);
            }
        }
        if (mode == 0) {
            float* Out = ws + OFF_ETQ;
            #pragma unroll
            for (int nt = 0; nt < 4; nt++) {
                int d = l16 + nt * 16;
                #pragma unroll
                for (int r = 0; r < 4; r++) {
                    int l = lbase + quad * 4 + r;
                    Out[(size_t)(bh * LSEQ + l) * 64 + d] =
                        __expf(2.f * (acc2[nt][r] + biasF[d]));
                }
            }
        } else {
            float* Out = ws + OFF_ETKT;
            #pragma unroll
            for (int nt = 0; nt < 4; nt++) {
                int d = l16 + nt * 16;
                float4 o;
                o.x = __expf(2.f * (acc2[nt][0] + biasF[d]));
                o.y = __expf(2.f * (acc2[nt][1] + biasF[d]));
                o.z = __expf(2.f * (acc2[nt][2] + biasF[d]));
                o.w = __expf(2.f * (acc2[nt][3] + biasF[d]));
                *reinterpret_cast<float4*>(
                    &Out[(size_t)(bh * 64 + d) * LSEQ + lbase + quad * 4]) = o;
            }
        }
    }
}

// ---------------------------------------------------------------------------
// Kernel 2: additive attention, TQ=8 q-rows per block, 384 threads (t = k).
// Energy: e2 += vw_d * rcp(fma(Etq, Etk, 1.0)); e = vbSum - 2*e2. (r8 kernel)
// ---------------------------------------------------------------------------
__global__ __launch_bounds__(384, 6) void attn_kernel(
    const void* qp, const void* vwp, const void* vbp,
    const float* __restrict__ ws_in, float* __restrict__ ws,
    const int* __restrict__ mask, void* __restrict__ dout)
{
    __shared__ int s_cnt;
    const int f = block_detect((const unsigned int*)qp, &s_cnt);

    const float* Etq = ws_in + OFF_ETQ;
    const float* Etk = ws_in + OFF_ETKT;
    const float* Vh  = ws_in + OFF_VH;
    float* Xh = ws + OFF_XH;

    const int bid = blockIdx.x;
    const int qt = bid % QTILES;
    const int bh = bid / QTILES;
    const int q0 = qt * TQ;
    const int b  = bh >> 3;
    const int h  = bh & 7;
    const int t  = threadIdx.x;
    const int wave = t >> 6;

    __shared__ __align__(16) float etq8[64][TQ];
    __shared__ float vws[64];
    __shared__ float ps[TQ][LSEQ];
    __shared__ float red[6][TQ][16][4];
    __shared__ float rmax[TQ][6];
    __shared__ float rsum[TQ][6];
    __shared__ float s_vb;

    for (int i = t; i < TQ * 64; i += 384) {
        int qi = i >> 6, d = i & 63;
        etq8[d][qi] = Etq[(size_t)(bh * LSEQ + q0 + qi) * 64 + d];
    }
    if (t < 64) {
        float v = ld1(vwp, t, f);
        vws[t] = v;
        #pragma unroll
        for (int off = 32; off > 0; off >>= 1) v += __shfl_xor(v, off, 64);
        if (t == 0) s_vb = ld1(vbp, 0, f) + v;
    }
    const int mok = mask[b * LSEQ + t];
    __syncthreads();
    const float vbSum = s_vb;

    float e2[TQ] = {0.f, 0.f, 0.f, 0.f, 0.f, 0.f, 0.f, 0.f};
    const float* ekp = Etk + (size_t)bh * 64 * LSEQ + t;
    #pragma unroll 4
    for (int d = 0; d < 64; d++) {
        float ekv = ekp[(size_t)d * LSEQ];
        float4 eqA = *reinterpret_cast<const float4*>(&etq8[d][0]);
        float4 eqB = *reinterpret_cast<const float4*>(&etq8[d][4]);
        float wv = vws[d];
        e2[0] = fmaf(wv, __builtin_amdgcn_rcpf(fmaf(eqA.x, ekv, 1.0f)), e2[0]);
        e2[1] = fmaf(wv, __builtin_amdgcn_rcpf(fmaf(eqA.y, ekv, 1.0f)), e2[1]);
        e2[2] = fmaf(wv, __builtin_amdgcn_rcpf(fmaf(eqA.z, ekv, 1.0f)), e2[2]);
        e2[3] = fmaf(wv, __builtin_amdgcn_rcpf(fmaf(eqA.w, ekv, 1.0f)), e2[3]);
        e2[4] = fmaf(wv, __builtin_amdgcn_rcpf(fmaf(eqB.x, ekv, 1.0f)), e2[4]);
        e2[5] = fmaf(wv, __builtin_amdgcn_rcpf(fmaf(eqB.y, ekv, 1.0f)), e2[5]);
        e2[6] = fmaf(wv, __builtin_amdgcn_rcpf(fmaf(eqB.z, ekv, 1.0f)), e2[6]);
        e2[7] = fmaf(wv, __builtin_amdgcn_rcpf(fmaf(eqB.w, ekv, 1.0f)), e2[7]);
    }
    float en[TQ];
    #pragma unroll
    for (int qi = 0; qi < TQ; qi++) {
        en[qi] = fmaf(-2.0f, e2[qi], vbSum);
        if (mok == 0) en[qi] = -1e10f;
    }

    #pragma unroll
    for (int qi = 0; qi < TQ; qi++) {
        float m = en[qi];
        #pragma unroll
        for (int off = 32; off > 0; off >>= 1) m = fmaxf(m, __shfl_xor(m, off, 64));
        if ((t & 63) == 0) rmax[qi][wave] = m;
    }
    __syncthreads();
    float p[TQ];
    #pragma unroll
    for (int qi = 0; qi < TQ; qi++) {
        float gm = fmaxf(fmaxf(fmaxf(rmax[qi][0], rmax[qi][1]),
                               fmaxf(rmax[qi][2], rmax[qi][3])),
                         fmaxf(rmax[qi][4], rmax[qi][5]));
        p[qi] = __expf(en[qi] - gm);
        float s = p[qi];
        #pragma unroll
        for (int off = 32; off > 0; off >>= 1) s += __shfl_xor(s, off, 64);
        if ((t & 63) == 0) rsum[qi][wave] = s;
    }
    __syncthreads();
    #pragma unroll
    for (int qi = 0; qi < TQ; qi++) {
        float gs = rsum[qi][0] + rsum[qi][1] + rsum[qi][2] +
                   rsum[qi][3] + rsum[qi][4] + rsum[qi][5];
        p[qi] *= 1.0f / gs;
        ps[qi][t] = p[qi];
        size_t aidx = XELEMS + (size_t)(bh * LSEQ + q0 + qi) * LSEQ + t;
        if (f) ((float*)dout)[aidx] = p[qi];
        else   ((ushort_t*)dout)[aidx] = f2bf(p[qi]);
    }
    __syncthreads();

    const int dq = t & 15;
    const int ksub = t >> 4;
    const float* vb4 = Vh + (size_t)bh * LSEQ * 64 + dq * 4;
    float4 acc[TQ];
    #pragma unroll
    for (int qi = 0; qi < TQ; qi++) acc[qi] = make_float4(0.f, 0.f, 0.f, 0.f);
    for (int kk = ksub; kk < LSEQ; kk += 24) {
        float4 v4 = *reinterpret_cast<const float4*>(vb4 + (size_t)kk * 64);
        #pragma unroll
        for (int qi = 0; qi < TQ; qi++) {
            float pq = ps[qi][kk];
            acc[qi].x = fmaf(pq, v4.x, acc[qi].x);
            acc[qi].y = fmaf(pq, v4.y, acc[qi].y);
            acc[qi].z = fmaf(pq, v4.z, acc[qi].z);
            acc[qi].w = fmaf(pq, v4.w, acc[qi].w);
        }
    }
    #pragma unroll
    for (int qi = 0; qi < TQ; qi++) {
        #pragma unroll
        for (int off = 16; off <= 32; off <<= 1) {
            acc[qi].x += __shfl_xor(acc[qi].x, off, 64);
            acc[qi].y += __shfl_xor(acc[qi].y, off, 64);
            acc[qi].z += __shfl_xor(acc[qi].z, off, 64);
            acc[qi].w += __shfl_xor(acc[qi].w, off, 64);
        }
    }
    if ((t & 63) < 16) {
        #pragma unroll
        for (int qi = 0; qi < TQ; qi++) {
            red[wave][qi][dq][0] = acc[qi].x;
            red[wave][qi][dq][1] = acc[qi].y;
            red[wave][qi][dq][2] = acc[qi].z;
            red[wave][qi][dq][3] = acc[qi].w;
        }
    }
    __syncthreads();
    if (t < 256) {
        int d = t & 63;
        #pragma unroll
        for (int half = 0; half < 2; half++) {
            int qi = (t >> 6) + half * 4;
            float sx = 0.f;
            #pragma unroll
            for (int w = 0; w < 6; w++) sx += red[w][qi][d >> 2][d & 3];
            Xh[((size_t)(b * LSEQ + q0 + qi) * NH + h) * 64 + d] = sx;
        }
    }
}

// ---------------------------------------------------------------------------
// Kernel 3: output projection via bf16 MFMA. x = Xh @ Wo^T + bo, dual-dtype.
// Same 32x64 / 2-wave template as gemm_qkv.
// ---------------------------------------------------------------------------
__global__ __launch_bounds__(128) void gemm_out(
    const void* qp, const void* Wop, const void* bop,
    const float* __restrict__ ws_in, void* __restrict__ dout)
{
    __shared__ int s_cnt;
    __shared__ ushort_t smA[32 * LDSTR];
    __shared__ ushort_t smB[64 * LDSTR];
    __shared__ float biasF[64];
    const int f = block_detect((const unsigned int*)qp, &s_cnt);

    const float* Xh = ws_in + OFF_XH;
    const int col0 = blockIdx.x * 64;
    const int row0 = blockIdx.y * 32;
    const int t = threadIdx.x;
    const int w = t >> 6, l16 = t & 15, quad = (t & 63) >> 4;

    if (t < 64) biasF[t] = ld1(bop, col0 + t, f);

    const int arow = t >> 2, acol = (t & 3) * 16;
    const int brow = t >> 1, bcol = (t & 1) * 32;
    const float* Ab = Xh + (size_t)(row0 + arow) * 512 + acol;
    const size_t bbase = (size_t)(col0 + brow) * 512 + bcol;

    float4 a4[4], b4[8];
    #pragma unroll
    for (int i = 0; i < 4; i++) a4[i] = *reinterpret_cast<const float4*>(Ab + i * 4);
    #pragma unroll
    for (int i = 0; i < 8; i++) b4[i] = ld4(Wop, bbase + i * 4, f);

    f32x4 acc[4];
    #pragma unroll
    for (int nt = 0; nt < 4; nt++) acc[nt] = (f32x4){0.f, 0.f, 0.f, 0.f};

    for (int k0 = 0; k0 < 512; k0 += 64) {
        __syncthreads();
        *reinterpret_cast<uint4*>(&smA[arow * LDSTR + acol])     = packu4(a4[0], a4[1]);
        *reinterpret_cast<uint4*>(&smA[arow * LDSTR + acol + 8]) = packu4(a4[2], a4[3]);
        *reinterpret_cast<uint4*>(&smB[brow * LDSTR + bcol])      = packu4(b4[0], b4[1]);
        *reinterpret_cast<uint4*>(&smB[brow * LDSTR + bcol + 8])  = packu4(b4[2], b4[3]);
        *reinterpret_cast<uint4*>(&smB[brow * LDSTR + bcol + 16]) = packu4(b4[4], b4[5]);
        *reinterpret_cast<uint4*>(&smB[brow * LDSTR + bcol + 24]) = packu4(b4[6], b4[7]);
        __syncthreads();
        if (k0 + 64 < 512) {
            #pragma unroll
            for (int i = 0; i < 4; i++)
                a4[i] = *reinterpret_cast<const float4*>(Ab + k0 + 64 + i * 4);
            #pragma unroll
            for (int i = 0; i < 8; i++) b4[i] = ld4(Wop, bbase + k0 + 64 + i * 4, f);
        }
        #pragma unroll
        for (int kk = 0; kk < 2; kk++) {
            bf16x8 af = *reinterpret_cast<const bf16x8*>(
                &smA[(w * 16 + l16) * LDSTR + kk * 32 + quad * 8]);
            #pragma unroll
            for (int nt = 0; nt < 4; nt++) {
                bf16x8 bfr = *reinterpret_cast<const bf16x8*>(
                    &smB[(nt * 16 + l16) * LDSTR + kk * 32 + quad * 8]);
                acc[nt] = __builtin_amdgcn_mfma_f32_16x16x32_bf16(af, bfr, acc[nt], 0, 0, 0);
            }
        }
    }

    #pragma unroll
    for (int nt = 0; nt < 4; nt++) {
        int n = col0 + l16 + nt * 16;
        float bi = biasF[l16 + nt * 16];
        #pragma unroll
        for (int r = 0; r < 4; r++) {
            int m = row0 + w * 16 + quad * 4 + r;
            float c = acc[nt][r] + bi;
            size_t idx = (size_t)m * 512 + n;
            if (f) ((float*)dout)[idx] = c;
            else   ((ushort_t*)dout)[idx] = f2bf(c);
        }
    }
}

// ---------------------------------------------------------------------------
extern "C" void kernel_launch(void* const* d_in, const int* in_sizes, int n_in,
                              void* d_out, int out_size, void* d_ws, size_t ws_size,
                              hipStream_t stream)
{
    const void* qp = d_in[0];
    const void* kp = d_in[1];
    const void* vp = d_in[2];
    const int* mask = (const int*)d_in[3];
    const void* Wqp = d_in[4];  const void* bqp = d_in[5];
    const void* Wkp = d_in[6];  const void* bkp = d_in[7];
    const void* Wvp = d_in[8];  const void* bvp = d_in[9];
    const void* Wop = d_in[10]; const void* bop = d_in[11];
    const void* W1p = d_in[12]; const void* b1p = d_in[13];
    const void* W2p = d_in[14]; const void* b2p = d_in[15];
    const void* vwp = d_in[16]; const void* vbp = d_in[17];

    float* ws = (float*)d_ws;

    gemm_qkv<<<dim3(8, 24, 3), 128, 0, stream>>>(qp, kp, vp, Wqp, Wkp, Wvp,
                                                 W1p, W2p, bqp, bkp, b1p, b2p,
                                                 bvp, ws);
    attn_kernel<<<BH * QTILES, 384, 0, stream>>>(qp, vwp, vbp, ws, ws, mask, d_out);
    gemm_out<<<dim3(8, 24, 1), 128, 0, stream>>>(qp, Wop, bop, ws, d_out);
}

// Round 10
// 167.984 us; speedup vs baseline: 2.5236x; 1.0058x over previous
//
#include <hip/hip_runtime.h>

// Problem constants
#define BATCH 2
#define LSEQ 384
#define NHID 512
#define NH 8
#define DH 64
#define BH (BATCH*NH)          // 16
#define XELEMS ((size_t)768 * NHID)        // 393216 (x output elems)
#define TQ 8                   // q-rows per attn block
#define QTILES (LSEQ/TQ)       // 48

typedef unsigned short ushort_t;
typedef __attribute__((ext_vector_type(8))) short bf16x8;
typedef __attribute__((ext_vector_type(4))) float f32x4;

__device__ __forceinline__ float bf2f(ushort_t u) {
    unsigned int v = ((unsigned int)u) << 16;
    return __uint_as_float(v);
}
__device__ __forceinline__ ushort_t f2bf(float f) {
    unsigned int u = __float_as_uint(f);
    unsigned int lsb = (u >> 16) & 1u;
    u += 0x7fffu + lsb;           // round-to-nearest-even
    return (ushort_t)(u >> 16);
}
__device__ __forceinline__ float ld1(const void* p, size_t i, int f) {
    return f ? ((const float*)p)[i] : bf2f(((const ushort_t*)p)[i]);
}
__device__ __forceinline__ float4 ld4(const void* p, size_t i, int f) {
    if (f) return ((const float4*)p)[i >> 2];
    ushort4 u = ((const ushort4*)p)[i >> 2];
    return make_float4(bf2f(u.x), bf2f(u.y), bf2f(u.z), bf2f(u.w));
}
__device__ __forceinline__ int block_detect(const unsigned int* q, int* cnt) {
    int t = threadIdx.x;
    if (t == 0) *cnt = 0;
    __syncthreads();
    int n = blockDim.x < 256 ? blockDim.x : 256;
    if (t < n) {
        unsigned int elo = (q[t] >> 7) & 0xFFu;
        if (elo >= 100u && elo <= 150u) atomicAdd(cnt, 1);
    }
    __syncthreads();
    return (*cnt * 2 > n) ? 0 : 1;     // 0 = bf16-packed, 1 = fp32
}
__device__ __forceinline__ uint4 packu4(float4 a, float4 b) {
    uint4 r;
    r.x = (unsigned)f2bf(a.x) | ((unsigned)f2bf(a.y) << 16);
    r.y = (unsigned)f2bf(a.z) | ((unsigned)f2bf(a.w) << 16);
    r.z = (unsigned)f2bf(b.x) | ((unsigned)f2bf(b.y) << 16);
    r.w = (unsigned)f2bf(b.z) | ((unsigned)f2bf(b.w) << 16);
    return r;
}
__device__ __forceinline__ bf16x8 pack_bf8(float4 a, float4 b) {
    bf16x8 r;
    r[0] = (short)f2bf(a.x); r[1] = (short)f2bf(a.y);
    r[2] = (short)f2bf(a.z); r[3] = (short)f2bf(a.w);
    r[4] = (short)f2bf(b.x); r[5] = (short)f2bf(b.y);
    r[6] = (short)f2bf(b.z); r[7] = (short)f2bf(b.w);
    return r;
}

// ---------------- workspace layout (float offsets) ----------------
#define OFF_P     16
#define PSTRIDE   393216
#define OFF_BQE   2359312   // fused bias (b1 + W1@bq)
#define OFF_BKE   2359824
#define OFF_ETQ   2360336   // Etq = exp(2 tq)  [bh][l][d]
#define OFF_ETKT  2753552   // Etk = exp(2 tk)  [bh][d][l]
#define OFF_VH    3146768   // V                [bh][l][d]
#define OFF_XH    3539984   // context [B,L,H,D]
// end = 3933200 floats = 15.7 MB

#define LDSTR 72   // LDS row stride in ushorts (144 B)

// ---------------------------------------------------------------------------
// Kernel 1: QKV GEMM via bf16 MFMA, split-K=2. z = mode*2 + ks, K-slab 256.
// 32(m) x 64(n=head) tile, 128 thr (2 waves). Modes 0/1 apply the W1/W2 fold
// per split (linear). Partials -> P[z] in natural [m][o] fp32 layout.
// ---------------------------------------------------------------------------
__global__ __launch_bounds__(128) void gemm_qkv(
    const void* qp, const void* kp, const void* vp,
    const void* Wqp, const void* Wkp, const void* Wvp,
    const void* W1p, const void* W2p,
    const void* bqp, const void* bkp, const void* b1p, const void* b2p,
    float* __restrict__ ws)
{
    __shared__ int s_cnt;
    __shared__ ushort_t smA[32 * LDSTR];
    __shared__ ushort_t smB[64 * LDSTR];
    const int f = block_detect((const unsigned int*)qp, &s_cnt);

    const int z = blockIdx.z;
    const int mode = z >> 1, ks = z & 1;
    const int kbase = ks * 256;
    const void* A = (mode == 0) ? qp : (mode == 1) ? kp : vp;
    const void* W = (mode == 0) ? Wqp : (mode == 1) ? Wkp : Wvp;
    const void* W1x = (mode == 1) ? W2p : W1p;
    float* P = ws + OFF_P + (size_t)z * PSTRIDE;

    const int h    = blockIdx.x;
    const int col0 = h * 64;
    const int row0 = blockIdx.y * 32;
    const int t = threadIdx.x;
    const int w = t >> 6, l16 = t & 15, quad = (t & 63) >> 4;

    const int arow = t >> 2, acol = (t & 3) * 16;
    const int brow = t >> 1, bcol = (t & 1) * 32;
    const size_t abase = (size_t)(row0 + arow) * 512 + kbase + acol;
    const size_t bbase = (size_t)(col0 + brow) * 512 + kbase + bcol;

    float4 a4[4], b4[8];
    #pragma unroll
    for (int i = 0; i < 4; i++) a4[i] = ld4(A, abase + i * 4, f);
    #pragma unroll
    for (int i = 0; i < 8; i++) b4[i] = ld4(W, bbase + i * 4, f);

    f32x4 acc[4];
    #pragma unroll
    for (int nt = 0; nt < 4; nt++) acc[nt] = (f32x4){0.f, 0.f, 0.f, 0.f};

    for (int k0 = 0; k0 < 256; k0 += 64) {
        __syncthreads();
        *reinterpret_cast<uint4*>(&smA[arow * LDSTR + acol])     = packu4(a4[0], a4[1]);
        *reinterpret_cast<uint4*>(&smA[arow * LDSTR + acol + 8]) = packu4(a4[2], a4[3]);
        *reinterpret_cast<uint4*>(&smB[brow * LDSTR + bcol])      = packu4(b4[0], b4[1]);
        *reinterpret_cast<uint4*>(&smB[brow * LDSTR + bcol + 8])  = packu4(b4[2], b4[3]);
        *reinterpret_cast<uint4*>(&smB[brow * LDSTR + bcol + 16]) = packu4(b4[4], b4[5]);
        *reinterpret_cast<uint4*>(&smB[brow * LDSTR + bcol + 24]) = packu4(b4[6], b4[7]);
        __syncthreads();
        if (k0 + 64 < 256) {
            #pragma unroll
            for (int i = 0; i < 4; i++) a4[i] = ld4(A, abase + k0 + 64 + i * 4, f);
            #pragma unroll
            for (int i = 0; i < 8; i++) b4[i] = ld4(W, bbase + k0 + 64 + i * 4, f);
        }
        #pragma unroll
        for (int kk = 0; kk < 2; kk++) {
            bf16x8 af = *reinterpret_cast<const bf16x8*>(
                &smA[(w * 16 + l16) * LDSTR + kk * 32 + quad * 8]);
            #pragma unroll
            for (int nt = 0; nt < 4; nt++) {
                bf16x8 bfr = *reinterpret_cast<const bf16x8*>(
                    &smB[(nt * 16 + l16) * LDSTR + kk * 32 + quad * 8]);
                acc[nt] = __builtin_amdgcn_mfma_f32_16x16x32_bf16(af, bfr, acc[nt], 0, 0, 0);
            }
        }
    }

    if (mode == 2) {
        #pragma unroll
        for (int nt = 0; nt < 4; nt++) {
            int o = col0 + l16 + nt * 16;
            #pragma unroll
            for (int r = 0; r < 4; r++) {
                int m = row0 + w * 16 + quad * 4 + r;
                P[(size_t)m * 512 + o] = acc[nt][r];
            }
        }
    } else {
        // ---- per-split W1-fold: restage acc bf16 in wave-private LDS rows ----
        #pragma unroll
        for (int nt = 0; nt < 4; nt++)
            #pragma unroll
            for (int r = 0; r < 4; r++)
                smA[(w * 16 + quad * 4 + r) * LDSTR + l16 + nt * 16] =
                    f2bf(acc[nt][r]);
        f32x4 acc2[4];
        #pragma unroll
        for (int nt = 0; nt < 4; nt++) acc2[nt] = (f32x4){0.f, 0.f, 0.f, 0.f};
        #pragma unroll
        for (int kk = 0; kk < 2; kk++) {
            bf16x8 af2 = *reinterpret_cast<const bf16x8*>(
                &smA[(w * 16 + l16) * LDSTR + kk * 32 + quad * 8]);
            #pragma unroll
            for (int nt = 0; nt < 4; nt++) {
                int od = nt * 16 + l16, j0 = kk * 32 + quad * 8;
                float4 wa = ld4(W1x, (size_t)od * 64 + j0, f);
                float4 wb = ld4(W1x, (size_t)od * 64 + j0 + 4, f);
                bf16x8 bfw = pack_bf8(wa, wb);
                acc2[nt] = __builtin_amdgcn_mfma_f32_16x16x32_bf16(af2, bfw, acc2[nt], 0, 0, 0);
            }
        }
        #pragma unroll
        for (int nt = 0; nt < 4; nt++) {
            int o = col0 + l16 + nt * 16;
            #pragma unroll
            for (int r = 0; r < 4; r++) {
                int m = row0 + w * 16 + quad * 4 + r;
                P[(size_t)m * 512 + o] = acc2[nt][r];
            }
        }
        // fused bias (once per head): biasF[o] = b1[od] + sum_j W1[od][j]*bq[h*64+j]
        if (blockIdx.y == 0 && ks == 0 && t < 64) {
            int od = t;
            const void* b1x = mode ? b2p : b1p;
            const void* bx  = mode ? bkp : bqp;
            float s = ld1(b1x, od, f);
            for (int j = 0; j < 64; j++)
                s = fmaf(ld1(W1x, (size_t)od * 64 + j, f), ld1(bx, h * 64 + j, f), s);
            ws[(mode ? OFF_BKE : OFF_BQE) + col0 + od] = s;
        }
    }
}

// ---------------------------------------------------------------------------
// Kernel 2: finalize (r6-proven). blocks 0..383: Etq=exp(2(P0+P1+bqE));
// 384..479: Etk transposed via LDS tiles; 480..863: V = P4+P5+bv.
// ---------------------------------------------------------------------------
__global__ __launch_bounds__(256) void finalize(
    const void* qp, const void* bvp,
    const float* __restrict__ ws_in, float* __restrict__ ws)
{
    __shared__ int s_cnt;
    __shared__ __align__(16) float T[64 * 68];
    const int f = block_detect((const unsigned int*)qp, &s_cnt);
    const int blk = blockIdx.x;
    const int tid = threadIdx.x;

    if (blk < 384 || blk >= 480) {
        const int isV = (blk >= 480);
        const float* P0 = ws_in + OFF_P + (size_t)(isV ? 4 : 0) * PSTRIDE;
        const float* P1 = P0 + PSTRIDE;
        float* Out = ws + (isV ? OFF_VH : OFF_ETQ);
        int gid = (isV ? blk - 480 : blk) * 256 + tid;
        int m = gid >> 7;
        int o4 = (gid & 127) * 4;
        float4 p0 = *reinterpret_cast<const float4*>(P0 + (size_t)m * 512 + o4);
        float4 p1 = *reinterpret_cast<const float4*>(P1 + (size_t)m * 512 + o4);
        float4 bb;
        if (isV) bb = ld4(bvp, o4, f);
        else     bb = *reinterpret_cast<const float4*>(ws_in + OFF_BQE + o4);
        float4 r;
        if (isV) {
            r.x = p0.x + p1.x + bb.x; r.y = p0.y + p1.y + bb.y;
            r.z = p0.z + p1.z + bb.z; r.w = p0.w + p1.w + bb.w;
        } else {
            r.x = __expf(2.f * (p0.x + p1.x + bb.x));
            r.y = __expf(2.f * (p0.y + p1.y + bb.y));
            r.z = __expf(2.f * (p0.z + p1.z + bb.z));
            r.w = __expf(2.f * (p0.w + p1.w + bb.w));
        }
        int b = m / LSEQ, l = m % LSEQ, h = o4 >> 6, d = o4 & 63;
        *reinterpret_cast<float4*>(&Out[(size_t)((b * NH + h) * LSEQ + l) * 64 + d]) = r;
    } else {
        int blk2 = blk - 384;              // 96 = 16 bh x 6 l-tiles
        int bh = blk2 / 6, l0 = (blk2 % 6) * 64;
        int b = bh >> 3, h = bh & 7;
        const float* P0 = ws_in + OFF_P + (size_t)2 * PSTRIDE;
        const float* P1 = P0 + PSTRIDE;
        #pragma unroll
        for (int it = 0; it < 4; it++) {
            int li = (tid >> 4) + it * 16;
            int d4 = (tid & 15) * 4;
            size_t src = (size_t)(b * LSEQ + l0 + li) * 512 + h * 64 + d4;
            float4 p0 = *reinterpret_cast<const float4*>(P0 + src);
            float4 p1 = *reinterpret_cast<const float4*>(P1 + src);
            const float4 bb = *reinterpret_cast<const float4*>(ws_in + OFF_BKE + h * 64 + d4);
            T[(d4 + 0) * 68 + li] = __expf(2.f * (p0.x + p1.x + bb.x));
            T[(d4 + 1) * 68 + li] = __expf(2.f * (p0.y + p1.y + bb.y));
            T[(d4 + 2) * 68 + li] = __expf(2.f * (p0.z + p1.z + bb.z));
            T[(d4 + 3) * 68 + li] = __expf(2.f * (p0.w + p1.w + bb.w));
        }
        __syncthreads();
        float* Out = ws + OFF_ETKT;
        #pragma unroll
        for (int it = 0; it < 4; it++) {
            int d = (tid >> 4) + it * 16;
            int l4 = (tid & 15) * 4;
            float4 v = *reinterpret_cast<const float4*>(&T[d * 68 + l4]);
            *reinterpret_cast<float4*>(&Out[(size_t)(bh * 64 + d) * LSEQ + l0 + l4]) = v;
        }
    }
}

// ---------------------------------------------------------------------------
// Kernel 3: additive attention, TQ=8, 384 threads. NO max-pass: energies are
// analytically bounded (|e| <= |vb| + sum|vw| ~ 1), exp cannot overflow;
// masked lanes exp(-1e10) = 0.
// ---------------------------------------------------------------------------
__global__ __launch_bounds__(384, 6) void attn_kernel(
    const void* qp, const void* vwp, const void* vbp,
    const float* __restrict__ ws_in, float* __restrict__ ws,
    const int* __restrict__ mask, void* __restrict__ dout)
{
    __shared__ int s_cnt;
    const int f = block_detect((const unsigned int*)qp, &s_cnt);

    const float* Etq = ws_in + OFF_ETQ;
    const float* Etk = ws_in + OFF_ETKT;
    const float* Vh  = ws_in + OFF_VH;
    float* Xh = ws + OFF_XH;

    const int bid = blockIdx.x;
    const int qt = bid % QTILES;
    const int bh = bid / QTILES;
    const int q0 = qt * TQ;
    const int b  = bh >> 3;
    const int h  = bh & 7;
    const int t  = threadIdx.x;
    const int wave = t >> 6;

    __shared__ __align__(16) float etq8[64][TQ];
    __shared__ float vws[64];
    __shared__ float ps[TQ][LSEQ];
    __shared__ float red[6][TQ][16][4];
    __shared__ float rsum[TQ][6];
    __shared__ float s_vb;

    for (int i = t; i < TQ * 64; i += 384) {
        int qi = i >> 6, d = i & 63;
        etq8[d][qi] = Etq[(size_t)(bh * LSEQ + q0 + qi) * 64 + d];
    }
    if (t < 64) {
        float v = ld1(vwp, t, f);
        vws[t] = v;
        #pragma unroll
        for (int off = 32; off > 0; off >>= 1) v += __shfl_xor(v, off, 64);
        if (t == 0) s_vb = ld1(vbp, 0, f) + v;
    }
    const int mok = mask[b * LSEQ + t];
    __syncthreads();
    const float vbSum = s_vb;

    float e2[TQ] = {0.f, 0.f, 0.f, 0.f, 0.f, 0.f, 0.f, 0.f};
    const float* ekp = Etk + (size_t)bh * 64 * LSEQ + t;
    #pragma unroll 4
    for (int d = 0; d < 64; d++) {
        float ekv = ekp[(size_t)d * LSEQ];
        float4 eqA = *reinterpret_cast<const float4*>(&etq8[d][0]);
        float4 eqB = *reinterpret_cast<const float4*>(&etq8[d][4]);
        float wv = vws[d];
        e2[0] = fmaf(wv, __builtin_amdgcn_rcpf(fmaf(eqA.x, ekv, 1.0f)), e2[0]);
        e2[1] = fmaf(wv, __builtin_amdgcn_rcpf(fmaf(eqA.y, ekv, 1.0f)), e2[1]);
        e2[2] = fmaf(wv, __builtin_amdgcn_rcpf(fmaf(eqA.z, ekv, 1.0f)), e2[2]);
        e2[3] = fmaf(wv, __builtin_amdgcn_rcpf(fmaf(eqA.w, ekv, 1.0f)), e2[3]);
        e2[4] = fmaf(wv, __builtin_amdgcn_rcpf(fmaf(eqB.x, ekv, 1.0f)), e2[4]);
        e2[5] = fmaf(wv, __builtin_amdgcn_rcpf(fmaf(eqB.y, ekv, 1.0f)), e2[5]);
        e2[6] = fmaf(wv, __builtin_amdgcn_rcpf(fmaf(eqB.z, ekv, 1.0f)), e2[6]);
        e2[7] = fmaf(wv, __builtin_amdgcn_rcpf(fmaf(eqB.w, ekv, 1.0f)), e2[7]);
    }

    float p[TQ];
    #pragma unroll
    for (int qi = 0; qi < TQ; qi++) {
        float en = fmaf(-2.0f, e2[qi], vbSum);
        if (mok == 0) en = -1e10f;
        p[qi] = __expf(en);                       // no max-shift needed
        float s = p[qi];
        #pragma unroll
        for (int off = 32; off > 0; off >>= 1) s += __shfl_xor(s, off, 64);
        if ((t & 63) == 0) rsum[qi][wave] = s;
    }
    __syncthreads();
    #pragma unroll
    for (int qi = 0; qi < TQ; qi++) {
        float gs = rsum[qi][0] + rsum[qi][1] + rsum[qi][2] +
                   rsum[qi][3] + rsum[qi][4] + rsum[qi][5];
        p[qi] *= 1.0f / gs;
        ps[qi][t] = p[qi];
        size_t aidx = XELEMS + (size_t)(bh * LSEQ + q0 + qi) * LSEQ + t;
        if (f) ((float*)dout)[aidx] = p[qi];
        else   ((ushort_t*)dout)[aidx] = f2bf(p[qi]);
    }
    __syncthreads();

    const int dq = t & 15;
    const int ksub = t >> 4;
    const float* vb4 = Vh + (size_t)bh * LSEQ * 64 + dq * 4;
    float4 acc[TQ];
    #pragma unroll
    for (int qi = 0; qi < TQ; qi++) acc[qi] = make_float4(0.f, 0.f, 0.f, 0.f);
    for (int kk = ksub; kk < LSEQ; kk += 24) {
        float4 v4 = *reinterpret_cast<const float4*>(vb4 + (size_t)kk * 64);
        #pragma unroll
        for (int qi = 0; qi < TQ; qi++) {
            float pq = ps[qi][kk];
            acc[qi].x = fmaf(pq, v4.x, acc[qi].x);
            acc[qi].y = fmaf(pq, v4.y, acc[qi].y);
            acc[qi].z = fmaf(pq, v4.z, acc[qi].z);
            acc[qi].w = fmaf(pq, v4.w, acc[qi].w);
        }
    }
    #pragma unroll
    for (int qi = 0; qi < TQ; qi++) {
        #pragma unroll
        for (int off = 16; off <= 32; off <<= 1) {
            acc[qi].x += __shfl_xor(acc[qi].x, off, 64);
            acc[qi].y += __shfl_xor(acc[qi].y, off, 64);
            acc[qi].z += __shfl_xor(acc[qi].z, off, 64);
            acc[qi].w += __shfl_xor(acc[qi].w, off, 64);
        }
    }
    if ((t & 63) < 16) {
        #pragma unroll
        for (int qi = 0; qi < TQ; qi++) {
            red[wave][qi][dq][0] = acc[qi].x;
            red[wave][qi][dq][1] = acc[qi].y;
            red[wave][qi][dq][2] = acc[qi].z;
            red[wave][qi][dq][3] = acc[qi].w;
        }
    }
    __syncthreads();
    if (t < 256) {
        int d = t & 63;
        #pragma unroll
        for (int half = 0; half < 2; half++) {
            int qi = (t >> 6) + half * 4;
            float sx = 0.f;
            #pragma unroll
            for (int w = 0; w < 6; w++) sx += red[w][qi][d >> 2][d & 3];
            Xh[((size_t)(b * LSEQ + q0 + qi) * NH + h) * 64 + d] = sx;
        }
    }
}

// ---------------------------------------------------------------------------
// Kernel 4: output projection via bf16 MFMA, split-K=4. K-slab 128.
// Partials -> P[ks] (region free after finalize+attn).
// ---------------------------------------------------------------------------
__global__ __launch_bounds__(128) void gemm_out(
    const void* qp, const void* Wop,
    const float* __restrict__ ws_in, float* __restrict__ ws)
{
    __shared__ int s_cnt;
    __shared__ ushort_t smA[32 * LDSTR];
    __shared__ ushort_t smB[64 * LDSTR];
    const int f = block_detect((const unsigned int*)qp, &s_cnt);

    const float* Xh = ws_in + OFF_XH;
    const int ks = blockIdx.z;
    const int kbase = ks * 128;
    float* P = ws + OFF_P + (size_t)ks * PSTRIDE;

    const int col0 = blockIdx.x * 64;
    const int row0 = blockIdx.y * 32;
    const int t = threadIdx.x;
    const int w = t >> 6, l16 = t & 15, quad = (t & 63) >> 4;

    const int arow = t >> 2, acol = (t & 3) * 16;
    const int brow = t >> 1, bcol = (t & 1) * 32;
    const float* Ab = Xh + (size_t)(row0 + arow) * 512 + kbase + acol;
    const size_t bbase = (size_t)(col0 + brow) * 512 + kbase + bcol;

    float4 a4[4], b4[8];
    #pragma unroll
    for (int i = 0; i < 4; i++) a4[i] = *reinterpret_cast<const float4*>(Ab + i * 4);
    #pragma unroll
    for (int i = 0; i < 8; i++) b4[i] = ld4(Wop, bbase + i * 4, f);

    f32x4 acc[4];
    #pragma unroll
    for (int nt = 0; nt < 4; nt++) acc[nt] = (f32x4){0.f, 0.f, 0.f, 0.f};

    for (int k0 = 0; k0 < 128; k0 += 64) {
        __syncthreads();
        *reinterpret_cast<uint4*>(&smA[arow * LDSTR + acol])     = packu4(a4[0], a4[1]);
        *reinterpret_cast<uint4*>(&smA[arow * LDSTR + acol + 8]) = packu4(a4[2], a4[3]);
        *reinterpret_cast<uint4*>(&smB[brow * LDSTR + bcol])      = packu4(b4[0], b4[1]);
        *reinterpret_cast<uint4*>(&smB[brow * LDSTR + bcol + 8])  = packu4(b4[2], b4[3]);
        *reinterpret_cast<uint4*>(&smB[brow * LDSTR + bcol + 16]) = packu4(b4[4], b4[5]);
        *reinterpret_cast<uint4*>(&smB[brow * LDSTR + bcol + 24]) = packu4(b4[6], b4[7]);
        __syncthreads();
        if (k0 + 64 < 128) {
            #pragma unroll
            for (int i = 0; i < 4; i++)
                a4[i] = *reinterpret_cast<const float4*>(Ab + k0 + 64 + i * 4);
            #pragma unroll
            for (int i = 0; i < 8; i++) b4[i] = ld4(Wop, bbase + k0 + 64 + i * 4, f);
        }
        #pragma unroll
        for (int kk = 0; kk < 2; kk++) {
            bf16x8 af = *reinterpret_cast<const bf16x8*>(
                &smA[(w * 16 + l16) * LDSTR + kk * 32 + quad * 8]);
            #pragma unroll
            for (int nt = 0; nt < 4; nt++) {
                bf16x8 bfr = *reinterpret_cast<const bf16x8*>(
                    &smB[(nt * 16 + l16) * LDSTR + kk * 32 + quad * 8]);
                acc[nt] = __builtin_amdgcn_mfma_f32_16x16x32_bf16(af, bfr, acc[nt], 0, 0, 0);
            }
        }
    }

    #pragma unroll
    for (int nt = 0; nt < 4; nt++) {
        int n = col0 + l16 + nt * 16;
        #pragma unroll
        for (int r = 0; r < 4; r++) {
            int m = row0 + w * 16 + quad * 4 + r;
            P[(size_t)m * 512 + n] = acc[nt][r];
        }
    }
}

// ---------------------------------------------------------------------------
// Kernel 5: out_reduce — x = sum of 4 partials + bo, dual-dtype write.
// ---------------------------------------------------------------------------
__global__ __launch_bounds__(256) void out_reduce(
    const void* qp, const void* bop,
    const float* __restrict__ ws_in, void* __restrict__ dout)
{
    __shared__ int s_cnt;
    const int f = block_detect((const unsigned int*)qp, &s_cnt);
    int gid = blockIdx.x * 256 + threadIdx.x;
    size_t idx = (size_t)gid * 4;
    int o4 = (int)(idx & 511);
    const float* P = ws_in + OFF_P;
    float4 s0 = *reinterpret_cast<const float4*>(P + idx);
    float4 s1 = *reinterpret_cast<const float4*>(P + PSTRIDE + idx);
    float4 s2 = *reinterpret_cast<const float4*>(P + 2 * (size_t)PSTRIDE + idx);
    float4 s3 = *reinterpret_cast<const float4*>(P + 3 * (size_t)PSTRIDE + idx);
    float4 bb = ld4(bop, o4, f);
    float4 r;
    r.x = (s0.x + s1.x) + (s2.x + s3.x) + bb.x;
    r.y = (s0.y + s1.y) + (s2.y + s3.y) + bb.y;
    r.z = (s0.z + s1.z) + (s2.z + s3.z) + bb.z;
    r.w = (s0.w + s1.w) + (s2.w + s3.w) + bb.w;
    if (f) {
        *reinterpret_cast<float4*>((float*)dout + idx) = r;
    } else {
        ushort4 u;
        u.x = f2bf(r.x); u.y = f2bf(r.y); u.z = f2bf(r.z); u.w = f2bf(r.w);
        *reinterpret_cast<ushort4*>((ushort_t*)dout + idx) = u;
    }
}

// ---------------------------------------------------------------------------
extern "C" void kernel_launch(void* const* d_in, const int* in_sizes, int n_in,
                              void* d_out, int out_size, void* d_ws, size_t ws_size,
                              hipStream_t stream)
{
    const void* qp = d_in[0];
    const void* kp = d_in[1];
    const void* vp = d_in[2];
    const int* mask = (const int*)d_in[3];
    const void* Wqp = d_in[4];  const void* bqp = d_in[5];
    const void* Wkp = d_in[6];  const void* bkp = d_in[7];
    const void* Wvp = d_in[8];  const void* bvp = d_in[9];
    const void* Wop = d_in[10]; const void* bop = d_in[11];
    const void* W1p = d_in[12]; const void* b1p = d_in[13];
    const void* W2p = d_in[14]; const void* b2p = d_in[15];
    const void* vwp = d_in[16]; const void* vbp = d_in[17];

    float* ws = (float*)d_ws;

    gemm_qkv<<<dim3(8, 24, 6), 128, 0, stream>>>(qp, kp, vp, Wqp, Wkp, Wvp,
                                                 W1p, W2p, bqp, bkp, b1p, b2p, ws);
    finalize<<<864, 256, 0, stream>>>(qp, bvp, ws, ws);
    attn_kernel<<<BH * QTILES, 384, 0, stream>>>(qp, vwp, vbp, ws, ws, mask, d_out);
    gemm_out<<<dim3(8, 24, 4), 128, 0, stream>>>(qp, Wop, ws, ws);
    out_reduce<<<384, 256, 0, stream>>>(qp, bop, ws, d_out);
}

// Round 11
// 166.777 us; speedup vs baseline: 2.5419x; 1.0072x over previous
//
#include <hip/hip_runtime.h>

// Problem constants
#define BATCH 2
#define LSEQ 384
#define NHID 512
#define NH 8
#define DH 64
#define BH (BATCH*NH)          // 16
#define XELEMS ((size_t)768 * NHID)        // 393216 (x output elems)
#define TQ 8                   // q-rows per attn block
#define QTILES (LSEQ/TQ)       // 48

typedef unsigned short ushort_t;
typedef __attribute__((ext_vector_type(8))) short bf16x8;
typedef __attribute__((ext_vector_type(4))) float f32x4;

__device__ __forceinline__ float bf2f(ushort_t u) {
    unsigned int v = ((unsigned int)u) << 16;
    return __uint_as_float(v);
}
__device__ __forceinline__ ushort_t f2bf(float f) {
    unsigned int u = __float_as_uint(f);
    unsigned int lsb = (u >> 16) & 1u;
    u += 0x7fffu + lsb;           // round-to-nearest-even
    return (ushort_t)(u >> 16);
}
// RNE bf16 pair-pack: 2x(bfe+add3) + v_perm (result: ushort0=bf16(a), ushort1=bf16(b))
__device__ __forceinline__ unsigned pk_bf16(float a, float b) {
    unsigned ua = __float_as_uint(a), ub = __float_as_uint(b);
    ua += 0x7fffu + ((ua >> 16) & 1u);
    ub += 0x7fffu + ((ub >> 16) & 1u);
    return __builtin_amdgcn_perm(ub, ua, 0x07060302);
}
__device__ __forceinline__ float ld1(const void* p, size_t i, int f) {
    return f ? ((const float*)p)[i] : bf2f(((const ushort_t*)p)[i]);
}
__device__ __forceinline__ float4 ld4(const void* p, size_t i, int f) {
    if (f) return ((const float4*)p)[i >> 2];
    ushort4 u = ((const ushort4*)p)[i >> 2];
    return make_float4(bf2f(u.x), bf2f(u.y), bf2f(u.z), bf2f(u.w));
}
__device__ __forceinline__ int block_detect(const unsigned int* q, int* cnt) {
    int t = threadIdx.x;
    if (t == 0) *cnt = 0;
    __syncthreads();
    int n = blockDim.x < 256 ? blockDim.x : 256;
    if (t < n) {
        unsigned int elo = (q[t] >> 7) & 0xFFu;
        if (elo >= 100u && elo <= 150u) atomicAdd(cnt, 1);
    }
    __syncthreads();
    return (*cnt * 2 > n) ? 0 : 1;     // 0 = bf16-packed, 1 = fp32
}
__device__ __forceinline__ uint4 packu4(float4 a, float4 b) {
    uint4 r;
    r.x = pk_bf16(a.x, a.y); r.y = pk_bf16(a.z, a.w);
    r.z = pk_bf16(b.x, b.y); r.w = pk_bf16(b.z, b.w);
    return r;
}
__device__ __forceinline__ bf16x8 pack_bf8(float4 a, float4 b) {
    union { uint4 u; bf16x8 v; } r;
    r.u = packu4(a, b);
    return r.v;
}

// ---------------- workspace layout (float offsets) ----------------
#define OFF_P     16
#define PSTRIDE   393216
#define OFF_BQE   2359312   // fused bias (b1 + W1@bq)
#define OFF_BKE   2359824
#define OFF_ETQ   2360336   // Etq = exp(2 tq)  [bh][l][d]
#define OFF_ETK   2753552   // Etk = exp(2 tk)  [bh][l][d]  (row-major now!)
#define OFF_VH    3146768   // V                [bh][l][d]
#define OFF_XH    3539984   // context [B,L,H,D]
// end = 3933200 floats = 15.7 MB

#define LDSTR 72   // LDS row stride in ushorts (144 B)

// ---------------------------------------------------------------------------
// Kernel 1: QKV GEMM via bf16 MFMA, split-K=2. z = mode*2 + ks, K-slab 256.
// 32(m) x 64(n=head) tile, 128 thr (2 waves). Modes 0/1 apply the W1/W2 fold
// per split (linear). Partials -> P[z] in natural [m][o] fp32 layout.
// ---------------------------------------------------------------------------
__global__ __launch_bounds__(128) void gemm_qkv(
    const void* qp, const void* kp, const void* vp,
    const void* Wqp, const void* Wkp, const void* Wvp,
    const void* W1p, const void* W2p,
    const void* bqp, const void* bkp, const void* b1p, const void* b2p,
    float* __restrict__ ws)
{
    __shared__ int s_cnt;
    __shared__ ushort_t smA[32 * LDSTR];
    __shared__ ushort_t smB[64 * LDSTR];
    const int f = block_detect((const unsigned int*)qp, &s_cnt);

    const int z = blockIdx.z;
    const int mode = z >> 1, ks = z & 1;
    const int kbase = ks * 256;
    const void* A = (mode == 0) ? qp : (mode == 1) ? kp : vp;
    const void* W = (mode == 0) ? Wqp : (mode == 1) ? Wkp : Wvp;
    const void* W1x = (mode == 1) ? W2p : W1p;
    float* P = ws + OFF_P + (size_t)z * PSTRIDE;

    const int h    = blockIdx.x;
    const int col0 = h * 64;
    const int row0 = blockIdx.y * 32;
    const int t = threadIdx.x;
    const int w = t >> 6, l16 = t & 15, quad = (t & 63) >> 4;

    const int arow = t >> 2, acol = (t & 3) * 16;
    const int brow = t >> 1, bcol = (t & 1) * 32;
    const size_t abase = (size_t)(row0 + arow) * 512 + kbase + acol;
    const size_t bbase = (size_t)(col0 + brow) * 512 + kbase + bcol;

    float4 a4[4], b4[8];
    #pragma unroll
    for (int i = 0; i < 4; i++) a4[i] = ld4(A, abase + i * 4, f);
    #pragma unroll
    for (int i = 0; i < 8; i++) b4[i] = ld4(W, bbase + i * 4, f);

    f32x4 acc[4];
    #pragma unroll
    for (int nt = 0; nt < 4; nt++) acc[nt] = (f32x4){0.f, 0.f, 0.f, 0.f};

    for (int k0 = 0; k0 < 256; k0 += 64) {
        __syncthreads();
        *reinterpret_cast<uint4*>(&smA[arow * LDSTR + acol])     = packu4(a4[0], a4[1]);
        *reinterpret_cast<uint4*>(&smA[arow * LDSTR + acol + 8]) = packu4(a4[2], a4[3]);
        *reinterpret_cast<uint4*>(&smB[brow * LDSTR + bcol])      = packu4(b4[0], b4[1]);
        *reinterpret_cast<uint4*>(&smB[brow * LDSTR + bcol + 8])  = packu4(b4[2], b4[3]);
        *reinterpret_cast<uint4*>(&smB[brow * LDSTR + bcol + 16]) = packu4(b4[4], b4[5]);
        *reinterpret_cast<uint4*>(&smB[brow * LDSTR + bcol + 24]) = packu4(b4[6], b4[7]);
        __syncthreads();
        if (k0 + 64 < 256) {
            #pragma unroll
            for (int i = 0; i < 4; i++) a4[i] = ld4(A, abase + k0 + 64 + i * 4, f);
            #pragma unroll
            for (int i = 0; i < 8; i++) b4[i] = ld4(W, bbase + k0 + 64 + i * 4, f);
        }
        #pragma unroll
        for (int kk = 0; kk < 2; kk++) {
            bf16x8 af = *reinterpret_cast<const bf16x8*>(
                &smA[(w * 16 + l16) * LDSTR + kk * 32 + quad * 8]);
            #pragma unroll
            for (int nt = 0; nt < 4; nt++) {
                bf16x8 bfr = *reinterpret_cast<const bf16x8*>(
                    &smB[(nt * 16 + l16) * LDSTR + kk * 32 + quad * 8]);
                acc[nt] = __builtin_amdgcn_mfma_f32_16x16x32_bf16(af, bfr, acc[nt], 0, 0, 0);
            }
        }
    }

    if (mode == 2) {
        #pragma unroll
        for (int nt = 0; nt < 4; nt++) {
            int o = col0 + l16 + nt * 16;
            #pragma unroll
            for (int r = 0; r < 4; r++) {
                int m = row0 + w * 16 + quad * 4 + r;
                P[(size_t)m * 512 + o] = acc[nt][r];
            }
        }
    } else {
        // ---- per-split W1-fold: restage acc bf16 in wave-private LDS rows ----
        #pragma unroll
        for (int nt = 0; nt < 4; nt++)
            #pragma unroll
            for (int r = 0; r < 4; r++)
                smA[(w * 16 + quad * 4 + r) * LDSTR + l16 + nt * 16] =
                    f2bf(acc[nt][r]);
        f32x4 acc2[4];
        #pragma unroll
        for (int nt = 0; nt < 4; nt++) acc2[nt] = (f32x4){0.f, 0.f, 0.f, 0.f};
        #pragma unroll
        for (int kk = 0; kk < 2; kk++) {
            bf16x8 af2 = *reinterpret_cast<const bf16x8*>(
                &smA[(w * 16 + l16) * LDSTR + kk * 32 + quad * 8]);
            #pragma unroll
            for (int nt = 0; nt < 4; nt++) {
                int od = nt * 16 + l16, j0 = kk * 32 + quad * 8;
                float4 wa = ld4(W1x, (size_t)od * 64 + j0, f);
                float4 wb = ld4(W1x, (size_t)od * 64 + j0 + 4, f);
                bf16x8 bfw = pack_bf8(wa, wb);
                acc2[nt] = __builtin_amdgcn_mfma_f32_16x16x32_bf16(af2, bfw, acc2[nt], 0, 0, 0);
            }
        }
        #pragma unroll
        for (int nt = 0; nt < 4; nt++) {
            int o = col0 + l16 + nt * 16;
            #pragma unroll
            for (int r = 0; r < 4; r++) {
                int m = row0 + w * 16 + quad * 4 + r;
                P[(size_t)m * 512 + o] = acc2[nt][r];
            }
        }
        if (blockIdx.y == 0 && ks == 0 && t < 64) {
            int od = t;
            const void* b1x = mode ? b2p : b1p;
            const void* bx  = mode ? bkp : bqp;
            float s = ld1(b1x, od, f);
            for (int j = 0; j < 64; j++)
                s = fmaf(ld1(W1x, (size_t)od * 64 + j, f), ld1(bx, h * 64 + j, f), s);
            ws[(mode ? OFF_BKE : OFF_BQE) + col0 + od] = s;
        }
    }
}

// ---------------------------------------------------------------------------
// Kernel 2: finalize — uniform: region 0: Etq=exp(2(P0+P1+bqE)); region 1:
// Etk=exp(2(P2+P3+bkE)); region 2: V=P4+P5+bv. ALL in [bh][l][d] layout
// (no transpose needed since attn now reads Etk rows).
// ---------------------------------------------------------------------------
__global__ __launch_bounds__(256) void finalize(
    const void* qp, const void* bvp,
    const float* __restrict__ ws_in, float* __restrict__ ws)
{
    __shared__ int s_cnt;
    const int f = block_detect((const unsigned int*)qp, &s_cnt);
    const int blk = blockIdx.x;              // 0..1151
    const int region = blk / 384;            // 0=Etq, 1=Etk, 2=V
    const int tid = threadIdx.x;

    const float* P0 = ws_in + OFF_P + (size_t)(region * 2) * PSTRIDE;
    const float* P1 = P0 + PSTRIDE;
    float* Out = ws + (region == 0 ? OFF_ETQ : region == 1 ? OFF_ETK : OFF_VH);

    int gid = (blk % 384) * 256 + tid;       // float4 index
    int m = gid >> 7;                        // 128 float4 per row
    int o4 = (gid & 127) * 4;
    float4 p0 = *reinterpret_cast<const float4*>(P0 + (size_t)m * 512 + o4);
    float4 p1 = *reinterpret_cast<const float4*>(P1 + (size_t)m * 512 + o4);
    float4 bb;
    if (region == 0)      bb = *reinterpret_cast<const float4*>(ws_in + OFF_BQE + o4);
    else if (region == 1) bb = *reinterpret_cast<const float4*>(ws_in + OFF_BKE + o4);
    else                  bb = ld4(bvp, o4, f);
    float4 r;
    if (region < 2) {
        r.x = __expf(2.f * (p0.x + p1.x + bb.x));
        r.y = __expf(2.f * (p0.y + p1.y + bb.y));
        r.z = __expf(2.f * (p0.z + p1.z + bb.z));
        r.w = __expf(2.f * (p0.w + p1.w + bb.w));
    } else {
        r.x = p0.x + p1.x + bb.x; r.y = p0.y + p1.y + bb.y;
        r.z = p0.z + p1.z + bb.z; r.w = p0.w + p1.w + bb.w;
    }
    int b = m / LSEQ, l = m % LSEQ, h = o4 >> 6, d = o4 & 63;
    *reinterpret_cast<float4*>(&Out[(size_t)((b * NH + h) * LSEQ + l) * 64 + d]) = r;
}

// ---------------------------------------------------------------------------
// Kernel 3: additive attention, TQ=8, 384 threads (t = k). Etk row-major:
// thread t reads its Etk row via 16 independent b128 loads (deep MLP, L1
// reuse). Energy: e2 += vw_d * rcp(fma(Etq, Etk, 1.0)). No max-pass
// (energies analytically bounded ~1; masked lanes exp(-1e10)=0).
// ---------------------------------------------------------------------------
__global__ __launch_bounds__(384, 6) void attn_kernel(
    const void* qp, const void* vwp, const void* vbp,
    const float* __restrict__ ws_in, float* __restrict__ ws,
    const int* __restrict__ mask, void* __restrict__ dout)
{
    __shared__ int s_cnt;
    const int f = block_detect((const unsigned int*)qp, &s_cnt);

    const float* Etq = ws_in + OFF_ETQ;
    const float* Etk = ws_in + OFF_ETK;
    const float* Vh  = ws_in + OFF_VH;
    float* Xh = ws + OFF_XH;

    const int bid = blockIdx.x;
    const int qt = bid % QTILES;
    const int bh = bid / QTILES;
    const int q0 = qt * TQ;
    const int b  = bh >> 3;
    const int h  = bh & 7;
    const int t  = threadIdx.x;
    const int wave = t >> 6;

    __shared__ __align__(16) float etq8[64][TQ];
    __shared__ float vws[64];
    __shared__ float ps[TQ][LSEQ];
    __shared__ float red[6][TQ][16][4];
    __shared__ float rsum[TQ][6];
    __shared__ float s_vb;

    for (int i = t; i < TQ * 64; i += 384) {
        int qi = i >> 6, d = i & 63;
        etq8[d][qi] = Etq[(size_t)(bh * LSEQ + q0 + qi) * 64 + d];
    }
    if (t < 64) {
        float v = ld1(vwp, t, f);
        vws[t] = v;
        #pragma unroll
        for (int off = 32; off > 0; off >>= 1) v += __shfl_xor(v, off, 64);
        if (t == 0) s_vb = ld1(vbp, 0, f) + v;
    }
    const int mok = mask[b * LSEQ + t];
    __syncthreads();
    const float vbSum = s_vb;

    float e2[TQ] = {0.f, 0.f, 0.f, 0.f, 0.f, 0.f, 0.f, 0.f};
    const float* ekrow = Etk + (size_t)(bh * LSEQ + t) * 64;
    #pragma unroll 4
    for (int dv = 0; dv < 16; dv++) {
        float4 ek4 = *reinterpret_cast<const float4*>(ekrow + dv * 4);
        #pragma unroll
        for (int j = 0; j < 4; j++) {
            int d = dv * 4 + j;
            float ekv = (j == 0) ? ek4.x : (j == 1) ? ek4.y : (j == 2) ? ek4.z : ek4.w;
            float4 eqA = *reinterpret_cast<const float4*>(&etq8[d][0]);
            float4 eqB = *reinterpret_cast<const float4*>(&etq8[d][4]);
            float wv = vws[d];
            e2[0] = fmaf(wv, __builtin_amdgcn_rcpf(fmaf(eqA.x, ekv, 1.0f)), e2[0]);
            e2[1] = fmaf(wv, __builtin_amdgcn_rcpf(fmaf(eqA.y, ekv, 1.0f)), e2[1]);
            e2[2] = fmaf(wv, __builtin_amdgcn_rcpf(fmaf(eqA.z, ekv, 1.0f)), e2[2]);
            e2[3] = fmaf(wv, __builtin_amdgcn_rcpf(fmaf(eqA.w, ekv, 1.0f)), e2[3]);
            e2[4] = fmaf(wv, __builtin_amdgcn_rcpf(fmaf(eqB.x, ekv, 1.0f)), e2[4]);
            e2[5] = fmaf(wv, __builtin_amdgcn_rcpf(fmaf(eqB.y, ekv, 1.0f)), e2[5]);
            e2[6] = fmaf(wv, __builtin_amdgcn_rcpf(fmaf(eqB.z, ekv, 1.0f)), e2[6]);
            e2[7] = fmaf(wv, __builtin_amdgcn_rcpf(fmaf(eqB.w, ekv, 1.0f)), e2[7]);
        }
    }

    float p[TQ];
    #pragma unroll
    for (int qi = 0; qi < TQ; qi++) {
        float en = fmaf(-2.0f, e2[qi], vbSum);
        if (mok == 0) en = -1e10f;
        p[qi] = __expf(en);
        float s = p[qi];
        #pragma unroll
        for (int off = 32; off > 0; off >>= 1) s += __shfl_xor(s, off, 64);
        if ((t & 63) == 0) rsum[qi][wave] = s;
    }
    __syncthreads();
    #pragma unroll
    for (int qi = 0; qi < TQ; qi++) {
        float gs = rsum[qi][0] + rsum[qi][1] + rsum[qi][2] +
                   rsum[qi][3] + rsum[qi][4] + rsum[qi][5];
        p[qi] *= 1.0f / gs;
        ps[qi][t] = p[qi];
        size_t aidx = XELEMS + (size_t)(bh * LSEQ + q0 + qi) * LSEQ + t;
        if (f) ((float*)dout)[aidx] = p[qi];
        else   ((ushort_t*)dout)[aidx] = f2bf(p[qi]);
    }
    __syncthreads();

    const int dq = t & 15;
    const int ksub = t >> 4;
    const float* vb4 = Vh + (size_t)bh * LSEQ * 64 + dq * 4;
    float4 acc[TQ];
    #pragma unroll
    for (int qi = 0; qi < TQ; qi++) acc[qi] = make_float4(0.f, 0.f, 0.f, 0.f);
    for (int kk = ksub; kk < LSEQ; kk += 24) {
        float4 v4 = *reinterpret_cast<const float4*>(vb4 + (size_t)kk * 64);
        #pragma unroll
        for (int qi = 0; qi < TQ; qi++) {
            float pq = ps[qi][kk];
            acc[qi].x = fmaf(pq, v4.x, acc[qi].x);
            acc[qi].y = fmaf(pq, v4.y, acc[qi].y);
            acc[qi].z = fmaf(pq, v4.z, acc[qi].z);
            acc[qi].w = fmaf(pq, v4.w, acc[qi].w);
        }
    }
    #pragma unroll
    for (int qi = 0; qi < TQ; qi++) {
        #pragma unroll
        for (int off = 16; off <= 32; off <<= 1) {
            acc[qi].x += __shfl_xor(acc[qi].x, off, 64);
            acc[qi].y += __shfl_xor(acc[qi].y, off, 64);
            acc[qi].z += __shfl_xor(acc[qi].z, off, 64);
            acc[qi].w += __shfl_xor(acc[qi].w, off, 64);
        }
    }
    if ((t & 63) < 16) {
        #pragma unroll
        for (int qi = 0; qi < TQ; qi++) {
            red[wave][qi][dq][0] = acc[qi].x;
            red[wave][qi][dq][1] = acc[qi].y;
            red[wave][qi][dq][2] = acc[qi].z;
            red[wave][qi][dq][3] = acc[qi].w;
        }
    }
    __syncthreads();
    if (t < 256) {
        int d = t & 63;
        #pragma unroll
        for (int half = 0; half < 2; half++) {
            int qi = (t >> 6) + half * 4;
            float sx = 0.f;
            #pragma unroll
            for (int w = 0; w < 6; w++) sx += red[w][qi][d >> 2][d & 3];
            Xh[((size_t)(b * LSEQ + q0 + qi) * NH + h) * 64 + d] = sx;
        }
    }
}

// ---------------------------------------------------------------------------
// Kernel 4: output projection via bf16 MFMA, split-K=4. K-slab 128.
// ---------------------------------------------------------------------------
__global__ __launch_bounds__(128) void gemm_out(
    const void* qp, const void* Wop,
    const float* __restrict__ ws_in, float* __restrict__ ws)
{
    __shared__ int s_cnt;
    __shared__ ushort_t smA[32 * LDSTR];
    __shared__ ushort_t smB[64 * LDSTR];
    const int f = block_detect((const unsigned int*)qp, &s_cnt);

    const float* Xh = ws_in + OFF_XH;
    const int ks = blockIdx.z;
    const int kbase = ks * 128;
    float* P = ws + OFF_P + (size_t)ks * PSTRIDE;

    const int col0 = blockIdx.x * 64;
    const int row0 = blockIdx.y * 32;
    const int t = threadIdx.x;
    const int w = t >> 6, l16 = t & 15, quad = (t & 63) >> 4;

    const int arow = t >> 2, acol = (t & 3) * 16;
    const int brow = t >> 1, bcol = (t & 1) * 32;
    const float* Ab = Xh + (size_t)(row0 + arow) * 512 + kbase + acol;
    const size_t bbase = (size_t)(col0 + brow) * 512 + kbase + bcol;

    float4 a4[4], b4[8];
    #pragma unroll
    for (int i = 0; i < 4; i++) a4[i] = *reinterpret_cast<const float4*>(Ab + i * 4);
    #pragma unroll
    for (int i = 0; i < 8; i++) b4[i] = ld4(Wop, bbase + i * 4, f);

    f32x4 acc[4];
    #pragma unroll
    for (int nt = 0; nt < 4; nt++) acc[nt] = (f32x4){0.f, 0.f, 0.f, 0.f};

    for (int k0 = 0; k0 < 128; k0 += 64) {
        __syncthreads();
        *reinterpret_cast<uint4*>(&smA[arow * LDSTR + acol])     = packu4(a4[0], a4[1]);
        *reinterpret_cast<uint4*>(&smA[arow * LDSTR + acol + 8]) = packu4(a4[2], a4[3]);
        *reinterpret_cast<uint4*>(&smB[brow * LDSTR + bcol])      = packu4(b4[0], b4[1]);
        *reinterpret_cast<uint4*>(&smB[brow * LDSTR + bcol + 8])  = packu4(b4[2], b4[3]);
        *reinterpret_cast<uint4*>(&smB[brow * LDSTR + bcol + 16]) = packu4(b4[4], b4[5]);
        *reinterpret_cast<uint4*>(&smB[brow * LDSTR + bcol + 24]) = packu4(b4[6], b4[7]);
        __syncthreads();
        if (k0 + 64 < 128) {
            #pragma unroll
            for (int i = 0; i < 4; i++)
                a4[i] = *reinterpret_cast<const float4*>(Ab + k0 + 64 + i * 4);
            #pragma unroll
            for (int i = 0; i < 8; i++) b4[i] = ld4(Wop, bbase + k0 + 64 + i * 4, f);
        }
        #pragma unroll
        for (int kk = 0; kk < 2; kk++) {
            bf16x8 af = *reinterpret_cast<const bf16x8*>(
                &smA[(w * 16 + l16) * LDSTR + kk * 32 + quad * 8]);
            #pragma unroll
            for (int nt = 0; nt < 4; nt++) {
                bf16x8 bfr = *reinterpret_cast<const bf16x8*>(
                    &smB[(nt * 16 + l16) * LDSTR + kk * 32 + quad * 8]);
                acc[nt] = __builtin_amdgcn_mfma_f32_16x16x32_bf16(af, bfr, acc[nt], 0, 0, 0);
            }
        }
    }

    #pragma unroll
    for (int nt = 0; nt < 4; nt++) {
        int n = col0 + l16 + nt * 16;
        #pragma unroll
        for (int r = 0; r < 4; r++) {
            int m = row0 + w * 16 + quad * 4 + r;
            P[(size_t)m * 512 + n] = acc[nt][r];
        }
    }
}

// ---------------------------------------------------------------------------
// Kernel 5: out_reduce — x = sum of 4 partials + bo, dual-dtype write.
// ---------------------------------------------------------------------------
__global__ __launch_bounds__(256) void out_reduce(
    const void* qp, const void* bop,
    const float* __restrict__ ws_in, void* __restrict__ dout)
{
    __shared__ int s_cnt;
    const int f = block_detect((const unsigned int*)qp, &s_cnt);
    int gid = blockIdx.x * 256 + threadIdx.x;
    size_t idx = (size_t)gid * 4;
    int o4 = (int)(idx & 511);
    const float* P = ws_in + OFF_P;
    float4 s0 = *reinterpret_cast<const float4*>(P + idx);
    float4 s1 = *reinterpret_cast<const float4*>(P + PSTRIDE + idx);
    float4 s2 = *reinterpret_cast<const float4*>(P + 2 * (size_t)PSTRIDE + idx);
    float4 s3 = *reinterpret_cast<const float4*>(P + 3 * (size_t)PSTRIDE + idx);
    float4 bb = ld4(bop, o4, f);
    float4 r;
    r.x = (s0.x + s1.x) + (s2.x + s3.x) + bb.x;
    r.y = (s0.y + s1.y) + (s2.y + s3.y) + bb.y;
    r.z = (s0.z + s1.z) + (s2.z + s3.z) + bb.z;
    r.w = (s0.w + s1.w) + (s2.w + s3.w) + bb.w;
    if (f) {
        *reinterpret_cast<float4*>((float*)dout + idx) = r;
    } else {
        ushort4 u;
        u.x = f2bf(r.x); u.y = f2bf(r.y); u.z = f2bf(r.z); u.w = f2bf(r.w);
        *reinterpret_cast<ushort4*>((ushort_t*)dout + idx) = u;
    }
}

// ---------------------------------------------------------------------------
extern "C" void kernel_launch(void* const* d_in, const int* in_sizes, int n_in,
                              void* d_out, int out_size, void* d_ws, size_t ws_size,
                              hipStream_t stream)
{
    const void* qp = d_in[0];
    const void* kp = d_in[1];
    const void* vp = d_in[2];
    const int* mask = (const int*)d_in[3];
    const void* Wqp = d_in[4];  const void* bqp = d_in[5];
    const void* Wkp = d_in[6];  const void* bkp = d_in[7];
    const void* Wvp = d_in[8];  const void* bvp = d_in[9];
    const void* Wop = d_in[10]; const void* bop = d_in[11];
    const void* W1p = d_in[12]; const void* b1p = d_in[13];
    const void* W2p = d_in[14]; const void* b2p = d_in[15];
    const void* vwp = d_in[16]; const void* vbp = d_in[17];

    float* ws = (float*)d_ws;

    gemm_qkv<<<dim3(8, 24, 6), 128, 0, stream>>>(qp, kp, vp, Wqp, Wkp, Wvp,
                                                 W1p, W2p, bqp, bkp, b1p, b2p, ws);
    finalize<<<1152, 256, 0, stream>>>(qp, bvp, ws, ws);
    attn_kernel<<<BH * QTILES, 384, 0, stream>>>(qp, vwp, vbp, ws, ws, mask, d_out);
    gemm_out<<<dim3(8, 24, 4), 128, 0, stream>>>(qp, Wop, ws, ws);
    out_reduce<<<384, 256, 0, stream>>>(qp, bop, ws, d_out);
}

// Round 12
// 165.098 us; speedup vs baseline: 2.5677x; 1.0102x over previous
//
#include <hip/hip_runtime.h>

// Problem constants
#define BATCH 2
#define LSEQ 384
#define NHID 512
#define NH 8
#define DH 64
#define BH (BATCH*NH)          // 16
#define XELEMS ((size_t)768 * NHID)        // 393216 (x output elems)
#define TQ 8                   // q-rows per attn block
#define QTILES (LSEQ/TQ)       // 48

typedef unsigned short ushort_t;
typedef __attribute__((ext_vector_type(8))) short bf16x8;
typedef __attribute__((ext_vector_type(4))) float f32x4;

__device__ __forceinline__ float bf2f(ushort_t u) {
    unsigned int v = ((unsigned int)u) << 16;
    return __uint_as_float(v);
}
__device__ __forceinline__ ushort_t f2bf(float f) {
    unsigned int u = __float_as_uint(f);
    unsigned int lsb = (u >> 16) & 1u;
    u += 0x7fffu + lsb;           // round-to-nearest-even
    return (ushort_t)(u >> 16);
}
// RNE bf16 pair-pack: 2x add + v_perm (ushort0=bf16(a), ushort1=bf16(b))
__device__ __forceinline__ unsigned pk_bf16(float a, float b) {
    unsigned ua = __float_as_uint(a), ub = __float_as_uint(b);
    ua += 0x7fffu + ((ua >> 16) & 1u);
    ub += 0x7fffu + ((ub >> 16) & 1u);
    return __builtin_amdgcn_perm(ub, ua, 0x07060302);
}
__device__ __forceinline__ float ld1(const void* p, size_t i, int f) {
    return f ? ((const float*)p)[i] : bf2f(((const ushort_t*)p)[i]);
}
__device__ __forceinline__ float4 ld4(const void* p, size_t i, int f) {
    if (f) return ((const float4*)p)[i >> 2];
    ushort4 u = ((const ushort4*)p)[i >> 2];
    return make_float4(bf2f(u.x), bf2f(u.y), bf2f(u.z), bf2f(u.w));
}
__device__ __forceinline__ int block_detect(const unsigned int* q, int* cnt) {
    int t = threadIdx.x;
    if (t == 0) *cnt = 0;
    __syncthreads();
    int n = blockDim.x < 256 ? blockDim.x : 256;
    if (t < n) {
        unsigned int elo = (q[t] >> 7) & 0xFFu;
        if (elo >= 100u && elo <= 150u) atomicAdd(cnt, 1);
    }
    __syncthreads();
    return (*cnt * 2 > n) ? 0 : 1;     // 0 = bf16-packed, 1 = fp32
}
__device__ __forceinline__ uint4 packu4(float4 a, float4 b) {
    uint4 r;
    r.x = pk_bf16(a.x, a.y); r.y = pk_bf16(a.z, a.w);
    r.z = pk_bf16(b.x, b.y); r.w = pk_bf16(b.z, b.w);
    return r;
}
__device__ __forceinline__ bf16x8 pack_bf8(float4 a, float4 b) {
    union { uint4 u; bf16x8 v; } r;
    r.u = packu4(a, b);
    return r.v;
}

// ---------------- workspace layout (float offsets) ----------------
#define OFF_ETQ   16                  // Etq = exp(2 tq)  [bh][l][d]
#define OFF_ETK   (16 + 393216)       // Etk = exp(2 tk)  [bh][l][d] (row-major)
#define OFF_VH    (16 + 2*393216)     // V                [bh][l][d]
#define OFF_XH    (16 + 3*393216)     // context [B,L,H,D]

#define LDSTR 72   // LDS row stride in ushorts (144 B)

// ---------------------------------------------------------------------------
// Kernel 1: QKV projection via bf16 MFMA. 32(m) x 64(n=head) tile, 128 thr
// (2 waves), K=512 step 64, reg prefetch. Modes 0/1 fold W1/W2 via a second
// in-register MFMA pass and write Etq/Etk = exp(2(..+biasF)) row-major;
// mode 2 writes V + bv. No split-K, no partial buffers.
// ---------------------------------------------------------------------------
__global__ __launch_bounds__(128) void gemm_qkv(
    const void* qp, const void* kp, const void* vp,
    const void* Wqp, const void* Wkp, const void* Wvp,
    const void* W1p, const void* W2p,
    const void* bqp, const void* bkp, const void* b1p, const void* b2p,
    const void* bvp, float* __restrict__ ws)
{
    __shared__ int s_cnt;
    __shared__ ushort_t smA[32 * LDSTR];
    __shared__ ushort_t smB[64 * LDSTR];
    __shared__ float biasF[64];
    const int f = block_detect((const unsigned int*)qp, &s_cnt);

    const int mode = blockIdx.z;
    const void* A = (mode == 0) ? qp : (mode == 1) ? kp : vp;
    const void* W = (mode == 0) ? Wqp : (mode == 1) ? Wkp : Wvp;
    const void* W1x = (mode == 1) ? W2p : W1p;

    const int h    = blockIdx.x;
    const int col0 = h * 64;
    const int row0 = blockIdx.y * 32;
    const int t = threadIdx.x;
    const int w = t >> 6, l16 = t & 15, quad = (t & 63) >> 4;

    // fused bias into LDS (threads 0..63), overlapped with prefetch
    if (t < 64) {
        if (mode == 2) {
            biasF[t] = ld1(bvp, col0 + t, f);
        } else {
            const void* b1x = (mode == 1) ? b2p : b1p;
            const void* bx  = (mode == 1) ? bkp : bqp;
            float s = ld1(b1x, t, f);
            for (int j = 0; j < 64; j++)
                s = fmaf(ld1(W1x, (size_t)t * 64 + j, f), ld1(bx, h * 64 + j, f), s);
            biasF[t] = s;
        }
    }

    const int arow = t >> 2, acol = (t & 3) * 16;
    const int brow = t >> 1, bcol = (t & 1) * 32;
    const size_t abase = (size_t)(row0 + arow) * 512 + acol;
    const size_t bbase = (size_t)(col0 + brow) * 512 + bcol;

    float4 a4[4], b4[8];
    #pragma unroll
    for (int i = 0; i < 4; i++) a4[i] = ld4(A, abase + i * 4, f);
    #pragma unroll
    for (int i = 0; i < 8; i++) b4[i] = ld4(W, bbase + i * 4, f);

    f32x4 acc[4];
    #pragma unroll
    for (int nt = 0; nt < 4; nt++) acc[nt] = (f32x4){0.f, 0.f, 0.f, 0.f};

    for (int k0 = 0; k0 < 512; k0 += 64) {
        __syncthreads();
        *reinterpret_cast<uint4*>(&smA[arow * LDSTR + acol])     = packu4(a4[0], a4[1]);
        *reinterpret_cast<uint4*>(&smA[arow * LDSTR + acol + 8]) = packu4(a4[2], a4[3]);
        *reinterpret_cast<uint4*>(&smB[brow * LDSTR + bcol])      = packu4(b4[0], b4[1]);
        *reinterpret_cast<uint4*>(&smB[brow * LDSTR + bcol + 8])  = packu4(b4[2], b4[3]);
        *reinterpret_cast<uint4*>(&smB[brow * LDSTR + bcol + 16]) = packu4(b4[4], b4[5]);
        *reinterpret_cast<uint4*>(&smB[brow * LDSTR + bcol + 24]) = packu4(b4[6], b4[7]);
        __syncthreads();
        if (k0 + 64 < 512) {
            #pragma unroll
            for (int i = 0; i < 4; i++) a4[i] = ld4(A, abase + k0 + 64 + i * 4, f);
            #pragma unroll
            for (int i = 0; i < 8; i++) b4[i] = ld4(W, bbase + k0 + 64 + i * 4, f);
        }
        #pragma unroll
        for (int kk = 0; kk < 2; kk++) {
            bf16x8 af = *reinterpret_cast<const bf16x8*>(
                &smA[(w * 16 + l16) * LDSTR + kk * 32 + quad * 8]);
            #pragma unroll
            for (int nt = 0; nt < 4; nt++) {
                bf16x8 bfr = *reinterpret_cast<const bf16x8*>(
                    &smB[(nt * 16 + l16) * LDSTR + kk * 32 + quad * 8]);
                acc[nt] = __builtin_amdgcn_mfma_f32_16x16x32_bf16(af, bfr, acc[nt], 0, 0, 0);
            }
        }
    }

    const int b  = (row0 >= LSEQ) ? 1 : 0;
    const int lbase = row0 - b * LSEQ + w * 16;
    const int bh = b * NH + h;

    if (mode == 2) {
        float* Out = ws + OFF_VH;
        #pragma unroll
        for (int nt = 0; nt < 4; nt++) {
            int d = l16 + nt * 16;
            float bi = biasF[d];
            #pragma unroll
            for (int r = 0; r < 4; r++) {
                int l = lbase + quad * 4 + r;
                Out[(size_t)(bh * LSEQ + l) * 64 + d] = acc[nt][r] + bi;
            }
        }
    } else {
        // ---- fold: restage acc (bf16) in wave-private LDS rows, x W1^T ----
        #pragma unroll
        for (int nt = 0; nt < 4; nt++)
            #pragma unroll
            for (int r = 0; r < 4; r++)
                smA[(w * 16 + quad * 4 + r) * LDSTR + l16 + nt * 16] =
                    f2bf(acc[nt][r]);
        f32x4 acc2[4];
        #pragma unroll
        for (int nt = 0; nt < 4; nt++) acc2[nt] = (f32x4){0.f, 0.f, 0.f, 0.f};
        #pragma unroll
        for (int kk = 0; kk < 2; kk++) {
            bf16x8 af2 = *reinterpret_cast<const bf16x8*>(
                &smA[(w * 16 + l16) * LDSTR + kk * 32 + quad * 8]);
            #pragma unroll
            for (int nt = 0; nt < 4; nt++) {
                int od = nt * 16 + l16, j0 = kk * 32 + quad * 8;
                float4 wa = ld4(W1x, (size_t)od * 64 + j0, f);
                float4 wb = ld4(W1x, (size_t)od * 64 + j0 + 4, f);
                bf16x8 bfw = pack_bf8(wa, wb);
                acc2[nt] = __builtin_amdgcn_mfma_f32_16x16x32_bf16(af2, bfw, acc2[nt], 0, 0, 0);
            }
        }
        float* Out = ws + ((mode == 0) ? OFF_ETQ : OFF_ETK);   // both row-major
        #pragma unroll
        for (int nt = 0; nt < 4; nt++) {
            int d = l16 + nt * 16;
            float bi = biasF[d];
            #pragma unroll
            for (int r = 0; r < 4; r++) {
                int l = lbase + quad * 4 + r;
                Out[(size_t)(bh * LSEQ + l) * 64 + d] =
                    __expf(2.f * (acc2[nt][r] + bi));
            }
        }
    }
}

// ---------------------------------------------------------------------------
// Kernel 2: additive attention, TQ=8, 384 threads (t = k). Etk row-major:
// thread t reads its Etk row via 16 b128 loads (deep MLP, L1 reuse).
// Energy: e2 += vw_d * rcp(fma(Etq, Etk, 1.0)); no max-pass (|e| <~ 1).
// ---------------------------------------------------------------------------
__global__ __launch_bounds__(384, 6) void attn_kernel(
    const void* qp, const void* vwp, const void* vbp,
    const float* __restrict__ ws_in, float* __restrict__ ws,
    const int* __restrict__ mask, void* __restrict__ dout)
{
    __shared__ int s_cnt;
    const int f = block_detect((const unsigned int*)qp, &s_cnt);

    const float* Etq = ws_in + OFF_ETQ;
    const float* Etk = ws_in + OFF_ETK;
    const float* Vh  = ws_in + OFF_VH;
    float* Xh = ws + OFF_XH;

    const int bid = blockIdx.x;
    const int qt = bid % QTILES;
    const int bh = bid / QTILES;
    const int q0 = qt * TQ;
    const int b  = bh >> 3;
    const int h  = bh & 7;
    const int t  = threadIdx.x;
    const int wave = t >> 6;

    __shared__ __align__(16) float etq8[64][TQ];
    __shared__ float vws[64];
    __shared__ float ps[TQ][LSEQ];
    __shared__ float red[6][TQ][16][4];
    __shared__ float rsum[TQ][6];
    __shared__ float s_vb;

    for (int i = t; i < TQ * 64; i += 384) {
        int qi = i >> 6, d = i & 63;
        etq8[d][qi] = Etq[(size_t)(bh * LSEQ + q0 + qi) * 64 + d];
    }
    if (t < 64) {
        float v = ld1(vwp, t, f);
        vws[t] = v;
        #pragma unroll
        for (int off = 32; off > 0; off >>= 1) v += __shfl_xor(v, off, 64);
        if (t == 0) s_vb = ld1(vbp, 0, f) + v;
    }
    const int mok = mask[b * LSEQ + t];
    __syncthreads();
    const float vbSum = s_vb;

    float e2[TQ] = {0.f, 0.f, 0.f, 0.f, 0.f, 0.f, 0.f, 0.f};
    const float* ekrow = Etk + (size_t)(bh * LSEQ + t) * 64;
    #pragma unroll 4
    for (int dv = 0; dv < 16; dv++) {
        float4 ek4 = *reinterpret_cast<const float4*>(ekrow + dv * 4);
        #pragma unroll
        for (int j = 0; j < 4; j++) {
            int d = dv * 4 + j;
            float ekv = (j == 0) ? ek4.x : (j == 1) ? ek4.y : (j == 2) ? ek4.z : ek4.w;
            float4 eqA = *reinterpret_cast<const float4*>(&etq8[d][0]);
            float4 eqB = *reinterpret_cast<const float4*>(&etq8[d][4]);
            float wv = vws[d];
            e2[0] = fmaf(wv, __builtin_amdgcn_rcpf(fmaf(eqA.x, ekv, 1.0f)), e2[0]);
            e2[1] = fmaf(wv, __builtin_amdgcn_rcpf(fmaf(eqA.y, ekv, 1.0f)), e2[1]);
            e2[2] = fmaf(wv, __builtin_amdgcn_rcpf(fmaf(eqA.z, ekv, 1.0f)), e2[2]);
            e2[3] = fmaf(wv, __builtin_amdgcn_rcpf(fmaf(eqA.w, ekv, 1.0f)), e2[3]);
            e2[4] = fmaf(wv, __builtin_amdgcn_rcpf(fmaf(eqB.x, ekv, 1.0f)), e2[4]);
            e2[5] = fmaf(wv, __builtin_amdgcn_rcpf(fmaf(eqB.y, ekv, 1.0f)), e2[5]);
            e2[6] = fmaf(wv, __builtin_amdgcn_rcpf(fmaf(eqB.z, ekv, 1.0f)), e2[6]);
            e2[7] = fmaf(wv, __builtin_amdgcn_rcpf(fmaf(eqB.w, ekv, 1.0f)), e2[7]);
        }
    }

    float p[TQ];
    #pragma unroll
    for (int qi = 0; qi < TQ; qi++) {
        float en = fmaf(-2.0f, e2[qi], vbSum);
        if (mok == 0) en = -1e10f;
        p[qi] = __expf(en);
        float s = p[qi];
        #pragma unroll
        for (int off = 32; off > 0; off >>= 1) s += __shfl_xor(s, off, 64);
        if ((t & 63) == 0) rsum[qi][wave] = s;
    }
    __syncthreads();
    #pragma unroll
    for (int qi = 0; qi < TQ; qi++) {
        float gs = rsum[qi][0] + rsum[qi][1] + rsum[qi][2] +
                   rsum[qi][3] + rsum[qi][4] + rsum[qi][5];
        p[qi] *= 1.0f / gs;
        ps[qi][t] = p[qi];
        size_t aidx = XELEMS + (size_t)(bh * LSEQ + q0 + qi) * LSEQ + t;
        if (f) ((float*)dout)[aidx] = p[qi];
        else   ((ushort_t*)dout)[aidx] = f2bf(p[qi]);
    }
    __syncthreads();

    const int dq = t & 15;
    const int ksub = t >> 4;
    const float* vb4 = Vh + (size_t)bh * LSEQ * 64 + dq * 4;
    float4 acc[TQ];
    #pragma unroll
    for (int qi = 0; qi < TQ; qi++) acc[qi] = make_float4(0.f, 0.f, 0.f, 0.f);
    for (int kk = ksub; kk < LSEQ; kk += 24) {
        float4 v4 = *reinterpret_cast<const float4*>(vb4 + (size_t)kk * 64);
        #pragma unroll
        for (int qi = 0; qi < TQ; qi++) {
            float pq = ps[qi][kk];
            acc[qi].x = fmaf(pq, v4.x, acc[qi].x);
            acc[qi].y = fmaf(pq, v4.y, acc[qi].y);
            acc[qi].z = fmaf(pq, v4.z, acc[qi].z);
            acc[qi].w = fmaf(pq, v4.w, acc[qi].w);
        }
    }
    #pragma unroll
    for (int qi = 0; qi < TQ; qi++) {
        #pragma unroll
        for (int off = 16; off <= 32; off <<= 1) {
            acc[qi].x += __shfl_xor(acc[qi].x, off, 64);
            acc[qi].y += __shfl_xor(acc[qi].y, off, 64);
            acc[qi].z += __shfl_xor(acc[qi].z, off, 64);
            acc[qi].w += __shfl_xor(acc[qi].w, off, 64);
        }
    }
    if ((t & 63) < 16) {
        #pragma unroll
        for (int qi = 0; qi < TQ; qi++) {
            red[wave][qi][dq][0] = acc[qi].x;
            red[wave][qi][dq][1] = acc[qi].y;
            red[wave][qi][dq][2] = acc[qi].z;
            red[wave][qi][dq][3] = acc[qi].w;
        }
    }
    __syncthreads();
    if (t < 256) {
        int d = t & 63;
        #pragma unroll
        for (int half = 0; half < 2; half++) {
            int qi = (t >> 6) + half * 4;
            float sx = 0.f;
            #pragma unroll
            for (int w = 0; w < 6; w++) sx += red[w][qi][d >> 2][d & 3];
            Xh[((size_t)(b * LSEQ + q0 + qi) * NH + h) * 64 + d] = sx;
        }
    }
}

// ---------------------------------------------------------------------------
// Kernel 3: output projection via bf16 MFMA. x = Xh @ Wo^T + bo, dual-dtype.
// Direct write (no split-K, no reduce kernel).
// ---------------------------------------------------------------------------
__global__ __launch_bounds__(128) void gemm_out(
    const void* qp, const void* Wop, const void* bop,
    const float* __restrict__ ws_in, void* __restrict__ dout)
{
    __shared__ int s_cnt;
    __shared__ ushort_t smA[32 * LDSTR];
    __shared__ ushort_t smB[64 * LDSTR];
    __shared__ float biasF[64];
    const int f = block_detect((const unsigned int*)qp, &s_cnt);

    const float* Xh = ws_in + OFF_XH;
    const int col0 = blockIdx.x * 64;
    const int row0 = blockIdx.y * 32;
    const int t = threadIdx.x;
    const int w = t >> 6, l16 = t & 15, quad = (t & 63) >> 4;

    if (t < 64) biasF[t] = ld1(bop, col0 + t, f);

    const int arow = t >> 2, acol = (t & 3) * 16;
    const int brow = t >> 1, bcol = (t & 1) * 32;
    const float* Ab = Xh + (size_t)(row0 + arow) * 512 + acol;
    const size_t bbase = (size_t)(col0 + brow) * 512 + bcol;

    float4 a4[4], b4[8];
    #pragma unroll
    for (int i = 0; i < 4; i++) a4[i] = *reinterpret_cast<const float4*>(Ab + i * 4);
    #pragma unroll
    for (int i = 0; i < 8; i++) b4[i] = ld4(Wop, bbase + i * 4, f);

    f32x4 acc[4];
    #pragma unroll
    for (int nt = 0; nt < 4; nt++) acc[nt] = (f32x4){0.f, 0.f, 0.f, 0.f};

    for (int k0 = 0; k0 < 512; k0 += 64) {
        __syncthreads();
        *reinterpret_cast<uint4*>(&smA[arow * LDSTR + acol])     = packu4(a4[0], a4[1]);
        *reinterpret_cast<uint4*>(&smA[arow * LDSTR + acol + 8]) = packu4(a4[2], a4[3]);
        *reinterpret_cast<uint4*>(&smB[brow * LDSTR + bcol])      = packu4(b4[0], b4[1]);
        *reinterpret_cast<uint4*>(&smB[brow * LDSTR + bcol + 8])  = packu4(b4[2], b4[3]);
        *reinterpret_cast<uint4*>(&smB[brow * LDSTR + bcol + 16]) = packu4(b4[4], b4[5]);
        *reinterpret_cast<uint4*>(&smB[brow * LDSTR + bcol + 24]) = packu4(b4[6], b4[7]);
        __syncthreads();
        if (k0 + 64 < 512) {
            #pragma unroll
            for (int i = 0; i < 4; i++)
                a4[i] = *reinterpret_cast<const float4*>(Ab + k0 + 64 + i * 4);
            #pragma unroll
            for (int i = 0; i < 8; i++) b4[i] = ld4(Wop, bbase + k0 + 64 + i * 4, f);
        }
        #pragma unroll
        for (int kk = 0; kk < 2; kk++) {
            bf16x8 af = *reinterpret_cast<const bf16x8*>(
                &smA[(w * 16 + l16) * LDSTR + kk * 32 + quad * 8]);
            #pragma unroll
            for (int nt = 0; nt < 4; nt++) {
                bf16x8 bfr = *reinterpret_cast<const bf16x8*>(
                    &smB[(nt * 16 + l16) * LDSTR + kk * 32 + quad * 8]);
                acc[nt] = __builtin_amdgcn_mfma_f32_16x16x32_bf16(af, bfr, acc[nt], 0, 0, 0);
            }
        }
    }

    #pragma unroll
    for (int nt = 0; nt < 4; nt++) {
        int n = col0 + l16 + nt * 16;
        float bi = biasF[l16 + nt * 16];
        #pragma unroll
        for (int r = 0; r < 4; r++) {
            int m = row0 + w * 16 + quad * 4 + r;
            float c = acc[nt][r] + bi;
            size_t idx = (size_t)m * 512 + n;
            if (f) ((float*)dout)[idx] = c;
            else   ((ushort_t*)dout)[idx] = f2bf(c);
        }
    }
}

// ---------------------------------------------------------------------------
extern "C" void kernel_launch(void* const* d_in, const int* in_sizes, int n_in,
                              void* d_out, int out_size, void* d_ws, size_t ws_size,
                              hipStream_t stream)
{
    const void* qp = d_in[0];
    const void* kp = d_in[1];
    const void* vp = d_in[2];
    const int* mask = (const int*)d_in[3];
    const void* Wqp = d_in[4];  const void* bqp = d_in[5];
    const void* Wkp = d_in[6];  const void* bkp = d_in[7];
    const void* Wvp = d_in[8];  const void* bvp = d_in[9];
    const void* Wop = d_in[10]; const void* bop = d_in[11];
    const void* W1p = d_in[12]; const void* b1p = d_in[13];
    const void* W2p = d_in[14]; const void* b2p = d_in[15];
    const void* vwp = d_in[16]; const void* vbp = d_in[17];

    float* ws = (float*)d_ws;

    gemm_qkv<<<dim3(8, 24, 3), 128, 0, stream>>>(qp, kp, vp, Wqp, Wkp, Wvp,
                                                 W1p, W2p, bqp, bkp, b1p, b2p,
                                                 bvp, ws);
    attn_kernel<<<BH * QTILES, 384, 0, stream>>>(qp, vwp, vbp, ws, ws, mask, d_out);
    gemm_out<<<dim3(8, 24, 1), 128, 0, stream>>>(qp, Wop, bop, ws, d_out);
}